// Round 7
// baseline (574.331 us; speedup 1.0000x reference)
//
#include <hip/hip_runtime.h>

#define D 128
#define HD 128
#define DE 16
#define MSG_IN 273
#define EB 64        // edges per block (mfma path)
#define NT 256
#define KP1 288      // padded msg K = 9 chunks of 32
#define NCH1 9
#define NCH2 4
#define NB 32
#define MSG_PAD 276  // fp32 fallback kernel
#define HID_PAD 132
#define CH8 (4 * EB * 64)   // ushort offset of chunk-8 region in lds[]

typedef __attribute__((ext_vector_type(8))) short short8v;
typedef __attribute__((ext_vector_type(4))) float f32x4;
typedef unsigned short ushort_t;

#define GLOAD_LDS16(gp, lp) \
    __builtin_amdgcn_global_load_lds((const __attribute__((address_space(1))) unsigned int*)(gp), \
                                     (__attribute__((address_space(3))) unsigned int*)(lp), 16, 0, 0)

__device__ __forceinline__ unsigned short f2bf(float v) {
    unsigned int u = __builtin_bit_cast(unsigned int, v);
    u += 0x7fffu + ((u >> 16) & 1u);
    return (unsigned short)(u >> 16);
}
__device__ __forceinline__ float bf2f(ushort_t u) {
    return __builtin_bit_cast(float, (unsigned int)u << 16);
}

// ---------------- weight repack: fp32 [K][N] -> bf16 transposed [N][Kpad] ----------------
__global__ void repack_kernel(const float* __restrict__ Wm1, const float* __restrict__ Wm2,
                              ushort_t* __restrict__ W1p, ushort_t* __restrict__ W2p) {
    int idx = blockIdx.x * 256 + threadIdx.x;
    const int n1 = 128 * KP1;
    if (idx < n1) {
        int n = idx / KP1, k = idx % KP1;
        float v = (k < MSG_IN) ? Wm1[(size_t)k * HD + n] : 0.f;
        W1p[idx] = f2bf(v);
    } else {
        int i2 = idx - n1;
        if (i2 < HD * D) {
            int n = i2 / HD, k = i2 % HD;
            W2p[i2] = f2bf(Wm2[(size_t)k * D + n]);
        }
    }
}

// ---------------- f -> bf16 pre-conversion ----------------
__global__ void fconv_kernel(const float* __restrict__ f, ushort_t* __restrict__ fb, int n8) {
    int i = blockIdx.x * 256 + threadIdx.x;
    if (i < n8) {
        float4 v0 = *(const float4*)(f + (size_t)i * 8);
        float4 v1 = *(const float4*)(f + (size_t)i * 8 + 4);
        union { ushort_t us[8]; short8v v; } pk;
        pk.us[0] = f2bf(v0.x); pk.us[1] = f2bf(v0.y);
        pk.us[2] = f2bf(v0.z); pk.us[3] = f2bf(v0.w);
        pk.us[4] = f2bf(v1.x); pk.us[5] = f2bf(v1.y);
        pk.us[6] = f2bf(v1.z); pk.us[7] = f2bf(v1.w);
        *(short8v*)(fb + (size_t)i * 8) = pk.v;
    }
}

// ---------------- CSR build: hist -> parallel scan -> scatter ----------------
__global__ void hist_kernel(const int* __restrict__ dst, int* __restrict__ cnt, int E) {
    int i = blockIdx.x * 256 + threadIdx.x;
    if (i < E) atomicAdd(&cnt[dst[i]], 1);
}

// 1 block x 1024 threads: exclusive scan of cnt -> roff AND cursor
__global__ __launch_bounds__(1024) void scan_kernel(const int* __restrict__ cnt,
                                                    int* __restrict__ roff,
                                                    int* __restrict__ cursor, int Nn) {
    __shared__ int wsum[16];
    const int t = threadIdx.x, l = t & 63, wid = t >> 6;
    int running = 0;
    for (int base = 0; base < Nn; base += 1024) {
        const int i = base + t;
        const int v = (i < Nn) ? cnt[i] : 0;
        int s = v;
        #pragma unroll
        for (int off = 1; off < 64; off <<= 1) {
            int u = __shfl_up(s, off, 64);
            if (l >= off) s += u;
        }
        if (l == 63) wsum[wid] = s;
        __syncthreads();
        if (wid == 0 && l < 16) {
            int xv = wsum[l];
            #pragma unroll
            for (int off = 1; off < 16; off <<= 1) {
                int u = __shfl_up(xv, off, 64);
                if (l >= off) xv += u;
            }
            wsum[l] = xv;
        }
        __syncthreads();
        const int prev  = (wid > 0) ? wsum[wid - 1] : 0;
        const int total = wsum[15];
        if (i < Nn) {
            int ex = running + prev + s - v;
            roff[i] = ex; cursor[i] = ex;
        }
        running += total;
        __syncthreads();   // protect wsum before next iteration
    }
}

__global__ void scatter_kernel(const int* __restrict__ dst, int* cursor,
                               int* __restrict__ perm, int* __restrict__ sdst, int E) {
    int i = blockIdx.x * 256 + threadIdx.x;
    if (i < E) {
        int d = dst[i];
        int s = atomicAdd(&cursor[d], 1);
        perm[s] = i;
        sdst[s] = d;
    }
}

// ---------------- edge kernel v7: sorted slots, gload_lds staging, PLAIN stores ----------------
// Identical compute structure to r6; atomic scatter replaced by coalesced stores of
// m_sorted[slot] (bf16 rows). dst-gathers are runs (sorted) -> L1 hits.
__global__ __launch_bounds__(NT, 4) void edge_mfma_sorted_kernel(
    const ushort_t* __restrict__ fbf, const float* __restrict__ x,
    const float* __restrict__ w, const int* __restrict__ src,
    const int* __restrict__ perm, const int* __restrict__ sdst,
    const ushort_t* __restrict__ W1p, const float* __restrict__ bm1,
    const ushort_t* __restrict__ W2p, const float* __restrict__ bm2,
    ushort_t* __restrict__ m_out, int E)
{
    __shared__ __align__(16) ushort_t lds[4 * EB * 64 + EB * 32];  // 36,864 B

    const int t    = threadIdx.x;
    const int lane = t & 63;
    const int wv   = t >> 6;
    const int e0   = blockIdx.x * EB;

    // ---- f staging: 8 x global_load_lds_dwordx4, pre-swizzled global source ----
    {
        const int el8 = lane >> 3;
        const int s   = lane & 7;
        const int sl  = s ^ el8;            // involution swizzle
        const int slA = min(e0 + wv * 16 + el8,     E - 1);
        const int slB = min(e0 + wv * 16 + 8 + el8, E - 1);
        const int geA = perm[slA], geB = perm[slB];
        const int nsA = src[geA], ndA = sdst[slA];
        const int nsB = src[geB], ndB = sdst[slB];
        #pragma unroll
        for (int p = 0; p < 4; ++p) {
            const int n0 = (p < 2) ? nsA : ndA;
            const int n1 = (p < 2) ? nsB : ndB;
            const ushort_t* g0 = fbf + (size_t)n0 * D + (p & 1) * 64 + sl * 8;
            const ushort_t* g1 = fbf + (size_t)n1 * D + (p & 1) * 64 + sl * 8;
            GLOAD_LDS16(g0, &lds[(p * EB + wv * 16    ) * 64]);
            GLOAD_LDS16(g1, &lds[(p * EB + wv * 16 + 8) * 64]);
        }
    }
    // ---- chunk 8: w feats (k0..15), sqd (k16), zeros; 2-bit swizzle ----
    {
        const int el = lane >> 2, q = lane & 3;
        const int qp = q ^ (el & 3);
        const int slot = e0 + wv * 16 + el;
        const bool ok = slot < E;
        const int sc = min(slot, E - 1);
        const int ge = perm[sc];
        union { ushort_t us[8]; short8v v; } pk;
        #pragma unroll
        for (int j = 0; j < 8; ++j) pk.us[j] = 0;
        if (ok) {
            if (q < 2) {
                float4 w0 = *(const float4*)(w + (size_t)ge * DE + q * 8);
                float4 w1 = *(const float4*)(w + (size_t)ge * DE + q * 8 + 4);
                pk.us[0] = f2bf(w0.x); pk.us[1] = f2bf(w0.y);
                pk.us[2] = f2bf(w0.z); pk.us[3] = f2bf(w0.w);
                pk.us[4] = f2bf(w1.x); pk.us[5] = f2bf(w1.y);
                pk.us[6] = f2bf(w1.z); pk.us[7] = f2bf(w1.w);
            } else if (q == 2) {
                const int ns = src[ge], nd = sdst[sc];
                float dx = x[ns*3+0] - x[nd*3+0];
                float dy = x[ns*3+1] - x[nd*3+1];
                float dz = x[ns*3+2] - x[nd*3+2];
                pk.us[0] = f2bf(dx*dx + dy*dy + dz*dz);
            }
        }
        *(short8v*)&lds[CH8 + (wv * 16 + el) * 32 + qp * 8] = pk.v;
    }

    const int col = lane & 15;
    const int g   = lane >> 4;

    // prefetch layer-1 chunk-0 B-frags before the barrier
    const size_t wrow0 = (size_t)(wv * 32 + col) * KP1;
    const size_t wrow1 = (size_t)(wv * 32 + 16 + col) * KP1;
    short8v nb0 = *(const short8v*)&W1p[wrow0 + g * 8];
    short8v nb1 = *(const short8v*)&W1p[wrow1 + g * 8];

    __syncthreads();   // B0: staging complete

    // ---- layer 1: [64,288] x [288,32] per wave ----
    f32x4 acc[4][2];
    {
        float bv0 = bm1[wv * 32 + col];
        float bv1 = bm1[wv * 32 + 16 + col];
        #pragma unroll
        for (int rt = 0; rt < 4; ++rt) {
            acc[rt][0] = (f32x4){bv0, bv0, bv0, bv0};
            acc[rt][1] = (f32x4){bv1, bv1, bv1, bv1};
        }
    }
    #pragma unroll
    for (int c = 0; c < NCH1; ++c) {
        short8v b0 = nb0, b1 = nb1;
        if (c + 1 < NCH1) {
            nb0 = *(const short8v*)&W1p[wrow0 + (c + 1) * 32 + g * 8];
            nb1 = *(const short8v*)&W1p[wrow1 + (c + 1) * 32 + g * 8];
        }
        short8v a[4];
        #pragma unroll
        for (int rt = 0; rt < 4; ++rt) {
            const int row = rt * 16 + col;
            if (c < 8) {
                const int sP = (((c & 1) << 2) + g) ^ (row & 7);
                a[rt] = *(const short8v*)&lds[((c >> 1) * EB + row) * 64 + sP * 8];
            } else {
                const int sP = g ^ (row & 3);
                a[rt] = *(const short8v*)&lds[CH8 + row * 32 + sP * 8];
            }
        }
        #pragma unroll
        for (int rt = 0; rt < 4; ++rt) {
            acc[rt][0] = __builtin_amdgcn_mfma_f32_16x16x32_bf16(a[rt], b0, acc[rt][0], 0, 0, 0);
            acc[rt][1] = __builtin_amdgcn_mfma_f32_16x16x32_bf16(a[rt], b1, acc[rt][1], 0, 0, 0);
        }
    }
    __syncthreads();   // B1: layer-1 LDS reads done -> pairs 0-1 reusable

    // hid (relu, bf16, pair-packed b32) -> pairs 0-1 region, same swizzle
    const bool even = (col & 1) == 0;
    const int ph = wv >> 1;
    #pragma unroll
    for (int rt = 0; rt < 4; ++rt)
        #pragma unroll
        for (int j = 0; j < 2; ++j)
            #pragma unroll
            for (int r = 0; r < 4; ++r) {
                const int row = rt * 16 + g * 4 + r;
                float v  = fmaxf(acc[rt][j][r], 0.f);
                float vn = __shfl_xor(v, 1, 64);
                if (even) {
                    unsigned int pk2 = (unsigned)f2bf(v) | ((unsigned)f2bf(vn) << 16);
                    const int sH = (((wv & 1) << 2) + j * 2 + (col >> 3)) ^ (row & 7);
                    *(unsigned int*)&lds[(ph * EB + row) * 64 + sH * 8 + (col & 7)] = pk2;
                }
            }
    __syncthreads();   // B2: hid complete block-wide

    // ---- layer 2: [64,128] x [128,32] per wave ----
    const size_t w2r0 = (size_t)(wv * 32 + col) * HD;
    const size_t w2r1 = (size_t)(wv * 32 + 16 + col) * HD;
    short8v m0 = *(const short8v*)&W2p[w2r0 + g * 8];
    short8v m1 = *(const short8v*)&W2p[w2r1 + g * 8];
    f32x4 acc2[4][2];
    {
        float bv0 = bm2[wv * 32 + col];
        float bv1 = bm2[wv * 32 + 16 + col];
        #pragma unroll
        for (int rt = 0; rt < 4; ++rt) {
            acc2[rt][0] = (f32x4){bv0, bv0, bv0, bv0};
            acc2[rt][1] = (f32x4){bv1, bv1, bv1, bv1};
        }
    }
    #pragma unroll
    for (int c = 0; c < NCH2; ++c) {
        short8v b0 = m0, b1 = m1;
        if (c + 1 < NCH2) {
            m0 = *(const short8v*)&W2p[w2r0 + (c + 1) * 32 + g * 8];
            m1 = *(const short8v*)&W2p[w2r1 + (c + 1) * 32 + g * 8];
        }
        short8v a[4];
        #pragma unroll
        for (int rt = 0; rt < 4; ++rt) {
            const int row = rt * 16 + col;
            const int sP = (((c & 1) << 2) + g) ^ (row & 7);
            a[rt] = *(const short8v*)&lds[((c >> 1) * EB + row) * 64 + sP * 8];
        }
        #pragma unroll
        for (int rt = 0; rt < 4; ++rt) {
            acc2[rt][0] = __builtin_amdgcn_mfma_f32_16x16x32_bf16(a[rt], b0, acc2[rt][0], 0, 0, 0);
            acc2[rt][1] = __builtin_amdgcn_mfma_f32_16x16x32_bf16(a[rt], b1, acc2[rt][1], 0, 0, 0);
        }
    }

    // ---- plain coalesced stores of m_sorted rows (no atomics) ----
    #pragma unroll
    for (int rt = 0; rt < 4; ++rt)
        #pragma unroll
        for (int r = 0; r < 4; ++r) {
            const int sl   = rt * 16 + g * 4 + r;
            const int slot = e0 + sl;
            #pragma unroll
            for (int j = 0; j < 2; ++j) {
                float v  = acc2[rt][j][r];
                float vn = __shfl_xor(v, 1, 64);
                if (even && slot < E) {
                    unsigned int pk2 = (unsigned)f2bf(v) | ((unsigned)f2bf(vn) << 16);
                    *(unsigned int*)&m_out[(size_t)slot * D + wv * 32 + j * 16 + col] = pk2;
                }
            }
        }
}

// ---------------- node kernel v7: CSR segment-reduce (fp32) + update MLP ----------------
__global__ __launch_bounds__(NT, 2) void node_csr_kernel(
    const float* __restrict__ f, const ushort_t* __restrict__ m_sorted,
    const int* __restrict__ roff, const int* __restrict__ cnt,
    const float* __restrict__ Wu1, const float* __restrict__ bu1,
    const float* __restrict__ Wu2, const float* __restrict__ bu2,
    float* out, int Nn)
{
    __shared__ __align__(16) float hin[NB][HID_PAD];
    __shared__ __align__(16) float hid[NB][HID_PAD];
    const int t  = threadIdx.x;
    const int n0 = blockIdx.x * NB;
    const int nn = min(NB, Nn - n0);

    {
        const int cg = t & 63;      // column pair 2cg, 2cg+1
        const int ng = t >> 6;      // wave id: node round-robin
        for (int e = ng; e < nn; e += 4) {
            const int n   = n0 + e;
            const int beg = roff[n];
            const int num = cnt[n];
            float s0 = 0.f, s1 = 0.f;
            for (int i = 0; i < num; ++i) {
                unsigned pk = *(const unsigned*)&m_sorted[(size_t)(beg + i) * D + cg * 2];
                s0 += bf2f((ushort_t)(pk & 0xffffu));
                s1 += bf2f((ushort_t)(pk >> 16));
            }
            float2 fv = *(const float2*)&f[(size_t)n * D + cg * 2];
            hin[e][cg * 2]     = s0 + fv.x;
            hin[e][cg * 2 + 1] = s1 + fv.y;
        }
    }
    __syncthreads();

    const int tc = t & 15, te2 = (t >> 4) * 2, c0 = tc * 8;
    float a1[2][8];
    #pragma unroll
    for (int c = 0; c < 8; ++c) { float bv = bu1[c0 + c]; a1[0][c] = bv; a1[1][c] = bv; }
    for (int i = 0; i < D; i += 4) {
        float m0[4], m1[4];
        *(float4*)m0 = *(const float4*)&hin[te2][i];
        *(float4*)m1 = *(const float4*)&hin[te2 + 1][i];
        #pragma unroll
        for (int r = 0; r < 4; ++r) {
            float wr[8];
            *(float4*)&wr[0] = *(const float4*)(Wu1 + (size_t)(i + r) * HD + c0);
            *(float4*)&wr[4] = *(const float4*)(Wu1 + (size_t)(i + r) * HD + c0 + 4);
            #pragma unroll
            for (int c = 0; c < 8; ++c) { a1[0][c] += m0[r]*wr[c]; a1[1][c] += m1[r]*wr[c]; }
        }
    }
    #pragma unroll
    for (int j = 0; j < 2; ++j) {
        float v[8];
        #pragma unroll
        for (int c = 0; c < 8; ++c) v[c] = fmaxf(a1[j][c], 0.f);
        *(float4*)&hid[te2 + j][c0] = *(float4*)&v[0];
        *(float4*)&hid[te2 + j][c0 + 4] = *(float4*)&v[4];
    }
    __syncthreads();
    float a2[2][8];
    #pragma unroll
    for (int c = 0; c < 8; ++c) { float bv = bu2[c0 + c]; a2[0][c] = bv; a2[1][c] = bv; }
    for (int h = 0; h < HD; h += 4) {
        float m0[4], m1[4];
        *(float4*)m0 = *(const float4*)&hid[te2][h];
        *(float4*)m1 = *(const float4*)&hid[te2 + 1][h];
        #pragma unroll
        for (int r = 0; r < 4; ++r) {
            float wr[8];
            *(float4*)&wr[0] = *(const float4*)(Wu2 + (size_t)(h + r) * D + c0);
            *(float4*)&wr[4] = *(const float4*)(Wu2 + (size_t)(h + r) * D + c0 + 4);
            #pragma unroll
            for (int c = 0; c < 8; ++c) { a2[0][c] += m0[r]*wr[c]; a2[1][c] += m1[r]*wr[c]; }
        }
    }
    #pragma unroll
    for (int j = 0; j < 2; ++j) {
        int e = te2 + j, gn = n0 + e;
        if (e < nn) {
            *(float4*)(out + (size_t)gn * D + c0) = *(float4*)&a2[j][0];
            *(float4*)(out + (size_t)gn * D + c0 + 4) = *(float4*)&a2[j][4];
        }
    }
}

// ================= fallback kernels (r6 pk-atomic path + r3 fp32 path) =================

__global__ __launch_bounds__(NT, 4) void edge_mfma_kernel(
    const ushort_t* __restrict__ fbf, const float* __restrict__ x,
    const float* __restrict__ w, const int* __restrict__ src,
    const int* __restrict__ dst,
    const ushort_t* __restrict__ W1p, const float* __restrict__ bm1,
    const ushort_t* __restrict__ W2p, const float* __restrict__ bm2,
    ushort_t* msum, int E)
{
    __shared__ __align__(16) ushort_t lds[4 * EB * 64 + EB * 32];
    __shared__ int s_dst[EB];

    const int t    = threadIdx.x;
    const int lane = t & 63;
    const int wv   = t >> 6;
    const int e0   = blockIdx.x * EB;

    if (t < EB) s_dst[t] = (e0 + t < E) ? dst[e0 + t] : 0;
    {
        const int el8 = lane >> 3;
        const int s   = lane & 7;
        const int sl  = s ^ el8;
        const int geA = min(e0 + wv * 16 + el8,     E - 1);
        const int geB = min(e0 + wv * 16 + 8 + el8, E - 1);
        const int nsA = src[geA], ndA = dst[geA];
        const int nsB = src[geB], ndB = dst[geB];
        #pragma unroll
        for (int p = 0; p < 4; ++p) {
            const int n0 = (p < 2) ? nsA : ndA;
            const int n1 = (p < 2) ? nsB : ndB;
            const ushort_t* g0 = fbf + (size_t)n0 * D + (p & 1) * 64 + sl * 8;
            const ushort_t* g1 = fbf + (size_t)n1 * D + (p & 1) * 64 + sl * 8;
            GLOAD_LDS16(g0, &lds[(p * EB + wv * 16    ) * 64]);
            GLOAD_LDS16(g1, &lds[(p * EB + wv * 16 + 8) * 64]);
        }
    }
    {
        const int el = lane >> 2, q = lane & 3;
        const int qp = q ^ (el & 3);
        const int ge = e0 + wv * 16 + el;
        const bool ok = ge < E;
        const int gc = min(ge, E - 1);
        union { ushort_t us[8]; short8v v; } pk;
        #pragma unroll
        for (int j = 0; j < 8; ++j) pk.us[j] = 0;
        if (ok) {
            if (q < 2) {
                float4 w0 = *(const float4*)(w + (size_t)gc * DE + q * 8);
                float4 w1 = *(const float4*)(w + (size_t)gc * DE + q * 8 + 4);
                pk.us[0] = f2bf(w0.x); pk.us[1] = f2bf(w0.y);
                pk.us[2] = f2bf(w0.z); pk.us[3] = f2bf(w0.w);
                pk.us[4] = f2bf(w1.x); pk.us[5] = f2bf(w1.y);
                pk.us[6] = f2bf(w1.z); pk.us[7] = f2bf(w1.w);
            } else if (q == 2) {
                const int ns = src[gc], nd = dst[gc];
                float dx = x[ns*3+0] - x[nd*3+0];
                float dy = x[ns*3+1] - x[nd*3+1];
                float dz = x[ns*3+2] - x[nd*3+2];
                pk.us[0] = f2bf(dx*dx + dy*dy + dz*dz);
            }
        }
        *(short8v*)&lds[CH8 + (wv * 16 + el) * 32 + qp * 8] = pk.v;
    }

    const int col = lane & 15;
    const int g   = lane >> 4;
    const size_t wrow0 = (size_t)(wv * 32 + col) * KP1;
    const size_t wrow1 = (size_t)(wv * 32 + 16 + col) * KP1;
    short8v nb0 = *(const short8v*)&W1p[wrow0 + g * 8];
    short8v nb1 = *(const short8v*)&W1p[wrow1 + g * 8];
    __syncthreads();

    f32x4 acc[4][2];
    {
        float bv0 = bm1[wv * 32 + col];
        float bv1 = bm1[wv * 32 + 16 + col];
        #pragma unroll
        for (int rt = 0; rt < 4; ++rt) {
            acc[rt][0] = (f32x4){bv0, bv0, bv0, bv0};
            acc[rt][1] = (f32x4){bv1, bv1, bv1, bv1};
        }
    }
    #pragma unroll
    for (int c = 0; c < NCH1; ++c) {
        short8v b0 = nb0, b1 = nb1;
        if (c + 1 < NCH1) {
            nb0 = *(const short8v*)&W1p[wrow0 + (c + 1) * 32 + g * 8];
            nb1 = *(const short8v*)&W1p[wrow1 + (c + 1) * 32 + g * 8];
        }
        short8v a[4];
        #pragma unroll
        for (int rt = 0; rt < 4; ++rt) {
            const int row = rt * 16 + col;
            if (c < 8) {
                const int sP = (((c & 1) << 2) + g) ^ (row & 7);
                a[rt] = *(const short8v*)&lds[((c >> 1) * EB + row) * 64 + sP * 8];
            } else {
                const int sP = g ^ (row & 3);
                a[rt] = *(const short8v*)&lds[CH8 + row * 32 + sP * 8];
            }
        }
        #pragma unroll
        for (int rt = 0; rt < 4; ++rt) {
            acc[rt][0] = __builtin_amdgcn_mfma_f32_16x16x32_bf16(a[rt], b0, acc[rt][0], 0, 0, 0);
            acc[rt][1] = __builtin_amdgcn_mfma_f32_16x16x32_bf16(a[rt], b1, acc[rt][1], 0, 0, 0);
        }
    }
    __syncthreads();

    const bool even = (col & 1) == 0;
    const int ph = wv >> 1;
    #pragma unroll
    for (int rt = 0; rt < 4; ++rt)
        #pragma unroll
        for (int j = 0; j < 2; ++j)
            #pragma unroll
            for (int r = 0; r < 4; ++r) {
                const int row = rt * 16 + g * 4 + r;
                float v  = fmaxf(acc[rt][j][r], 0.f);
                float vn = __shfl_xor(v, 1, 64);
                if (even) {
                    unsigned int pk2 = (unsigned)f2bf(v) | ((unsigned)f2bf(vn) << 16);
                    const int sH = (((wv & 1) << 2) + j * 2 + (col >> 3)) ^ (row & 7);
                    *(unsigned int*)&lds[(ph * EB + row) * 64 + sH * 8 + (col & 7)] = pk2;
                }
            }
    __syncthreads();

    const size_t w2r0 = (size_t)(wv * 32 + col) * HD;
    const size_t w2r1 = (size_t)(wv * 32 + 16 + col) * HD;
    short8v m0 = *(const short8v*)&W2p[w2r0 + g * 8];
    short8v m1 = *(const short8v*)&W2p[w2r1 + g * 8];
    f32x4 acc2[4][2];
    {
        float bv0 = bm2[wv * 32 + col];
        float bv1 = bm2[wv * 32 + 16 + col];
        #pragma unroll
        for (int rt = 0; rt < 4; ++rt) {
            acc2[rt][0] = (f32x4){bv0, bv0, bv0, bv0};
            acc2[rt][1] = (f32x4){bv1, bv1, bv1, bv1};
        }
    }
    #pragma unroll
    for (int c = 0; c < NCH2; ++c) {
        short8v b0 = m0, b1 = m1;
        if (c + 1 < NCH2) {
            m0 = *(const short8v*)&W2p[w2r0 + (c + 1) * 32 + g * 8];
            m1 = *(const short8v*)&W2p[w2r1 + (c + 1) * 32 + g * 8];
        }
        short8v a[4];
        #pragma unroll
        for (int rt = 0; rt < 4; ++rt) {
            const int row = rt * 16 + col;
            const int sP = (((c & 1) << 2) + g) ^ (row & 7);
            a[rt] = *(const short8v*)&lds[((c >> 1) * EB + row) * 64 + sP * 8];
        }
        #pragma unroll
        for (int rt = 0; rt < 4; ++rt) {
            acc2[rt][0] = __builtin_amdgcn_mfma_f32_16x16x32_bf16(a[rt], b0, acc2[rt][0], 0, 0, 0);
            acc2[rt][1] = __builtin_amdgcn_mfma_f32_16x16x32_bf16(a[rt], b1, acc2[rt][1], 0, 0, 0);
        }
    }

    #pragma unroll
    for (int rt = 0; rt < 4; ++rt)
        #pragma unroll
        for (int r = 0; r < 4; ++r) {
            const int e  = rt * 16 + g * 4 + r;
            const int ge = e0 + e;
            const int dg = s_dst[e];
            #pragma unroll
            for (int j = 0; j < 2; ++j) {
                float v  = acc2[rt][j][r];
                float vn = __shfl_xor(v, 1, 64);
                if (even && ge < E) {
                    unsigned int pk2 = (unsigned)f2bf(v) | ((unsigned)f2bf(vn) << 16);
                    ushort_t* p = msum + (size_t)dg * D + wv * 32 + j * 16 + col;
                    asm volatile("global_atomic_pk_add_bf16 %0, %1, off"
                                 :: "v"(p), "v"(pk2) : "memory");
                }
            }
        }
}

template<bool MB16>
__global__ __launch_bounds__(NT, 2) void node_kernel(
    const float* __restrict__ f, const void* __restrict__ msum_v,
    const float* __restrict__ Wu1, const float* __restrict__ bu1,
    const float* __restrict__ Wu2, const float* __restrict__ bu2,
    float* out, int Nn)
{
    __shared__ __align__(16) float hin[NB][HID_PAD];
    __shared__ __align__(16) float hid[NB][HID_PAD];
    const int t  = threadIdx.x;
    const int n0 = blockIdx.x * NB;
    const int nn = min(NB, Nn - n0);

    {
        const int half = t >> 7, tt = t & 127;
        for (int e = half; e < nn; e += 2) {
            size_t off = (size_t)(n0 + e) * D + tt;
            float mv = MB16 ? bf2f(((const ushort_t*)msum_v)[off])
                            : ((const float*)msum_v)[off];
            hin[e][tt] = mv + f[off];
        }
    }
    __syncthreads();

    const int tc = t & 15, te2 = (t >> 4) * 2, c0 = tc * 8;
    float a1[2][8];
    #pragma unroll
    for (int c = 0; c < 8; ++c) { float bv = bu1[c0 + c]; a1[0][c] = bv; a1[1][c] = bv; }
    for (int i = 0; i < D; i += 4) {
        float m0[4], m1[4];
        *(float4*)m0 = *(const float4*)&hin[te2][i];
        *(float4*)m1 = *(const float4*)&hin[te2 + 1][i];
        #pragma unroll
        for (int r = 0; r < 4; ++r) {
            float wr[8];
            *(float4*)&wr[0] = *(const float4*)(Wu1 + (size_t)(i + r) * HD + c0);
            *(float4*)&wr[4] = *(const float4*)(Wu1 + (size_t)(i + r) * HD + c0 + 4);
            #pragma unroll
            for (int c = 0; c < 8; ++c) { a1[0][c] += m0[r]*wr[c]; a1[1][c] += m1[r]*wr[c]; }
        }
    }
    #pragma unroll
    for (int j = 0; j < 2; ++j) {
        float v[8];
        #pragma unroll
        for (int c = 0; c < 8; ++c) v[c] = fmaxf(a1[j][c], 0.f);
        *(float4*)&hid[te2 + j][c0] = *(float4*)&v[0];
        *(float4*)&hid[te2 + j][c0 + 4] = *(float4*)&v[4];
    }
    __syncthreads();
    float a2[2][8];
    #pragma unroll
    for (int c = 0; c < 8; ++c) { float bv = bu2[c0 + c]; a2[0][c] = bv; a2[1][c] = bv; }
    for (int h = 0; h < HD; h += 4) {
        float m0[4], m1[4];
        *(float4*)m0 = *(const float4*)&hid[te2][h];
        *(float4*)m1 = *(const float4*)&hid[te2 + 1][h];
        #pragma unroll
        for (int r = 0; r < 4; ++r) {
            float wr[8];
            *(float4*)&wr[0] = *(const float4*)(Wu2 + (size_t)(h + r) * D + c0);
            *(float4*)&wr[4] = *(const float4*)(Wu2 + (size_t)(h + r) * D + c0 + 4);
            #pragma unroll
            for (int c = 0; c < 8; ++c) { a2[0][c] += m0[r]*wr[c]; a2[1][c] += m1[r]*wr[c]; }
        }
    }
    #pragma unroll
    for (int j = 0; j < 2; ++j) {
        int e = te2 + j, gn = n0 + e;
        if (e < nn) {
            *(float4*)(out + (size_t)gn * D + c0) = *(float4*)&a2[j][0];
            *(float4*)(out + (size_t)gn * D + c0 + 4) = *(float4*)&a2[j][4];
        }
    }
}

// fp32-atomic fallback edge kernel (msum in d_out)
__global__ __launch_bounds__(NT, 4) void edge_mfma_kernel_fa(
    const float* __restrict__ f, const float* __restrict__ x,
    const float* __restrict__ w, const int* __restrict__ src,
    const int* __restrict__ dst,
    const ushort_t* __restrict__ W1p, const float* __restrict__ bm1,
    const ushort_t* __restrict__ W2p, const float* __restrict__ bm2,
    float* msum, int E)
{
    __shared__ __align__(16) ushort_t msg_c[NCH1 * EB * 32];

    const int t    = threadIdx.x;
    const int lane = t & 63;
    const int wv   = t >> 6;
    const int e0   = blockIdx.x * EB;

    {
        const int el = lane >> 2;
        const int q  = lane & 3;
        const int ge = e0 + wv * 16 + el;
        const bool ok = ge < E;
        const int ns = ok ? src[ge] : 0;
        const int nd = ok ? dst[ge] : 0;
        const int mrow = wv * 16 + el;
        #pragma unroll
        for (int i = 0; i < 8; ++i) {
            const int k0 = i * 32 + q * 8;
            union { unsigned short us[8]; short8v v; } pk;
            if (ok) {
                const float* base = (k0 < D) ? (f + (size_t)ns * D + k0)
                                             : (f + (size_t)nd * D + (k0 - D));
                float4 v0 = *(const float4*)base;
                float4 v1 = *(const float4*)(base + 4);
                pk.us[0] = f2bf(v0.x); pk.us[1] = f2bf(v0.y);
                pk.us[2] = f2bf(v0.z); pk.us[3] = f2bf(v0.w);
                pk.us[4] = f2bf(v1.x); pk.us[5] = f2bf(v1.y);
                pk.us[6] = f2bf(v1.z); pk.us[7] = f2bf(v1.w);
            } else {
                #pragma unroll
                for (int j = 0; j < 8; ++j) pk.us[j] = 0;
            }
            *(short8v*)&msg_c[(i * EB + mrow) * 32 + q * 8] = pk.v;
        }
        {
            union { unsigned short us[8]; short8v v; } pk;
            #pragma unroll
            for (int j = 0; j < 8; ++j) pk.us[j] = 0;
            if (ok) {
                if (q < 2) {
                    float4 w0 = *(const float4*)(w + (size_t)ge * DE + q * 8);
                    float4 w1 = *(const float4*)(w + (size_t)ge * DE + q * 8 + 4);
                    pk.us[0] = f2bf(w0.x); pk.us[1] = f2bf(w0.y);
                    pk.us[2] = f2bf(w0.z); pk.us[3] = f2bf(w0.w);
                    pk.us[4] = f2bf(w1.x); pk.us[5] = f2bf(w1.y);
                    pk.us[6] = f2bf(w1.z); pk.us[7] = f2bf(w1.w);
                } else if (q == 2) {
                    float dx = x[ns*3+0] - x[nd*3+0];
                    float dy = x[ns*3+1] - x[nd*3+1];
                    float dz = x[ns*3+2] - x[nd*3+2];
                    pk.us[0] = f2bf(dx*dx + dy*dy + dz*dz);
                }
            }
            *(short8v*)&msg_c[(8 * EB + mrow) * 32 + q * 8] = pk.v;
        }
    }

    const int col  = lane & 15;
    const int g    = lane >> 4;
    const int erow = wv * 16 + col;

    f32x4 acc[8];
    #pragma unroll
    for (int ct = 0; ct < 8; ++ct) {
        float bv = bm1[ct * 16 + col];
        acc[ct] = (f32x4){bv, bv, bv, bv};
    }
    for (int c = 0; c < NCH1; ++c) {
        short8v a = *(const short8v*)&msg_c[(c * EB + erow) * 32 + g * 8];
        #pragma unroll
        for (int ct = 0; ct < 8; ++ct) {
            short8v b = *(const short8v*)&W1p[(size_t)(ct * 16 + col) * KP1 + c * 32 + g * 8];
            acc[ct] = __builtin_amdgcn_mfma_f32_16x16x32_bf16(a, b, acc[ct], 0, 0, 0);
        }
    }
    #pragma unroll
    for (int ct = 0; ct < 8; ++ct) {
        const int h  = ct * 16 + col;
        const int hc = h >> 5, hi = h & 31;
        #pragma unroll
        for (int r = 0; r < 4; ++r) {
            const int e = wv * 16 + g * 4 + r;
            msg_c[(hc * EB + e) * 32 + hi] = f2bf(fmaxf(acc[ct][r], 0.f));
        }
    }

    f32x4 acc2[8];
    #pragma unroll
    for (int ct = 0; ct < 8; ++ct) {
        float bv = bm2[ct * 16 + col];
        acc2[ct] = (f32x4){bv, bv, bv, bv};
    }
    for (int c = 0; c < NCH2; ++c) {
        short8v a = *(const short8v*)&msg_c[(c * EB + erow) * 32 + g * 8];
        #pragma unroll
        for (int ct = 0; ct < 8; ++ct) {
            short8v b = *(const short8v*)&W2p[(size_t)(ct * 16 + col) * HD + c * 32 + g * 8];
            acc2[ct] = __builtin_amdgcn_mfma_f32_16x16x32_bf16(a, b, acc2[ct], 0, 0, 0);
        }
    }

    #pragma unroll
    for (int r = 0; r < 4; ++r) {
        const int el = wv * 16 + g * 4 + r;
        const int ge = e0 + el;
        if (ge < E) {
            const int dg = dst[ge];
            float* p = msum + (size_t)dg * D + col;
            #pragma unroll
            for (int ct = 0; ct < 8; ++ct)
                atomicAdd(p + ct * 16, acc2[ct][r]);
        }
    }
}

extern "C" void kernel_launch(void* const* d_in, const int* in_sizes, int n_in,
                              void* d_out, int out_size, void* d_ws, size_t ws_size,
                              hipStream_t stream) {
    const float* f   = (const float*)d_in[0];
    const float* x   = (const float*)d_in[1];
    const float* w   = (const float*)d_in[2];
    const int*   src = (const int*)d_in[3];
    const int*   dst = (const int*)d_in[4];
    const float* Wm1 = (const float*)d_in[5];
    const float* bm1 = (const float*)d_in[6];
    const float* Wm2 = (const float*)d_in[7];
    const float* bm2 = (const float*)d_in[8];
    const float* Wu1 = (const float*)d_in[9];
    const float* bu1 = (const float*)d_in[10];
    const float* Wu2 = (const float*)d_in[11];
    const float* bu2 = (const float*)d_in[12];

    const int Nn = in_sizes[0] / D;
    const int E  = in_sizes[3];

    const size_t wbytes = (size_t)(128 * KP1 + HD * D) * sizeof(ushort_t);
    auto align512 = [](size_t v) { return (v + 511) & ~(size_t)511; };

    const size_t fb_bytes = (size_t)Nn * D * 2;
    char* wsb = (char*)d_ws;
    const int rp_elems = 128 * KP1 + HD * D;

    // ---------------- two-phase CSR layout ----------------
    size_t off = 0;
    const size_t o_w    = off; off = align512(off + wbytes);
    const size_t o_fb   = off; off = align512(off + fb_bytes);
    const size_t o_cnt  = off; off = align512(off + (size_t)Nn * 4);
    const size_t o_roff = off; off = align512(off + (size_t)Nn * 4);
    const size_t o_cur  = off; off = align512(off + (size_t)Nn * 4);
    const size_t o_perm = off; off = align512(off + (size_t)E * 4);
    const size_t o_sdst = off; off = align512(off + (size_t)E * 4);
    const size_t o_m    = off; off = align512(off + (size_t)E * D * 2);
    const size_t two_phase_total = off;

    if (ws_size >= two_phase_total) {
        ushort_t* W1p   = (ushort_t*)(wsb + o_w);
        ushort_t* W2p   = W1p + 128 * KP1;
        ushort_t* fbf   = (ushort_t*)(wsb + o_fb);
        int* cnt        = (int*)(wsb + o_cnt);
        int* roff       = (int*)(wsb + o_roff);
        int* cursor     = (int*)(wsb + o_cur);
        int* perm       = (int*)(wsb + o_perm);
        int* sdst       = (int*)(wsb + o_sdst);
        ushort_t* m_srt = (ushort_t*)(wsb + o_m);

        hipMemsetAsync(cnt, 0, (size_t)Nn * 4, stream);
        repack_kernel<<<dim3((rp_elems + 255) / 256), dim3(256), 0, stream>>>(Wm1, Wm2, W1p, W2p);
        const int n8 = Nn * D / 8;
        fconv_kernel<<<dim3((n8 + 255) / 256), dim3(256), 0, stream>>>(f, fbf, n8);
        hist_kernel<<<dim3((E + 255) / 256), dim3(256), 0, stream>>>(dst, cnt, E);
        scan_kernel<<<dim3(1), dim3(1024), 0, stream>>>(cnt, roff, cursor, Nn);
        scatter_kernel<<<dim3((E + 255) / 256), dim3(256), 0, stream>>>(dst, cursor, perm, sdst, E);
        edge_mfma_sorted_kernel<<<dim3((E + EB - 1) / EB), dim3(NT), 0, stream>>>(
            fbf, x, w, src, perm, sdst, W1p, bm1, W2p, bm2, m_srt, E);
        node_csr_kernel<<<dim3((Nn + NB - 1) / NB), dim3(NT), 0, stream>>>(
            f, m_srt, roff, cnt, Wu1, bu1, Wu2, bu2, (float*)d_out, Nn);
        return;
    }

    // ---------------- fallback: r6 pk-atomic path ----------------
    size_t off2 = 0;
    const size_t p_w  = off2; off2 = align512(off2 + wbytes);
    const size_t p_fb = off2; off2 = align512(off2 + fb_bytes);
    const size_t p_ms = off2; off2 = align512(off2 + (size_t)Nn * D * 2);
    if (ws_size >= off2) {
        ushort_t* W1p  = (ushort_t*)(wsb + p_w);
        ushort_t* W2p  = W1p + 128 * KP1;
        ushort_t* fbf  = (ushort_t*)(wsb + p_fb);
        ushort_t* msum = (ushort_t*)(wsb + p_ms);
        hipMemsetAsync(msum, 0, (size_t)Nn * D * 2, stream);
        repack_kernel<<<dim3((rp_elems + 255) / 256), dim3(256), 0, stream>>>(Wm1, Wm2, W1p, W2p);
        const int n8 = Nn * D / 8;
        fconv_kernel<<<dim3((n8 + 255) / 256), dim3(256), 0, stream>>>(f, fbf, n8);
        edge_mfma_kernel<<<dim3((E + EB - 1) / EB), dim3(NT), 0, stream>>>(
            fbf, x, w, src, dst, W1p, bm1, W2p, bm2, msum, E);
        node_kernel<true><<<dim3((Nn + NB - 1) / NB), dim3(NT), 0, stream>>>(
            f, msum, Wu1, bu1, Wu2, bu2, (float*)d_out, Nn);
        return;
    }

    // ---------------- last resort: fp32 atomics, msum in d_out ----------------
    {
        ushort_t* W1p  = (ushort_t*)wsb;          // requires ws >= wbytes (always true in practice)
        ushort_t* W2p  = W1p + 128 * KP1;
        float* msum    = (float*)d_out;
        hipMemsetAsync(msum, 0, (size_t)Nn * D * 4, stream);
        repack_kernel<<<dim3((rp_elems + 255) / 256), dim3(256), 0, stream>>>(Wm1, Wm2, W1p, W2p);
        edge_mfma_kernel_fa<<<dim3((E + EB - 1) / EB), dim3(NT), 0, stream>>>(
            f, x, w, src, dst, W1p, bm1, W2p, bm2, msum, E);
        node_kernel<false><<<dim3((Nn + NB - 1) / NB), dim3(NT), 0, stream>>>(
            f, msum, Wu1, bu1, Wu2, bu2, (float*)d_out, Nn);
    }
}

// Round 8
// 533.173 us; speedup vs baseline: 1.0772x; 1.0772x over previous
//
#include <hip/hip_runtime.h>

#define D 128
#define HD 128
#define DE 16
#define MSG_IN 273
#define EB 64        // edges per block (mfma path)
#define NT 256
#define KP1 288      // padded msg K = 9 chunks of 32
#define NCH1 9
#define NCH2 4
#define NB 32
#define MSG_PAD 276  // fp32 fallback kernel
#define HID_PAD 132
#define CH8 (4 * EB * 64)   // ushort offset of chunk-8 region in lds[]

typedef __attribute__((ext_vector_type(8))) short short8v;
typedef __attribute__((ext_vector_type(4))) float f32x4;
typedef unsigned short ushort_t;

#define GLOAD_LDS16(gp, lp) \
    __builtin_amdgcn_global_load_lds((const __attribute__((address_space(1))) unsigned int*)(gp), \
                                     (__attribute__((address_space(3))) unsigned int*)(lp), 16, 0, 0)

__device__ __forceinline__ unsigned short f2bf(float v) {
    unsigned int u = __builtin_bit_cast(unsigned int, v);
    u += 0x7fffu + ((u >> 16) & 1u);
    return (unsigned short)(u >> 16);
}
__device__ __forceinline__ float bf2f(ushort_t u) {
    return __builtin_bit_cast(float, (unsigned int)u << 16);
}

// ---------------- weight repack: fp32 [K][N] -> bf16 transposed [N][Kpad] ----------------
__global__ void repack_kernel(const float* __restrict__ Wm1, const float* __restrict__ Wm2,
                              ushort_t* __restrict__ W1p, ushort_t* __restrict__ W2p) {
    int idx = blockIdx.x * 256 + threadIdx.x;
    const int n1 = 128 * KP1;
    if (idx < n1) {
        int n = idx / KP1, k = idx % KP1;
        float v = (k < MSG_IN) ? Wm1[(size_t)k * HD + n] : 0.f;
        W1p[idx] = f2bf(v);
    } else {
        int i2 = idx - n1;
        if (i2 < HD * D) {
            int n = i2 / HD, k = i2 % HD;
            W2p[i2] = f2bf(Wm2[(size_t)k * D + n]);
        }
    }
}

// ---------------- f -> bf16 pre-conversion ----------------
__global__ void fconv_kernel(const float* __restrict__ f, ushort_t* __restrict__ fb, int n8) {
    int i = blockIdx.x * 256 + threadIdx.x;
    if (i < n8) {
        float4 v0 = *(const float4*)(f + (size_t)i * 8);
        float4 v1 = *(const float4*)(f + (size_t)i * 8 + 4);
        union { ushort_t us[8]; short8v v; } pk;
        pk.us[0] = f2bf(v0.x); pk.us[1] = f2bf(v0.y);
        pk.us[2] = f2bf(v0.z); pk.us[3] = f2bf(v0.w);
        pk.us[4] = f2bf(v1.x); pk.us[5] = f2bf(v1.y);
        pk.us[6] = f2bf(v1.z); pk.us[7] = f2bf(v1.w);
        *(short8v*)(fb + (size_t)i * 8) = pk.v;
    }
}

// ---------------- CSR build: hist -> parallel scan -> scatter ----------------
__global__ void hist_kernel(const int* __restrict__ dst, int* __restrict__ cnt, int E) {
    int i = blockIdx.x * 256 + threadIdx.x;
    if (i < E) atomicAdd(&cnt[dst[i]], 1);
}

// 1 block x 1024 threads: exclusive scan of cnt -> roff AND cursor
__global__ __launch_bounds__(1024) void scan_kernel(const int* __restrict__ cnt,
                                                    int* __restrict__ roff,
                                                    int* __restrict__ cursor, int Nn) {
    __shared__ int wsum[16];
    const int t = threadIdx.x, l = t & 63, wid = t >> 6;
    int running = 0;
    for (int base = 0; base < Nn; base += 1024) {
        const int i = base + t;
        const int v = (i < Nn) ? cnt[i] : 0;
        int s = v;
        #pragma unroll
        for (int off = 1; off < 64; off <<= 1) {
            int u = __shfl_up(s, off, 64);
            if (l >= off) s += u;
        }
        if (l == 63) wsum[wid] = s;
        __syncthreads();
        if (wid == 0 && l < 16) {
            int xv = wsum[l];
            #pragma unroll
            for (int off = 1; off < 16; off <<= 1) {
                int u = __shfl_up(xv, off, 64);
                if (l >= off) xv += u;
            }
            wsum[l] = xv;
        }
        __syncthreads();
        const int prev  = (wid > 0) ? wsum[wid - 1] : 0;
        const int total = wsum[15];
        if (i < Nn) {
            int ex = running + prev + s - v;
            roff[i] = ex; cursor[i] = ex;
        }
        running += total;
        __syncthreads();   // protect wsum before next iteration
    }
}

__global__ void scatter_kernel(const int* __restrict__ dst, int* cursor,
                               int* __restrict__ perm, int* __restrict__ sdst, int E) {
    int i = blockIdx.x * 256 + threadIdx.x;
    if (i < E) {
        int d = dst[i];
        int s = atomicAdd(&cursor[d], 1);
        perm[s] = i;
        sdst[s] = d;
    }
}

// ---------------- edge kernel v7: sorted slots, gload_lds staging, PLAIN stores ----------------
__global__ __launch_bounds__(NT, 4) void edge_mfma_sorted_kernel(
    const ushort_t* __restrict__ fbf, const float* __restrict__ x,
    const float* __restrict__ w, const int* __restrict__ src,
    const int* __restrict__ perm, const int* __restrict__ sdst,
    const ushort_t* __restrict__ W1p, const float* __restrict__ bm1,
    const ushort_t* __restrict__ W2p, const float* __restrict__ bm2,
    ushort_t* __restrict__ m_out, int E)
{
    __shared__ __align__(16) ushort_t lds[4 * EB * 64 + EB * 32];  // 36,864 B

    const int t    = threadIdx.x;
    const int lane = t & 63;
    const int wv   = t >> 6;
    const int e0   = blockIdx.x * EB;

    // ---- f staging: 8 x global_load_lds_dwordx4, pre-swizzled global source ----
    {
        const int el8 = lane >> 3;
        const int s   = lane & 7;
        const int sl  = s ^ el8;            // involution swizzle
        const int slA = min(e0 + wv * 16 + el8,     E - 1);
        const int slB = min(e0 + wv * 16 + 8 + el8, E - 1);
        const int geA = perm[slA], geB = perm[slB];
        const int nsA = src[geA], ndA = sdst[slA];
        const int nsB = src[geB], ndB = sdst[slB];
        #pragma unroll
        for (int p = 0; p < 4; ++p) {
            const int n0 = (p < 2) ? nsA : ndA;
            const int n1 = (p < 2) ? nsB : ndB;
            const ushort_t* g0 = fbf + (size_t)n0 * D + (p & 1) * 64 + sl * 8;
            const ushort_t* g1 = fbf + (size_t)n1 * D + (p & 1) * 64 + sl * 8;
            GLOAD_LDS16(g0, &lds[(p * EB + wv * 16    ) * 64]);
            GLOAD_LDS16(g1, &lds[(p * EB + wv * 16 + 8) * 64]);
        }
    }
    // ---- chunk 8: w feats (k0..15), sqd (k16), zeros; 2-bit swizzle ----
    {
        const int el = lane >> 2, q = lane & 3;
        const int qp = q ^ (el & 3);
        const int slot = e0 + wv * 16 + el;
        const bool ok = slot < E;
        const int sc = min(slot, E - 1);
        const int ge = perm[sc];
        union { ushort_t us[8]; short8v v; } pk;
        #pragma unroll
        for (int j = 0; j < 8; ++j) pk.us[j] = 0;
        if (ok) {
            if (q < 2) {
                float4 w0 = *(const float4*)(w + (size_t)ge * DE + q * 8);
                float4 w1 = *(const float4*)(w + (size_t)ge * DE + q * 8 + 4);
                pk.us[0] = f2bf(w0.x); pk.us[1] = f2bf(w0.y);
                pk.us[2] = f2bf(w0.z); pk.us[3] = f2bf(w0.w);
                pk.us[4] = f2bf(w1.x); pk.us[5] = f2bf(w1.y);
                pk.us[6] = f2bf(w1.z); pk.us[7] = f2bf(w1.w);
            } else if (q == 2) {
                const int ns = src[ge], nd = sdst[sc];
                float dx = x[ns*3+0] - x[nd*3+0];
                float dy = x[ns*3+1] - x[nd*3+1];
                float dz = x[ns*3+2] - x[nd*3+2];
                pk.us[0] = f2bf(dx*dx + dy*dy + dz*dz);
            }
        }
        *(short8v*)&lds[CH8 + (wv * 16 + el) * 32 + qp * 8] = pk.v;
    }

    const int col = lane & 15;
    const int g   = lane >> 4;

    const size_t wrow0 = (size_t)(wv * 32 + col) * KP1;
    const size_t wrow1 = (size_t)(wv * 32 + 16 + col) * KP1;
    short8v nb0 = *(const short8v*)&W1p[wrow0 + g * 8];
    short8v nb1 = *(const short8v*)&W1p[wrow1 + g * 8];

    __syncthreads();   // B0: staging complete

    // ---- layer 1: [64,288] x [288,32] per wave ----
    f32x4 acc[4][2];
    {
        float bv0 = bm1[wv * 32 + col];
        float bv1 = bm1[wv * 32 + 16 + col];
        #pragma unroll
        for (int rt = 0; rt < 4; ++rt) {
            acc[rt][0] = (f32x4){bv0, bv0, bv0, bv0};
            acc[rt][1] = (f32x4){bv1, bv1, bv1, bv1};
        }
    }
    #pragma unroll
    for (int c = 0; c < NCH1; ++c) {
        short8v b0 = nb0, b1 = nb1;
        if (c + 1 < NCH1) {
            nb0 = *(const short8v*)&W1p[wrow0 + (c + 1) * 32 + g * 8];
            nb1 = *(const short8v*)&W1p[wrow1 + (c + 1) * 32 + g * 8];
        }
        short8v a[4];
        #pragma unroll
        for (int rt = 0; rt < 4; ++rt) {
            const int row = rt * 16 + col;
            if (c < 8) {
                const int sP = (((c & 1) << 2) + g) ^ (row & 7);
                a[rt] = *(const short8v*)&lds[((c >> 1) * EB + row) * 64 + sP * 8];
            } else {
                const int sP = g ^ (row & 3);
                a[rt] = *(const short8v*)&lds[CH8 + row * 32 + sP * 8];
            }
        }
        #pragma unroll
        for (int rt = 0; rt < 4; ++rt) {
            acc[rt][0] = __builtin_amdgcn_mfma_f32_16x16x32_bf16(a[rt], b0, acc[rt][0], 0, 0, 0);
            acc[rt][1] = __builtin_amdgcn_mfma_f32_16x16x32_bf16(a[rt], b1, acc[rt][1], 0, 0, 0);
        }
    }
    __syncthreads();   // B1

    // hid (relu, bf16, pair-packed b32) -> pairs 0-1 region, same swizzle
    const bool even = (col & 1) == 0;
    const int ph = wv >> 1;
    #pragma unroll
    for (int rt = 0; rt < 4; ++rt)
        #pragma unroll
        for (int j = 0; j < 2; ++j)
            #pragma unroll
            for (int r = 0; r < 4; ++r) {
                const int row = rt * 16 + g * 4 + r;
                float v  = fmaxf(acc[rt][j][r], 0.f);
                float vn = __shfl_xor(v, 1, 64);
                if (even) {
                    unsigned int pk2 = (unsigned)f2bf(v) | ((unsigned)f2bf(vn) << 16);
                    const int sH = (((wv & 1) << 2) + j * 2 + (col >> 3)) ^ (row & 7);
                    *(unsigned int*)&lds[(ph * EB + row) * 64 + sH * 8 + (col & 7)] = pk2;
                }
            }
    __syncthreads();   // B2

    // ---- layer 2: [64,128] x [128,32] per wave ----
    const size_t w2r0 = (size_t)(wv * 32 + col) * HD;
    const size_t w2r1 = (size_t)(wv * 32 + 16 + col) * HD;
    short8v m0 = *(const short8v*)&W2p[w2r0 + g * 8];
    short8v m1 = *(const short8v*)&W2p[w2r1 + g * 8];
    f32x4 acc2[4][2];
    {
        float bv0 = bm2[wv * 32 + col];
        float bv1 = bm2[wv * 32 + 16 + col];
        #pragma unroll
        for (int rt = 0; rt < 4; ++rt) {
            acc2[rt][0] = (f32x4){bv0, bv0, bv0, bv0};
            acc2[rt][1] = (f32x4){bv1, bv1, bv1, bv1};
        }
    }
    #pragma unroll
    for (int c = 0; c < NCH2; ++c) {
        short8v b0 = m0, b1 = m1;
        if (c + 1 < NCH2) {
            m0 = *(const short8v*)&W2p[w2r0 + (c + 1) * 32 + g * 8];
            m1 = *(const short8v*)&W2p[w2r1 + (c + 1) * 32 + g * 8];
        }
        short8v a[4];
        #pragma unroll
        for (int rt = 0; rt < 4; ++rt) {
            const int row = rt * 16 + col;
            const int sP = (((c & 1) << 2) + g) ^ (row & 7);
            a[rt] = *(const short8v*)&lds[((c >> 1) * EB + row) * 64 + sP * 8];
        }
        #pragma unroll
        for (int rt = 0; rt < 4; ++rt) {
            acc2[rt][0] = __builtin_amdgcn_mfma_f32_16x16x32_bf16(a[rt], b0, acc2[rt][0], 0, 0, 0);
            acc2[rt][1] = __builtin_amdgcn_mfma_f32_16x16x32_bf16(a[rt], b1, acc2[rt][1], 0, 0, 0);
        }
    }

    // ---- plain coalesced stores of m_sorted rows (no atomics) ----
    #pragma unroll
    for (int rt = 0; rt < 4; ++rt)
        #pragma unroll
        for (int r = 0; r < 4; ++r) {
            const int sl   = rt * 16 + g * 4 + r;
            const int slot = e0 + sl;
            #pragma unroll
            for (int j = 0; j < 2; ++j) {
                float v  = acc2[rt][j][r];
                float vn = __shfl_xor(v, 1, 64);
                if (even && slot < E) {
                    unsigned int pk2 = (unsigned)f2bf(v) | ((unsigned)f2bf(vn) << 16);
                    *(unsigned int*)&m_out[(size_t)slot * D + wv * 32 + j * 16 + col] = pk2;
                }
            }
        }
}

// ---------------- node kernel v8: latency-hidden CSR segment-reduce + update MLP ----------------
// Reduce: 8B loads (4 cols/lane, 32 lanes/row, half-waves on even/odd rows),
// TWO nodes in flight per wave for ILP; cross-half combine via shfl_xor(32).
__global__ __launch_bounds__(NT, 2) void node_csr_kernel(
    const float* __restrict__ f, const ushort_t* __restrict__ m_sorted,
    const int* __restrict__ roff, const int* __restrict__ cnt,
    const float* __restrict__ Wu1, const float* __restrict__ bu1,
    const float* __restrict__ Wu2, const float* __restrict__ bu2,
    float* out, int Nn)
{
    __shared__ __align__(16) float hin[NB][HID_PAD];
    __shared__ __align__(16) float hid[NB][HID_PAD];
    const int t    = threadIdx.x;
    const int lane = t & 63;
    const int wv   = t >> 6;
    const int n0   = blockIdx.x * NB;
    const int nn   = min(NB, Nn - n0);

    {
        const int halfr = lane >> 5;        // row parity
        const int c4    = (lane & 31) * 4;  // col base (4 floats)
        for (int e = wv; e < nn; e += 8) {
            const int eB   = e + 4;
            const bool hb  = eB < nn;
            const int nA   = n0 + e;
            const int nBx  = n0 + (hb ? eB : e);
            const int begA = roff[nA], numA = cnt[nA];
            const int begB = roff[nBx];
            const int numB = hb ? cnt[nBx] : 0;
            float a0=0.f,a1=0.f,a2=0.f,a3=0.f;
            float b0=0.f,b1=0.f,b2=0.f,b3=0.f;
            const int mx = max(numA, numB);
            for (int i = halfr; i < mx; i += 2) {
                if (i < numA) {
                    uint2 pk = *(const uint2*)&m_sorted[(size_t)(begA + i) * D + c4];
                    a0 += bf2f((ushort_t)(pk.x & 0xffffu));
                    a1 += bf2f((ushort_t)(pk.x >> 16));
                    a2 += bf2f((ushort_t)(pk.y & 0xffffu));
                    a3 += bf2f((ushort_t)(pk.y >> 16));
                }
                if (i < numB) {
                    uint2 pk = *(const uint2*)&m_sorted[(size_t)(begB + i) * D + c4];
                    b0 += bf2f((ushort_t)(pk.x & 0xffffu));
                    b1 += bf2f((ushort_t)(pk.x >> 16));
                    b2 += bf2f((ushort_t)(pk.y & 0xffffu));
                    b3 += bf2f((ushort_t)(pk.y >> 16));
                }
            }
            a0 += __shfl_xor(a0, 32, 64); a1 += __shfl_xor(a1, 32, 64);
            a2 += __shfl_xor(a2, 32, 64); a3 += __shfl_xor(a3, 32, 64);
            b0 += __shfl_xor(b0, 32, 64); b1 += __shfl_xor(b1, 32, 64);
            b2 += __shfl_xor(b2, 32, 64); b3 += __shfl_xor(b3, 32, 64);
            if (halfr == 0) {
                float4 fv = *(const float4*)&f[(size_t)nA * D + c4];
                float4 o; o.x = a0+fv.x; o.y = a1+fv.y; o.z = a2+fv.z; o.w = a3+fv.w;
                *(float4*)&hin[e][c4] = o;
                if (hb) {
                    float4 fv2 = *(const float4*)&f[(size_t)nBx * D + c4];
                    float4 o2; o2.x = b0+fv2.x; o2.y = b1+fv2.y; o2.z = b2+fv2.z; o2.w = b3+fv2.w;
                    *(float4*)&hin[eB][c4] = o2;
                }
            }
        }
    }
    __syncthreads();

    const int tc = t & 15, te2 = (t >> 4) * 2, c0 = tc * 8;
    float a1m[2][8];
    #pragma unroll
    for (int c = 0; c < 8; ++c) { float bv = bu1[c0 + c]; a1m[0][c] = bv; a1m[1][c] = bv; }
    for (int i = 0; i < D; i += 4) {
        float m0[4], m1[4];
        *(float4*)m0 = *(const float4*)&hin[te2][i];
        *(float4*)m1 = *(const float4*)&hin[te2 + 1][i];
        #pragma unroll
        for (int r = 0; r < 4; ++r) {
            float wr[8];
            *(float4*)&wr[0] = *(const float4*)(Wu1 + (size_t)(i + r) * HD + c0);
            *(float4*)&wr[4] = *(const float4*)(Wu1 + (size_t)(i + r) * HD + c0 + 4);
            #pragma unroll
            for (int c = 0; c < 8; ++c) { a1m[0][c] += m0[r]*wr[c]; a1m[1][c] += m1[r]*wr[c]; }
        }
    }
    #pragma unroll
    for (int j = 0; j < 2; ++j) {
        float v[8];
        #pragma unroll
        for (int c = 0; c < 8; ++c) v[c] = fmaxf(a1m[j][c], 0.f);
        *(float4*)&hid[te2 + j][c0] = *(float4*)&v[0];
        *(float4*)&hid[te2 + j][c0 + 4] = *(float4*)&v[4];
    }
    __syncthreads();
    float a2m[2][8];
    #pragma unroll
    for (int c = 0; c < 8; ++c) { float bv = bu2[c0 + c]; a2m[0][c] = bv; a2m[1][c] = bv; }
    for (int h = 0; h < HD; h += 4) {
        float m0[4], m1[4];
        *(float4*)m0 = *(const float4*)&hid[te2][h];
        *(float4*)m1 = *(const float4*)&hid[te2 + 1][h];
        #pragma unroll
        for (int r = 0; r < 4; ++r) {
            float wr[8];
            *(float4*)&wr[0] = *(const float4*)(Wu2 + (size_t)(h + r) * D + c0);
            *(float4*)&wr[4] = *(const float4*)(Wu2 + (size_t)(h + r) * D + c0 + 4);
            #pragma unroll
            for (int c = 0; c < 8; ++c) { a2m[0][c] += m0[r]*wr[c]; a2m[1][c] += m1[r]*wr[c]; }
        }
    }
    #pragma unroll
    for (int j = 0; j < 2; ++j) {
        int e = te2 + j, gn = n0 + e;
        if (e < nn) {
            *(float4*)(out + (size_t)gn * D + c0) = *(float4*)&a2m[j][0];
            *(float4*)(out + (size_t)gn * D + c0 + 4) = *(float4*)&a2m[j][4];
        }
    }
}

// ================= fallback kernels =================

__global__ __launch_bounds__(NT, 4) void edge_mfma_kernel(
    const ushort_t* __restrict__ fbf, const float* __restrict__ x,
    const float* __restrict__ w, const int* __restrict__ src,
    const int* __restrict__ dst,
    const ushort_t* __restrict__ W1p, const float* __restrict__ bm1,
    const ushort_t* __restrict__ W2p, const float* __restrict__ bm2,
    ushort_t* msum, int E)
{
    __shared__ __align__(16) ushort_t lds[4 * EB * 64 + EB * 32];
    __shared__ int s_dst[EB];

    const int t    = threadIdx.x;
    const int lane = t & 63;
    const int wv   = t >> 6;
    const int e0   = blockIdx.x * EB;

    if (t < EB) s_dst[t] = (e0 + t < E) ? dst[e0 + t] : 0;
    {
        const int el8 = lane >> 3;
        const int s   = lane & 7;
        const int sl  = s ^ el8;
        const int geA = min(e0 + wv * 16 + el8,     E - 1);
        const int geB = min(e0 + wv * 16 + 8 + el8, E - 1);
        const int nsA = src[geA], ndA = dst[geA];
        const int nsB = src[geB], ndB = dst[geB];
        #pragma unroll
        for (int p = 0; p < 4; ++p) {
            const int n0 = (p < 2) ? nsA : ndA;
            const int n1 = (p < 2) ? nsB : ndB;
            const ushort_t* g0 = fbf + (size_t)n0 * D + (p & 1) * 64 + sl * 8;
            const ushort_t* g1 = fbf + (size_t)n1 * D + (p & 1) * 64 + sl * 8;
            GLOAD_LDS16(g0, &lds[(p * EB + wv * 16    ) * 64]);
            GLOAD_LDS16(g1, &lds[(p * EB + wv * 16 + 8) * 64]);
        }
    }
    {
        const int el = lane >> 2, q = lane & 3;
        const int qp = q ^ (el & 3);
        const int ge = e0 + wv * 16 + el;
        const bool ok = ge < E;
        const int gc = min(ge, E - 1);
        union { ushort_t us[8]; short8v v; } pk;
        #pragma unroll
        for (int j = 0; j < 8; ++j) pk.us[j] = 0;
        if (ok) {
            if (q < 2) {
                float4 w0 = *(const float4*)(w + (size_t)gc * DE + q * 8);
                float4 w1 = *(const float4*)(w + (size_t)gc * DE + q * 8 + 4);
                pk.us[0] = f2bf(w0.x); pk.us[1] = f2bf(w0.y);
                pk.us[2] = f2bf(w0.z); pk.us[3] = f2bf(w0.w);
                pk.us[4] = f2bf(w1.x); pk.us[5] = f2bf(w1.y);
                pk.us[6] = f2bf(w1.z); pk.us[7] = f2bf(w1.w);
            } else if (q == 2) {
                const int ns = src[gc], nd = dst[gc];
                float dx = x[ns*3+0] - x[nd*3+0];
                float dy = x[ns*3+1] - x[nd*3+1];
                float dz = x[ns*3+2] - x[nd*3+2];
                pk.us[0] = f2bf(dx*dx + dy*dy + dz*dz);
            }
        }
        *(short8v*)&lds[CH8 + (wv * 16 + el) * 32 + qp * 8] = pk.v;
    }

    const int col = lane & 15;
    const int g   = lane >> 4;
    const size_t wrow0 = (size_t)(wv * 32 + col) * KP1;
    const size_t wrow1 = (size_t)(wv * 32 + 16 + col) * KP1;
    short8v nb0 = *(const short8v*)&W1p[wrow0 + g * 8];
    short8v nb1 = *(const short8v*)&W1p[wrow1 + g * 8];
    __syncthreads();

    f32x4 acc[4][2];
    {
        float bv0 = bm1[wv * 32 + col];
        float bv1 = bm1[wv * 32 + 16 + col];
        #pragma unroll
        for (int rt = 0; rt < 4; ++rt) {
            acc[rt][0] = (f32x4){bv0, bv0, bv0, bv0};
            acc[rt][1] = (f32x4){bv1, bv1, bv1, bv1};
        }
    }
    #pragma unroll
    for (int c = 0; c < NCH1; ++c) {
        short8v b0 = nb0, b1 = nb1;
        if (c + 1 < NCH1) {
            nb0 = *(const short8v*)&W1p[wrow0 + (c + 1) * 32 + g * 8];
            nb1 = *(const short8v*)&W1p[wrow1 + (c + 1) * 32 + g * 8];
        }
        short8v a[4];
        #pragma unroll
        for (int rt = 0; rt < 4; ++rt) {
            const int row = rt * 16 + col;
            if (c < 8) {
                const int sP = (((c & 1) << 2) + g) ^ (row & 7);
                a[rt] = *(const short8v*)&lds[((c >> 1) * EB + row) * 64 + sP * 8];
            } else {
                const int sP = g ^ (row & 3);
                a[rt] = *(const short8v*)&lds[CH8 + row * 32 + sP * 8];
            }
        }
        #pragma unroll
        for (int rt = 0; rt < 4; ++rt) {
            acc[rt][0] = __builtin_amdgcn_mfma_f32_16x16x32_bf16(a[rt], b0, acc[rt][0], 0, 0, 0);
            acc[rt][1] = __builtin_amdgcn_mfma_f32_16x16x32_bf16(a[rt], b1, acc[rt][1], 0, 0, 0);
        }
    }
    __syncthreads();

    const bool even = (col & 1) == 0;
    const int ph = wv >> 1;
    #pragma unroll
    for (int rt = 0; rt < 4; ++rt)
        #pragma unroll
        for (int j = 0; j < 2; ++j)
            #pragma unroll
            for (int r = 0; r < 4; ++r) {
                const int row = rt * 16 + g * 4 + r;
                float v  = fmaxf(acc[rt][j][r], 0.f);
                float vn = __shfl_xor(v, 1, 64);
                if (even) {
                    unsigned int pk2 = (unsigned)f2bf(v) | ((unsigned)f2bf(vn) << 16);
                    const int sH = (((wv & 1) << 2) + j * 2 + (col >> 3)) ^ (row & 7);
                    *(unsigned int*)&lds[(ph * EB + row) * 64 + sH * 8 + (col & 7)] = pk2;
                }
            }
    __syncthreads();

    const size_t w2r0 = (size_t)(wv * 32 + col) * HD;
    const size_t w2r1 = (size_t)(wv * 32 + 16 + col) * HD;
    short8v m0 = *(const short8v*)&W2p[w2r0 + g * 8];
    short8v m1 = *(const short8v*)&W2p[w2r1 + g * 8];
    f32x4 acc2[4][2];
    {
        float bv0 = bm2[wv * 32 + col];
        float bv1 = bm2[wv * 32 + 16 + col];
        #pragma unroll
        for (int rt = 0; rt < 4; ++rt) {
            acc2[rt][0] = (f32x4){bv0, bv0, bv0, bv0};
            acc2[rt][1] = (f32x4){bv1, bv1, bv1, bv1};
        }
    }
    #pragma unroll
    for (int c = 0; c < NCH2; ++c) {
        short8v b0 = m0, b1 = m1;
        if (c + 1 < NCH2) {
            m0 = *(const short8v*)&W2p[w2r0 + (c + 1) * 32 + g * 8];
            m1 = *(const short8v*)&W2p[w2r1 + (c + 1) * 32 + g * 8];
        }
        short8v a[4];
        #pragma unroll
        for (int rt = 0; rt < 4; ++rt) {
            const int row = rt * 16 + col;
            const int sP = (((c & 1) << 2) + g) ^ (row & 7);
            a[rt] = *(const short8v*)&lds[((c >> 1) * EB + row) * 64 + sP * 8];
        }
        #pragma unroll
        for (int rt = 0; rt < 4; ++rt) {
            acc2[rt][0] = __builtin_amdgcn_mfma_f32_16x16x32_bf16(a[rt], b0, acc2[rt][0], 0, 0, 0);
            acc2[rt][1] = __builtin_amdgcn_mfma_f32_16x16x32_bf16(a[rt], b1, acc2[rt][1], 0, 0, 0);
        }
    }

    #pragma unroll
    for (int rt = 0; rt < 4; ++rt)
        #pragma unroll
        for (int r = 0; r < 4; ++r) {
            const int e  = rt * 16 + g * 4 + r;
            const int ge = e0 + e;
            const int dg = s_dst[e];
            #pragma unroll
            for (int j = 0; j < 2; ++j) {
                float v  = acc2[rt][j][r];
                float vn = __shfl_xor(v, 1, 64);
                if (even && ge < E) {
                    unsigned int pk2 = (unsigned)f2bf(v) | ((unsigned)f2bf(vn) << 16);
                    ushort_t* p = msum + (size_t)dg * D + wv * 32 + j * 16 + col;
                    asm volatile("global_atomic_pk_add_bf16 %0, %1, off"
                                 :: "v"(p), "v"(pk2) : "memory");
                }
            }
        }
}

template<bool MB16>
__global__ __launch_bounds__(NT, 2) void node_kernel(
    const float* __restrict__ f, const void* __restrict__ msum_v,
    const float* __restrict__ Wu1, const float* __restrict__ bu1,
    const float* __restrict__ Wu2, const float* __restrict__ bu2,
    float* out, int Nn)
{
    __shared__ __align__(16) float hin[NB][HID_PAD];
    __shared__ __align__(16) float hid[NB][HID_PAD];
    const int t  = threadIdx.x;
    const int n0 = blockIdx.x * NB;
    const int nn = min(NB, Nn - n0);

    {
        const int half = t >> 7, tt = t & 127;
        for (int e = half; e < nn; e += 2) {
            size_t off = (size_t)(n0 + e) * D + tt;
            float mv = MB16 ? bf2f(((const ushort_t*)msum_v)[off])
                            : ((const float*)msum_v)[off];
            hin[e][tt] = mv + f[off];
        }
    }
    __syncthreads();

    const int tc = t & 15, te2 = (t >> 4) * 2, c0 = tc * 8;
    float a1[2][8];
    #pragma unroll
    for (int c = 0; c < 8; ++c) { float bv = bu1[c0 + c]; a1[0][c] = bv; a1[1][c] = bv; }
    for (int i = 0; i < D; i += 4) {
        float m0[4], m1[4];
        *(float4*)m0 = *(const float4*)&hin[te2][i];
        *(float4*)m1 = *(const float4*)&hin[te2 + 1][i];
        #pragma unroll
        for (int r = 0; r < 4; ++r) {
            float wr[8];
            *(float4*)&wr[0] = *(const float4*)(Wu1 + (size_t)(i + r) * HD + c0);
            *(float4*)&wr[4] = *(const float4*)(Wu1 + (size_t)(i + r) * HD + c0 + 4);
            #pragma unroll
            for (int c = 0; c < 8; ++c) { a1[0][c] += m0[r]*wr[c]; a1[1][c] += m1[r]*wr[c]; }
        }
    }
    #pragma unroll
    for (int j = 0; j < 2; ++j) {
        float v[8];
        #pragma unroll
        for (int c = 0; c < 8; ++c) v[c] = fmaxf(a1[j][c], 0.f);
        *(float4*)&hid[te2 + j][c0] = *(float4*)&v[0];
        *(float4*)&hid[te2 + j][c0 + 4] = *(float4*)&v[4];
    }
    __syncthreads();
    float a2[2][8];
    #pragma unroll
    for (int c = 0; c < 8; ++c) { float bv = bu2[c0 + c]; a2[0][c] = bv; a2[1][c] = bv; }
    for (int h = 0; h < HD; h += 4) {
        float m0[4], m1[4];
        *(float4*)m0 = *(const float4*)&hid[te2][h];
        *(float4*)m1 = *(const float4*)&hid[te2 + 1][h];
        #pragma unroll
        for (int r = 0; r < 4; ++r) {
            float wr[8];
            *(float4*)&wr[0] = *(const float4*)(Wu2 + (size_t)(h + r) * D + c0);
            *(float4*)&wr[4] = *(const float4*)(Wu2 + (size_t)(h + r) * D + c0 + 4);
            #pragma unroll
            for (int c = 0; c < 8; ++c) { a2[0][c] += m0[r]*wr[c]; a2[1][c] += m1[r]*wr[c]; }
        }
    }
    #pragma unroll
    for (int j = 0; j < 2; ++j) {
        int e = te2 + j, gn = n0 + e;
        if (e < nn) {
            *(float4*)(out + (size_t)gn * D + c0) = *(float4*)&a2[j][0];
            *(float4*)(out + (size_t)gn * D + c0 + 4) = *(float4*)&a2[j][4];
        }
    }
}

__global__ __launch_bounds__(NT, 4) void edge_mfma_kernel_fa(
    const float* __restrict__ f, const float* __restrict__ x,
    const float* __restrict__ w, const int* __restrict__ src,
    const int* __restrict__ dst,
    const ushort_t* __restrict__ W1p, const float* __restrict__ bm1,
    const ushort_t* __restrict__ W2p, const float* __restrict__ bm2,
    float* msum, int E)
{
    __shared__ __align__(16) ushort_t msg_c[NCH1 * EB * 32];

    const int t    = threadIdx.x;
    const int lane = t & 63;
    const int wv   = t >> 6;
    const int e0   = blockIdx.x * EB;

    {
        const int el = lane >> 2;
        const int q  = lane & 3;
        const int ge = e0 + wv * 16 + el;
        const bool ok = ge < E;
        const int ns = ok ? src[ge] : 0;
        const int nd = ok ? dst[ge] : 0;
        const int mrow = wv * 16 + el;
        #pragma unroll
        for (int i = 0; i < 8; ++i) {
            const int k0 = i * 32 + q * 8;
            union { unsigned short us[8]; short8v v; } pk;
            if (ok) {
                const float* base = (k0 < D) ? (f + (size_t)ns * D + k0)
                                             : (f + (size_t)nd * D + (k0 - D));
                float4 v0 = *(const float4*)base;
                float4 v1 = *(const float4*)(base + 4);
                pk.us[0] = f2bf(v0.x); pk.us[1] = f2bf(v0.y);
                pk.us[2] = f2bf(v0.z); pk.us[3] = f2bf(v0.w);
                pk.us[4] = f2bf(v1.x); pk.us[5] = f2bf(v1.y);
                pk.us[6] = f2bf(v1.z); pk.us[7] = f2bf(v1.w);
            } else {
                #pragma unroll
                for (int j = 0; j < 8; ++j) pk.us[j] = 0;
            }
            *(short8v*)&msg_c[(i * EB + mrow) * 32 + q * 8] = pk.v;
        }
        {
            union { unsigned short us[8]; short8v v; } pk;
            #pragma unroll
            for (int j = 0; j < 8; ++j) pk.us[j] = 0;
            if (ok) {
                if (q < 2) {
                    float4 w0 = *(const float4*)(w + (size_t)ge * DE + q * 8);
                    float4 w1 = *(const float4*)(w + (size_t)ge * DE + q * 8 + 4);
                    pk.us[0] = f2bf(w0.x); pk.us[1] = f2bf(w0.y);
                    pk.us[2] = f2bf(w0.z); pk.us[3] = f2bf(w0.w);
                    pk.us[4] = f2bf(w1.x); pk.us[5] = f2bf(w1.y);
                    pk.us[6] = f2bf(w1.z); pk.us[7] = f2bf(w1.w);
                } else if (q == 2) {
                    float dx = x[ns*3+0] - x[nd*3+0];
                    float dy = x[ns*3+1] - x[nd*3+1];
                    float dz = x[ns*3+2] - x[nd*3+2];
                    pk.us[0] = f2bf(dx*dx + dy*dy + dz*dz);
                }
            }
            *(short8v*)&msg_c[(8 * EB + mrow) * 32 + q * 8] = pk.v;
        }
    }

    const int col  = lane & 15;
    const int g    = lane >> 4;
    const int erow = wv * 16 + col;

    f32x4 acc[8];
    #pragma unroll
    for (int ct = 0; ct < 8; ++ct) {
        float bv = bm1[ct * 16 + col];
        acc[ct] = (f32x4){bv, bv, bv, bv};
    }
    for (int c = 0; c < NCH1; ++c) {
        short8v a = *(const short8v*)&msg_c[(c * EB + erow) * 32 + g * 8];
        #pragma unroll
        for (int ct = 0; ct < 8; ++ct) {
            short8v b = *(const short8v*)&W1p[(size_t)(ct * 16 + col) * KP1 + c * 32 + g * 8];
            acc[ct] = __builtin_amdgcn_mfma_f32_16x16x32_bf16(a, b, acc[ct], 0, 0, 0);
        }
    }
    #pragma unroll
    for (int ct = 0; ct < 8; ++ct) {
        const int h  = ct * 16 + col;
        const int hc = h >> 5, hi = h & 31;
        #pragma unroll
        for (int r = 0; r < 4; ++r) {
            const int e = wv * 16 + g * 4 + r;
            msg_c[(hc * EB + e) * 32 + hi] = f2bf(fmaxf(acc[ct][r], 0.f));
        }
    }

    f32x4 acc2[8];
    #pragma unroll
    for (int ct = 0; ct < 8; ++ct) {
        float bv = bm2[ct * 16 + col];
        acc2[ct] = (f32x4){bv, bv, bv, bv};
    }
    for (int c = 0; c < NCH2; ++c) {
        short8v a = *(const short8v*)&msg_c[(c * EB + erow) * 32 + g * 8];
        #pragma unroll
        for (int ct = 0; ct < 8; ++ct) {
            short8v b = *(const short8v*)&W2p[(size_t)(ct * 16 + col) * HD + c * 32 + g * 8];
            acc2[ct] = __builtin_amdgcn_mfma_f32_16x16x32_bf16(a, b, acc2[ct], 0, 0, 0);
        }
    }

    #pragma unroll
    for (int r = 0; r < 4; ++r) {
        const int el = wv * 16 + g * 4 + r;
        const int ge = e0 + el;
        if (ge < E) {
            const int dg = dst[ge];
            float* p = msum + (size_t)dg * D + col;
            #pragma unroll
            for (int ct = 0; ct < 8; ++ct)
                atomicAdd(p + ct * 16, acc2[ct][r]);
        }
    }
}

extern "C" void kernel_launch(void* const* d_in, const int* in_sizes, int n_in,
                              void* d_out, int out_size, void* d_ws, size_t ws_size,
                              hipStream_t stream) {
    const float* f   = (const float*)d_in[0];
    const float* x   = (const float*)d_in[1];
    const float* w   = (const float*)d_in[2];
    const int*   src = (const int*)d_in[3];
    const int*   dst = (const int*)d_in[4];
    const float* Wm1 = (const float*)d_in[5];
    const float* bm1 = (const float*)d_in[6];
    const float* Wm2 = (const float*)d_in[7];
    const float* bm2 = (const float*)d_in[8];
    const float* Wu1 = (const float*)d_in[9];
    const float* bu1 = (const float*)d_in[10];
    const float* Wu2 = (const float*)d_in[11];
    const float* bu2 = (const float*)d_in[12];

    const int Nn = in_sizes[0] / D;
    const int E  = in_sizes[3];

    const size_t wbytes = (size_t)(128 * KP1 + HD * D) * sizeof(ushort_t);
    auto align512 = [](size_t v) { return (v + 511) & ~(size_t)511; };

    const size_t fb_bytes = (size_t)Nn * D * 2;
    char* wsb = (char*)d_ws;
    const int rp_elems = 128 * KP1 + HD * D;

    // ---------------- two-phase CSR layout ----------------
    size_t off = 0;
    const size_t o_w    = off; off = align512(off + wbytes);
    const size_t o_fb   = off; off = align512(off + fb_bytes);
    const size_t o_cnt  = off; off = align512(off + (size_t)Nn * 4);
    const size_t o_roff = off; off = align512(off + (size_t)Nn * 4);
    const size_t o_cur  = off; off = align512(off + (size_t)Nn * 4);
    const size_t o_perm = off; off = align512(off + (size_t)E * 4);
    const size_t o_sdst = off; off = align512(off + (size_t)E * 4);
    const size_t o_m    = off; off = align512(off + (size_t)E * D * 2);
    const size_t two_phase_total = off;

    if (ws_size >= two_phase_total) {
        ushort_t* W1p   = (ushort_t*)(wsb + o_w);
        ushort_t* W2p   = W1p + 128 * KP1;
        ushort_t* fbf   = (ushort_t*)(wsb + o_fb);
        int* cnt        = (int*)(wsb + o_cnt);
        int* roff       = (int*)(wsb + o_roff);
        int* cursor     = (int*)(wsb + o_cur);
        int* perm       = (int*)(wsb + o_perm);
        int* sdst       = (int*)(wsb + o_sdst);
        ushort_t* m_srt = (ushort_t*)(wsb + o_m);

        hipMemsetAsync(cnt, 0, (size_t)Nn * 4, stream);
        repack_kernel<<<dim3((rp_elems + 255) / 256), dim3(256), 0, stream>>>(Wm1, Wm2, W1p, W2p);
        const int n8 = Nn * D / 8;
        fconv_kernel<<<dim3((n8 + 255) / 256), dim3(256), 0, stream>>>(f, fbf, n8);
        hist_kernel<<<dim3((E + 255) / 256), dim3(256), 0, stream>>>(dst, cnt, E);
        scan_kernel<<<dim3(1), dim3(1024), 0, stream>>>(cnt, roff, cursor, Nn);
        scatter_kernel<<<dim3((E + 255) / 256), dim3(256), 0, stream>>>(dst, cursor, perm, sdst, E);
        edge_mfma_sorted_kernel<<<dim3((E + EB - 1) / EB), dim3(NT), 0, stream>>>(
            fbf, x, w, src, perm, sdst, W1p, bm1, W2p, bm2, m_srt, E);
        node_csr_kernel<<<dim3((Nn + NB - 1) / NB), dim3(NT), 0, stream>>>(
            f, m_srt, roff, cnt, Wu1, bu1, Wu2, bu2, (float*)d_out, Nn);
        return;
    }

    // ---------------- fallback: r6 pk-atomic path ----------------
    size_t off2 = 0;
    const size_t p_w  = off2; off2 = align512(off2 + wbytes);
    const size_t p_fb = off2; off2 = align512(off2 + fb_bytes);
    const size_t p_ms = off2; off2 = align512(off2 + (size_t)Nn * D * 2);
    if (ws_size >= off2) {
        ushort_t* W1p  = (ushort_t*)(wsb + p_w);
        ushort_t* W2p  = W1p + 128 * KP1;
        ushort_t* fbf  = (ushort_t*)(wsb + p_fb);
        ushort_t* msum = (ushort_t*)(wsb + p_ms);
        hipMemsetAsync(msum, 0, (size_t)Nn * D * 2, stream);
        repack_kernel<<<dim3((rp_elems + 255) / 256), dim3(256), 0, stream>>>(Wm1, Wm2, W1p, W2p);
        const int n8 = Nn * D / 8;
        fconv_kernel<<<dim3((n8 + 255) / 256), dim3(256), 0, stream>>>(f, fbf, n8);
        edge_mfma_kernel<<<dim3((E + EB - 1) / EB), dim3(NT), 0, stream>>>(
            fbf, x, w, src, dst, W1p, bm1, W2p, bm2, msum, E);
        node_kernel<true><<<dim3((Nn + NB - 1) / NB), dim3(NT), 0, stream>>>(
            f, msum, Wu1, bu1, Wu2, bu2, (float*)d_out, Nn);
        return;
    }

    // ---------------- last resort: fp32 atomics, msum in d_out ----------------
    {
        ushort_t* W1p  = (ushort_t*)wsb;
        ushort_t* W2p  = W1p + 128 * KP1;
        float* msum    = (float*)d_out;
        hipMemsetAsync(msum, 0, (size_t)Nn * D * 4, stream);
        repack_kernel<<<dim3((rp_elems + 255) / 256), dim3(256), 0, stream>>>(Wm1, Wm2, W1p, W2p);
        edge_mfma_kernel_fa<<<dim3((E + EB - 1) / EB), dim3(NT), 0, stream>>>(
            f, x, w, src, dst, W1p, bm1, W2p, bm2, msum, E);
        node_kernel<false><<<dim3((Nn + NB - 1) / NB), dim3(NT), 0, stream>>>(
            f, msum, Wu1, bu1, Wu2, bu2, (float*)d_out, Nn);
    }
}

// Round 9
// 504.626 us; speedup vs baseline: 1.1381x; 1.0566x over previous
//
#include <hip/hip_runtime.h>

#define D 128
#define HD 128
#define DE 16
#define MSG_IN 273
#define EB 64        // edges per block (mfma path)
#define NT 256
#define KP1 288      // padded msg K = 9 chunks of 32
#define NCH1 9
#define NCH2 4
#define NB 32
#define HID_PAD 132
#define CH8 (4 * EB * 64)   // ushort offset of chunk-8 region in lds[]

typedef __attribute__((ext_vector_type(8))) short short8v;
typedef __attribute__((ext_vector_type(4))) float f32x4;
typedef unsigned short ushort_t;

#define GLOAD_LDS16(gp, lp) \
    __builtin_amdgcn_global_load_lds((const __attribute__((address_space(1))) unsigned int*)(gp), \
                                     (__attribute__((address_space(3))) unsigned int*)(lp), 16, 0, 0)

__device__ __forceinline__ unsigned short f2bf(float v) {
    unsigned int u = __builtin_bit_cast(unsigned int, v);
    u += 0x7fffu + ((u >> 16) & 1u);
    return (unsigned short)(u >> 16);
}
__device__ __forceinline__ float bf2f(ushort_t u) {
    return __builtin_bit_cast(float, (unsigned int)u << 16);
}

// ---------------- weight repack: fp32 [K][N] -> bf16 transposed [N][Kpad] ----------------
__global__ void repack_kernel(const float* __restrict__ Wm1, const float* __restrict__ Wm2,
                              ushort_t* __restrict__ W1p, ushort_t* __restrict__ W2p) {
    int idx = blockIdx.x * 256 + threadIdx.x;
    const int n1 = 128 * KP1;
    if (idx < n1) {
        int n = idx / KP1, k = idx % KP1;
        float v = (k < MSG_IN) ? Wm1[(size_t)k * HD + n] : 0.f;
        W1p[idx] = f2bf(v);
    } else {
        int i2 = idx - n1;
        if (i2 < HD * D) {
            int n = i2 / HD, k = i2 % HD;
            W2p[i2] = f2bf(Wm2[(size_t)k * D + n]);
        }
    }
}

// ---------------- f -> bf16 pre-conversion ----------------
__global__ void fconv_kernel(const float* __restrict__ f, ushort_t* __restrict__ fb, int n8) {
    int i = blockIdx.x * 256 + threadIdx.x;
    if (i < n8) {
        float4 v0 = *(const float4*)(f + (size_t)i * 8);
        float4 v1 = *(const float4*)(f + (size_t)i * 8 + 4);
        union { ushort_t us[8]; short8v v; } pk;
        pk.us[0] = f2bf(v0.x); pk.us[1] = f2bf(v0.y);
        pk.us[2] = f2bf(v0.z); pk.us[3] = f2bf(v0.w);
        pk.us[4] = f2bf(v1.x); pk.us[5] = f2bf(v1.y);
        pk.us[6] = f2bf(v1.z); pk.us[7] = f2bf(v1.w);
        *(short8v*)(fb + (size_t)i * 8) = pk.v;
    }
}

// ---------------- CSR build: hist -> parallel scan -> scatter ----------------
__global__ void hist_kernel(const int* __restrict__ dst, int* __restrict__ cnt, int E) {
    int i = blockIdx.x * 256 + threadIdx.x;
    if (i < E) atomicAdd(&cnt[dst[i]], 1);
}

__global__ __launch_bounds__(1024) void scan_kernel(const int* __restrict__ cnt,
                                                    int* __restrict__ roff,
                                                    int* __restrict__ cursor, int Nn) {
    __shared__ int wsum[16];
    const int t = threadIdx.x, l = t & 63, wid = t >> 6;
    int running = 0;
    for (int base = 0; base < Nn; base += 1024) {
        const int i = base + t;
        const int v = (i < Nn) ? cnt[i] : 0;
        int s = v;
        #pragma unroll
        for (int off = 1; off < 64; off <<= 1) {
            int u = __shfl_up(s, off, 64);
            if (l >= off) s += u;
        }
        if (l == 63) wsum[wid] = s;
        __syncthreads();
        if (wid == 0 && l < 16) {
            int xv = wsum[l];
            #pragma unroll
            for (int off = 1; off < 16; off <<= 1) {
                int u = __shfl_up(xv, off, 64);
                if (l >= off) xv += u;
            }
            wsum[l] = xv;
        }
        __syncthreads();
        const int prev  = (wid > 0) ? wsum[wid - 1] : 0;
        const int total = wsum[15];
        if (i < Nn) {
            int ex = running + prev + s - v;
            roff[i] = ex; cursor[i] = ex;
        }
        running += total;
        __syncthreads();
    }
}

__global__ void scatter_kernel(const int* __restrict__ dst, int* cursor,
                               int* __restrict__ perm, int* __restrict__ sdst, int E) {
    int i = blockIdx.x * 256 + threadIdx.x;
    if (i < E) {
        int d = dst[i];
        int s = atomicAdd(&cursor[d], 1);
        perm[s] = i;
        sdst[s] = d;
    }
}

// ---------------- edge kernel: sorted slots, gload_lds staging, PLAIN stores ----------------
__global__ __launch_bounds__(NT, 4) void edge_mfma_sorted_kernel(
    const ushort_t* __restrict__ fbf, const float* __restrict__ x,
    const float* __restrict__ w, const int* __restrict__ src,
    const int* __restrict__ perm, const int* __restrict__ sdst,
    const ushort_t* __restrict__ W1p, const float* __restrict__ bm1,
    const ushort_t* __restrict__ W2p, const float* __restrict__ bm2,
    ushort_t* __restrict__ m_out, int E)
{
    __shared__ __align__(16) ushort_t lds[4 * EB * 64 + EB * 32];  // 36,864 B

    const int t    = threadIdx.x;
    const int lane = t & 63;
    const int wv   = t >> 6;
    const int e0   = blockIdx.x * EB;

    // ---- f staging: 8 x global_load_lds_dwordx4, pre-swizzled global source ----
    {
        const int el8 = lane >> 3;
        const int s   = lane & 7;
        const int sl  = s ^ el8;            // involution swizzle
        const int slA = min(e0 + wv * 16 + el8,     E - 1);
        const int slB = min(e0 + wv * 16 + 8 + el8, E - 1);
        const int geA = perm[slA], geB = perm[slB];
        const int nsA = src[geA], ndA = sdst[slA];
        const int nsB = src[geB], ndB = sdst[slB];
        #pragma unroll
        for (int p = 0; p < 4; ++p) {
            const int n0 = (p < 2) ? nsA : ndA;
            const int n1 = (p < 2) ? nsB : ndB;
            const ushort_t* g0 = fbf + (size_t)n0 * D + (p & 1) * 64 + sl * 8;
            const ushort_t* g1 = fbf + (size_t)n1 * D + (p & 1) * 64 + sl * 8;
            GLOAD_LDS16(g0, &lds[(p * EB + wv * 16    ) * 64]);
            GLOAD_LDS16(g1, &lds[(p * EB + wv * 16 + 8) * 64]);
        }
    }
    // ---- chunk 8: w feats (k0..15), sqd (k16), zeros; 2-bit swizzle ----
    {
        const int el = lane >> 2, q = lane & 3;
        const int qp = q ^ (el & 3);
        const int slot = e0 + wv * 16 + el;
        const bool ok = slot < E;
        const int sc = min(slot, E - 1);
        const int ge = perm[sc];
        union { ushort_t us[8]; short8v v; } pk;
        #pragma unroll
        for (int j = 0; j < 8; ++j) pk.us[j] = 0;
        if (ok) {
            if (q < 2) {
                float4 w0 = *(const float4*)(w + (size_t)ge * DE + q * 8);
                float4 w1 = *(const float4*)(w + (size_t)ge * DE + q * 8 + 4);
                pk.us[0] = f2bf(w0.x); pk.us[1] = f2bf(w0.y);
                pk.us[2] = f2bf(w0.z); pk.us[3] = f2bf(w0.w);
                pk.us[4] = f2bf(w1.x); pk.us[5] = f2bf(w1.y);
                pk.us[6] = f2bf(w1.z); pk.us[7] = f2bf(w1.w);
            } else if (q == 2) {
                const int ns = src[ge], nd = sdst[sc];
                float dx = x[ns*3+0] - x[nd*3+0];
                float dy = x[ns*3+1] - x[nd*3+1];
                float dz = x[ns*3+2] - x[nd*3+2];
                pk.us[0] = f2bf(dx*dx + dy*dy + dz*dz);
            }
        }
        *(short8v*)&lds[CH8 + (wv * 16 + el) * 32 + qp * 8] = pk.v;
    }

    const int col = lane & 15;
    const int g   = lane >> 4;

    const size_t wrow0 = (size_t)(wv * 32 + col) * KP1;
    const size_t wrow1 = (size_t)(wv * 32 + 16 + col) * KP1;
    short8v nb0 = *(const short8v*)&W1p[wrow0 + g * 8];
    short8v nb1 = *(const short8v*)&W1p[wrow1 + g * 8];

    __syncthreads();   // B0: staging complete

    // ---- layer 1: [64,288] x [288,32] per wave ----
    f32x4 acc[4][2];
    {
        float bv0 = bm1[wv * 32 + col];
        float bv1 = bm1[wv * 32 + 16 + col];
        #pragma unroll
        for (int rt = 0; rt < 4; ++rt) {
            acc[rt][0] = (f32x4){bv0, bv0, bv0, bv0};
            acc[rt][1] = (f32x4){bv1, bv1, bv1, bv1};
        }
    }
    #pragma unroll
    for (int c = 0; c < NCH1; ++c) {
        short8v b0 = nb0, b1 = nb1;
        if (c + 1 < NCH1) {
            nb0 = *(const short8v*)&W1p[wrow0 + (c + 1) * 32 + g * 8];
            nb1 = *(const short8v*)&W1p[wrow1 + (c + 1) * 32 + g * 8];
        }
        short8v a[4];
        #pragma unroll
        for (int rt = 0; rt < 4; ++rt) {
            const int row = rt * 16 + col;
            if (c < 8) {
                const int sP = (((c & 1) << 2) + g) ^ (row & 7);
                a[rt] = *(const short8v*)&lds[((c >> 1) * EB + row) * 64 + sP * 8];
            } else {
                const int sP = g ^ (row & 3);
                a[rt] = *(const short8v*)&lds[CH8 + row * 32 + sP * 8];
            }
        }
        #pragma unroll
        for (int rt = 0; rt < 4; ++rt) {
            acc[rt][0] = __builtin_amdgcn_mfma_f32_16x16x32_bf16(a[rt], b0, acc[rt][0], 0, 0, 0);
            acc[rt][1] = __builtin_amdgcn_mfma_f32_16x16x32_bf16(a[rt], b1, acc[rt][1], 0, 0, 0);
        }
    }
    __syncthreads();   // B1

    // hid (relu, bf16, pair-packed b32) -> pairs 0-1 region, same swizzle
    const bool even = (col & 1) == 0;
    const int ph = wv >> 1;
    #pragma unroll
    for (int rt = 0; rt < 4; ++rt)
        #pragma unroll
        for (int j = 0; j < 2; ++j)
            #pragma unroll
            for (int r = 0; r < 4; ++r) {
                const int row = rt * 16 + g * 4 + r;
                float v  = fmaxf(acc[rt][j][r], 0.f);
                float vn = __shfl_xor(v, 1, 64);
                if (even) {
                    unsigned int pk2 = (unsigned)f2bf(v) | ((unsigned)f2bf(vn) << 16);
                    const int sH = (((wv & 1) << 2) + j * 2 + (col >> 3)) ^ (row & 7);
                    *(unsigned int*)&lds[(ph * EB + row) * 64 + sH * 8 + (col & 7)] = pk2;
                }
            }
    __syncthreads();   // B2

    // ---- layer 2: [64,128] x [128,32] per wave ----
    const size_t w2r0 = (size_t)(wv * 32 + col) * HD;
    const size_t w2r1 = (size_t)(wv * 32 + 16 + col) * HD;
    short8v m0 = *(const short8v*)&W2p[w2r0 + g * 8];
    short8v m1 = *(const short8v*)&W2p[w2r1 + g * 8];
    f32x4 acc2[4][2];
    {
        float bv0 = bm2[wv * 32 + col];
        float bv1 = bm2[wv * 32 + 16 + col];
        #pragma unroll
        for (int rt = 0; rt < 4; ++rt) {
            acc2[rt][0] = (f32x4){bv0, bv0, bv0, bv0};
            acc2[rt][1] = (f32x4){bv1, bv1, bv1, bv1};
        }
    }
    #pragma unroll
    for (int c = 0; c < NCH2; ++c) {
        short8v b0 = m0, b1 = m1;
        if (c + 1 < NCH2) {
            m0 = *(const short8v*)&W2p[w2r0 + (c + 1) * 32 + g * 8];
            m1 = *(const short8v*)&W2p[w2r1 + (c + 1) * 32 + g * 8];
        }
        short8v a[4];
        #pragma unroll
        for (int rt = 0; rt < 4; ++rt) {
            const int row = rt * 16 + col;
            const int sP = (((c & 1) << 2) + g) ^ (row & 7);
            a[rt] = *(const short8v*)&lds[((c >> 1) * EB + row) * 64 + sP * 8];
        }
        #pragma unroll
        for (int rt = 0; rt < 4; ++rt) {
            acc2[rt][0] = __builtin_amdgcn_mfma_f32_16x16x32_bf16(a[rt], b0, acc2[rt][0], 0, 0, 0);
            acc2[rt][1] = __builtin_amdgcn_mfma_f32_16x16x32_bf16(a[rt], b1, acc2[rt][1], 0, 0, 0);
        }
    }

    // ---- plain coalesced stores of m_sorted rows (no atomics) ----
    #pragma unroll
    for (int rt = 0; rt < 4; ++rt)
        #pragma unroll
        for (int r = 0; r < 4; ++r) {
            const int sl   = rt * 16 + g * 4 + r;
            const int slot = e0 + sl;
            #pragma unroll
            for (int j = 0; j < 2; ++j) {
                float v  = acc2[rt][j][r];
                float vn = __shfl_xor(v, 1, 64);
                if (even && slot < E) {
                    unsigned int pk2 = (unsigned)f2bf(v) | ((unsigned)f2bf(vn) << 16);
                    *(unsigned int*)&m_out[(size_t)slot * D + wv * 32 + j * 16 + col] = pk2;
                }
            }
        }
}

// ---------------- node kernel v9: 16B-load CSR segment-reduce + update MLP ----------------
// Reduce: uint4 loads (8 bf16 cols/lane, 16 lanes/row, 4 row-groups/wave),
// TWO nodes in flight per wave; combine via shfl_xor(16)+shfl_xor(32).
__global__ __launch_bounds__(NT, 4) void node_csr_kernel(
    const float* __restrict__ f, const ushort_t* __restrict__ m_sorted,
    const int* __restrict__ roff, const int* __restrict__ cnt,
    const float* __restrict__ Wu1, const float* __restrict__ bu1,
    const float* __restrict__ Wu2, const float* __restrict__ bu2,
    float* out, int Nn)
{
    __shared__ __align__(16) float hin[NB][HID_PAD];
    __shared__ __align__(16) float hid[NB][HID_PAD];
    const int t    = threadIdx.x;
    const int lane = t & 63;
    const int wv   = t >> 6;
    const int n0   = blockIdx.x * NB;
    const int nn   = min(NB, Nn - n0);

    {
        const int rg = lane >> 4;           // row-group 0..3
        const int c8 = (lane & 15) * 8;     // col base (8 bf16)
        for (int e = wv; e < nn; e += 8) {
            const int eB   = e + 4;
            const bool hb  = eB < nn;
            const int nA   = n0 + e;
            const int nBx  = n0 + (hb ? eB : e);
            const int begA = roff[nA], numA = cnt[nA];
            const int begB = roff[nBx];
            const int numB = hb ? cnt[nBx] : 0;
            float a0=0.f,a1=0.f,a2=0.f,a3=0.f,a4=0.f,a5=0.f,a6=0.f,a7=0.f;
            float b0=0.f,b1=0.f,b2=0.f,b3=0.f,b4=0.f,b5=0.f,b6=0.f,b7=0.f;
            const int mx = max(numA, numB);
            for (int i = rg; i < mx; i += 4) {
                if (i < numA) {
                    uint4 pk = *(const uint4*)&m_sorted[(size_t)(begA + i) * D + c8];
                    a0 += bf2f((ushort_t)(pk.x & 0xffffu)); a1 += bf2f((ushort_t)(pk.x >> 16));
                    a2 += bf2f((ushort_t)(pk.y & 0xffffu)); a3 += bf2f((ushort_t)(pk.y >> 16));
                    a4 += bf2f((ushort_t)(pk.z & 0xffffu)); a5 += bf2f((ushort_t)(pk.z >> 16));
                    a6 += bf2f((ushort_t)(pk.w & 0xffffu)); a7 += bf2f((ushort_t)(pk.w >> 16));
                }
                if (i < numB) {
                    uint4 pk = *(const uint4*)&m_sorted[(size_t)(begB + i) * D + c8];
                    b0 += bf2f((ushort_t)(pk.x & 0xffffu)); b1 += bf2f((ushort_t)(pk.x >> 16));
                    b2 += bf2f((ushort_t)(pk.y & 0xffffu)); b3 += bf2f((ushort_t)(pk.y >> 16));
                    b4 += bf2f((ushort_t)(pk.z & 0xffffu)); b5 += bf2f((ushort_t)(pk.z >> 16));
                    b6 += bf2f((ushort_t)(pk.w & 0xffffu)); b7 += bf2f((ushort_t)(pk.w >> 16));
                }
            }
            // combine the 4 row-groups
            #pragma unroll
            for (int s = 16; s <= 32; s <<= 1) {
                a0 += __shfl_xor(a0, s, 64); a1 += __shfl_xor(a1, s, 64);
                a2 += __shfl_xor(a2, s, 64); a3 += __shfl_xor(a3, s, 64);
                a4 += __shfl_xor(a4, s, 64); a5 += __shfl_xor(a5, s, 64);
                a6 += __shfl_xor(a6, s, 64); a7 += __shfl_xor(a7, s, 64);
                b0 += __shfl_xor(b0, s, 64); b1 += __shfl_xor(b1, s, 64);
                b2 += __shfl_xor(b2, s, 64); b3 += __shfl_xor(b3, s, 64);
                b4 += __shfl_xor(b4, s, 64); b5 += __shfl_xor(b5, s, 64);
                b6 += __shfl_xor(b6, s, 64); b7 += __shfl_xor(b7, s, 64);
            }
            if (rg == 0) {
                float4 f0 = *(const float4*)&f[(size_t)nA * D + c8];
                float4 f1 = *(const float4*)&f[(size_t)nA * D + c8 + 4];
                float4 o0 = {a0+f0.x, a1+f0.y, a2+f0.z, a3+f0.w};
                float4 o1 = {a4+f1.x, a5+f1.y, a6+f1.z, a7+f1.w};
                *(float4*)&hin[e][c8]     = o0;
                *(float4*)&hin[e][c8 + 4] = o1;
                if (hb) {
                    float4 g0 = *(const float4*)&f[(size_t)nBx * D + c8];
                    float4 g1 = *(const float4*)&f[(size_t)nBx * D + c8 + 4];
                    float4 p0 = {b0+g0.x, b1+g0.y, b2+g0.z, b3+g0.w};
                    float4 p1 = {b4+g1.x, b5+g1.y, b6+g1.z, b7+g1.w};
                    *(float4*)&hin[eB][c8]     = p0;
                    *(float4*)&hin[eB][c8 + 4] = p1;
                }
            }
        }
    }
    __syncthreads();

    const int tc = t & 15, te2 = (t >> 4) * 2, c0 = tc * 8;
    float a1m[2][8];
    #pragma unroll
    for (int c = 0; c < 8; ++c) { float bv = bu1[c0 + c]; a1m[0][c] = bv; a1m[1][c] = bv; }
    for (int i = 0; i < D; i += 4) {
        float m0[4], m1[4];
        *(float4*)m0 = *(const float4*)&hin[te2][i];
        *(float4*)m1 = *(const float4*)&hin[te2 + 1][i];
        #pragma unroll
        for (int r = 0; r < 4; ++r) {
            float wr[8];
            *(float4*)&wr[0] = *(const float4*)(Wu1 + (size_t)(i + r) * HD + c0);
            *(float4*)&wr[4] = *(const float4*)(Wu1 + (size_t)(i + r) * HD + c0 + 4);
            #pragma unroll
            for (int c = 0; c < 8; ++c) { a1m[0][c] += m0[r]*wr[c]; a1m[1][c] += m1[r]*wr[c]; }
        }
    }
    #pragma unroll
    for (int j = 0; j < 2; ++j) {
        float v[8];
        #pragma unroll
        for (int c = 0; c < 8; ++c) v[c] = fmaxf(a1m[j][c], 0.f);
        *(float4*)&hid[te2 + j][c0] = *(float4*)&v[0];
        *(float4*)&hid[te2 + j][c0 + 4] = *(float4*)&v[4];
    }
    __syncthreads();
    float a2m[2][8];
    #pragma unroll
    for (int c = 0; c < 8; ++c) { float bv = bu2[c0 + c]; a2m[0][c] = bv; a2m[1][c] = bv; }
    for (int h = 0; h < HD; h += 4) {
        float m0[4], m1[4];
        *(float4*)m0 = *(const float4*)&hid[te2][h];
        *(float4*)m1 = *(const float4*)&hid[te2 + 1][h];
        #pragma unroll
        for (int r = 0; r < 4; ++r) {
            float wr[8];
            *(float4*)&wr[0] = *(const float4*)(Wu2 + (size_t)(h + r) * D + c0);
            *(float4*)&wr[4] = *(const float4*)(Wu2 + (size_t)(h + r) * D + c0 + 4);
            #pragma unroll
            for (int c = 0; c < 8; ++c) { a2m[0][c] += m0[r]*wr[c]; a2m[1][c] += m1[r]*wr[c]; }
        }
    }
    #pragma unroll
    for (int j = 0; j < 2; ++j) {
        int e = te2 + j, gn = n0 + e;
        if (e < nn) {
            *(float4*)(out + (size_t)gn * D + c0) = *(float4*)&a2m[j][0];
            *(float4*)(out + (size_t)gn * D + c0 + 4) = *(float4*)&a2m[j][4];
        }
    }
}

// ================= fallback kernels =================

__global__ __launch_bounds__(NT, 4) void edge_mfma_kernel(
    const ushort_t* __restrict__ fbf, const float* __restrict__ x,
    const float* __restrict__ w, const int* __restrict__ src,
    const int* __restrict__ dst,
    const ushort_t* __restrict__ W1p, const float* __restrict__ bm1,
    const ushort_t* __restrict__ W2p, const float* __restrict__ bm2,
    ushort_t* msum, int E)
{
    __shared__ __align__(16) ushort_t lds[4 * EB * 64 + EB * 32];
    __shared__ int s_dst[EB];

    const int t    = threadIdx.x;
    const int lane = t & 63;
    const int wv   = t >> 6;
    const int e0   = blockIdx.x * EB;

    if (t < EB) s_dst[t] = (e0 + t < E) ? dst[e0 + t] : 0;
    {
        const int el8 = lane >> 3;
        const int s   = lane & 7;
        const int sl  = s ^ el8;
        const int geA = min(e0 + wv * 16 + el8,     E - 1);
        const int geB = min(e0 + wv * 16 + 8 + el8, E - 1);
        const int nsA = src[geA], ndA = dst[geA];
        const int nsB = src[geB], ndB = dst[geB];
        #pragma unroll
        for (int p = 0; p < 4; ++p) {
            const int n0 = (p < 2) ? nsA : ndA;
            const int n1 = (p < 2) ? nsB : ndB;
            const ushort_t* g0 = fbf + (size_t)n0 * D + (p & 1) * 64 + sl * 8;
            const ushort_t* g1 = fbf + (size_t)n1 * D + (p & 1) * 64 + sl * 8;
            GLOAD_LDS16(g0, &lds[(p * EB + wv * 16    ) * 64]);
            GLOAD_LDS16(g1, &lds[(p * EB + wv * 16 + 8) * 64]);
        }
    }
    {
        const int el = lane >> 2, q = lane & 3;
        const int qp = q ^ (el & 3);
        const int ge = e0 + wv * 16 + el;
        const bool ok = ge < E;
        const int gc = min(ge, E - 1);
        union { ushort_t us[8]; short8v v; } pk;
        #pragma unroll
        for (int j = 0; j < 8; ++j) pk.us[j] = 0;
        if (ok) {
            if (q < 2) {
                float4 w0 = *(const float4*)(w + (size_t)gc * DE + q * 8);
                float4 w1 = *(const float4*)(w + (size_t)gc * DE + q * 8 + 4);
                pk.us[0] = f2bf(w0.x); pk.us[1] = f2bf(w0.y);
                pk.us[2] = f2bf(w0.z); pk.us[3] = f2bf(w0.w);
                pk.us[4] = f2bf(w1.x); pk.us[5] = f2bf(w1.y);
                pk.us[6] = f2bf(w1.z); pk.us[7] = f2bf(w1.w);
            } else if (q == 2) {
                const int ns = src[gc], nd = dst[gc];
                float dx = x[ns*3+0] - x[nd*3+0];
                float dy = x[ns*3+1] - x[nd*3+1];
                float dz = x[ns*3+2] - x[nd*3+2];
                pk.us[0] = f2bf(dx*dx + dy*dy + dz*dz);
            }
        }
        *(short8v*)&lds[CH8 + (wv * 16 + el) * 32 + qp * 8] = pk.v;
    }

    const int col = lane & 15;
    const int g   = lane >> 4;
    const size_t wrow0 = (size_t)(wv * 32 + col) * KP1;
    const size_t wrow1 = (size_t)(wv * 32 + 16 + col) * KP1;
    short8v nb0 = *(const short8v*)&W1p[wrow0 + g * 8];
    short8v nb1 = *(const short8v*)&W1p[wrow1 + g * 8];
    __syncthreads();

    f32x4 acc[4][2];
    {
        float bv0 = bm1[wv * 32 + col];
        float bv1 = bm1[wv * 32 + 16 + col];
        #pragma unroll
        for (int rt = 0; rt < 4; ++rt) {
            acc[rt][0] = (f32x4){bv0, bv0, bv0, bv0};
            acc[rt][1] = (f32x4){bv1, bv1, bv1, bv1};
        }
    }
    #pragma unroll
    for (int c = 0; c < NCH1; ++c) {
        short8v b0 = nb0, b1 = nb1;
        if (c + 1 < NCH1) {
            nb0 = *(const short8v*)&W1p[wrow0 + (c + 1) * 32 + g * 8];
            nb1 = *(const short8v*)&W1p[wrow1 + (c + 1) * 32 + g * 8];
        }
        short8v a[4];
        #pragma unroll
        for (int rt = 0; rt < 4; ++rt) {
            const int row = rt * 16 + col;
            if (c < 8) {
                const int sP = (((c & 1) << 2) + g) ^ (row & 7);
                a[rt] = *(const short8v*)&lds[((c >> 1) * EB + row) * 64 + sP * 8];
            } else {
                const int sP = g ^ (row & 3);
                a[rt] = *(const short8v*)&lds[CH8 + row * 32 + sP * 8];
            }
        }
        #pragma unroll
        for (int rt = 0; rt < 4; ++rt) {
            acc[rt][0] = __builtin_amdgcn_mfma_f32_16x16x32_bf16(a[rt], b0, acc[rt][0], 0, 0, 0);
            acc[rt][1] = __builtin_amdgcn_mfma_f32_16x16x32_bf16(a[rt], b1, acc[rt][1], 0, 0, 0);
        }
    }
    __syncthreads();

    const bool even = (col & 1) == 0;
    const int ph = wv >> 1;
    #pragma unroll
    for (int rt = 0; rt < 4; ++rt)
        #pragma unroll
        for (int j = 0; j < 2; ++j)
            #pragma unroll
            for (int r = 0; r < 4; ++r) {
                const int row = rt * 16 + g * 4 + r;
                float v  = fmaxf(acc[rt][j][r], 0.f);
                float vn = __shfl_xor(v, 1, 64);
                if (even) {
                    unsigned int pk2 = (unsigned)f2bf(v) | ((unsigned)f2bf(vn) << 16);
                    const int sH = (((wv & 1) << 2) + j * 2 + (col >> 3)) ^ (row & 7);
                    *(unsigned int*)&lds[(ph * EB + row) * 64 + sH * 8 + (col & 7)] = pk2;
                }
            }
    __syncthreads();

    const size_t w2r0 = (size_t)(wv * 32 + col) * HD;
    const size_t w2r1 = (size_t)(wv * 32 + 16 + col) * HD;
    short8v m0 = *(const short8v*)&W2p[w2r0 + g * 8];
    short8v m1 = *(const short8v*)&W2p[w2r1 + g * 8];
    f32x4 acc2[4][2];
    {
        float bv0 = bm2[wv * 32 + col];
        float bv1 = bm2[wv * 32 + 16 + col];
        #pragma unroll
        for (int rt = 0; rt < 4; ++rt) {
            acc2[rt][0] = (f32x4){bv0, bv0, bv0, bv0};
            acc2[rt][1] = (f32x4){bv1, bv1, bv1, bv1};
        }
    }
    #pragma unroll
    for (int c = 0; c < NCH2; ++c) {
        short8v b0 = m0, b1 = m1;
        if (c + 1 < NCH2) {
            m0 = *(const short8v*)&W2p[w2r0 + (c + 1) * 32 + g * 8];
            m1 = *(const short8v*)&W2p[w2r1 + (c + 1) * 32 + g * 8];
        }
        short8v a[4];
        #pragma unroll
        for (int rt = 0; rt < 4; ++rt) {
            const int row = rt * 16 + col;
            const int sP = (((c & 1) << 2) + g) ^ (row & 7);
            a[rt] = *(const short8v*)&lds[((c >> 1) * EB + row) * 64 + sP * 8];
        }
        #pragma unroll
        for (int rt = 0; rt < 4; ++rt) {
            acc2[rt][0] = __builtin_amdgcn_mfma_f32_16x16x32_bf16(a[rt], b0, acc2[rt][0], 0, 0, 0);
            acc2[rt][1] = __builtin_amdgcn_mfma_f32_16x16x32_bf16(a[rt], b1, acc2[rt][1], 0, 0, 0);
        }
    }

    #pragma unroll
    for (int rt = 0; rt < 4; ++rt)
        #pragma unroll
        for (int r = 0; r < 4; ++r) {
            const int e  = rt * 16 + g * 4 + r;
            const int ge = e0 + e;
            const int dg = s_dst[e];
            #pragma unroll
            for (int j = 0; j < 2; ++j) {
                float v  = acc2[rt][j][r];
                float vn = __shfl_xor(v, 1, 64);
                if (even && ge < E) {
                    unsigned int pk2 = (unsigned)f2bf(v) | ((unsigned)f2bf(vn) << 16);
                    ushort_t* p = msum + (size_t)dg * D + wv * 32 + j * 16 + col;
                    asm volatile("global_atomic_pk_add_bf16 %0, %1, off"
                                 :: "v"(p), "v"(pk2) : "memory");
                }
            }
        }
}

template<bool MB16>
__global__ __launch_bounds__(NT, 2) void node_kernel(
    const float* __restrict__ f, const void* __restrict__ msum_v,
    const float* __restrict__ Wu1, const float* __restrict__ bu1,
    const float* __restrict__ Wu2, const float* __restrict__ bu2,
    float* out, int Nn)
{
    __shared__ __align__(16) float hin[NB][HID_PAD];
    __shared__ __align__(16) float hid[NB][HID_PAD];
    const int t  = threadIdx.x;
    const int n0 = blockIdx.x * NB;
    const int nn = min(NB, Nn - n0);

    {
        const int half = t >> 7, tt = t & 127;
        for (int e = half; e < nn; e += 2) {
            size_t off = (size_t)(n0 + e) * D + tt;
            float mv = MB16 ? bf2f(((const ushort_t*)msum_v)[off])
                            : ((const float*)msum_v)[off];
            hin[e][tt] = mv + f[off];
        }
    }
    __syncthreads();

    const int tc = t & 15, te2 = (t >> 4) * 2, c0 = tc * 8;
    float a1[2][8];
    #pragma unroll
    for (int c = 0; c < 8; ++c) { float bv = bu1[c0 + c]; a1[0][c] = bv; a1[1][c] = bv; }
    for (int i = 0; i < D; i += 4) {
        float m0[4], m1[4];
        *(float4*)m0 = *(const float4*)&hin[te2][i];
        *(float4*)m1 = *(const float4*)&hin[te2 + 1][i];
        #pragma unroll
        for (int r = 0; r < 4; ++r) {
            float wr[8];
            *(float4*)&wr[0] = *(const float4*)(Wu1 + (size_t)(i + r) * HD + c0);
            *(float4*)&wr[4] = *(const float4*)(Wu1 + (size_t)(i + r) * HD + c0 + 4);
            #pragma unroll
            for (int c = 0; c < 8; ++c) { a1[0][c] += m0[r]*wr[c]; a1[1][c] += m1[r]*wr[c]; }
        }
    }
    #pragma unroll
    for (int j = 0; j < 2; ++j) {
        float v[8];
        #pragma unroll
        for (int c = 0; c < 8; ++c) v[c] = fmaxf(a1[j][c], 0.f);
        *(float4*)&hid[te2 + j][c0] = *(float4*)&v[0];
        *(float4*)&hid[te2 + j][c0 + 4] = *(float4*)&v[4];
    }
    __syncthreads();
    float a2[2][8];
    #pragma unroll
    for (int c = 0; c < 8; ++c) { float bv = bu2[c0 + c]; a2[0][c] = bv; a2[1][c] = bv; }
    for (int h = 0; h < HD; h += 4) {
        float m0[4], m1[4];
        *(float4*)m0 = *(const float4*)&hid[te2][h];
        *(float4*)m1 = *(const float4*)&hid[te2 + 1][h];
        #pragma unroll
        for (int r = 0; r < 4; ++r) {
            float wr[8];
            *(float4*)&wr[0] = *(const float4*)(Wu2 + (size_t)(h + r) * D + c0);
            *(float4*)&wr[4] = *(const float4*)(Wu2 + (size_t)(h + r) * D + c0 + 4);
            #pragma unroll
            for (int c = 0; c < 8; ++c) { a2[0][c] += m0[r]*wr[c]; a2[1][c] += m1[r]*wr[c]; }
        }
    }
    #pragma unroll
    for (int j = 0; j < 2; ++j) {
        int e = te2 + j, gn = n0 + e;
        if (e < nn) {
            *(float4*)(out + (size_t)gn * D + c0) = *(float4*)&a2[j][0];
            *(float4*)(out + (size_t)gn * D + c0 + 4) = *(float4*)&a2[j][4];
        }
    }
}

__global__ __launch_bounds__(NT, 4) void edge_mfma_kernel_fa(
    const float* __restrict__ f, const float* __restrict__ x,
    const float* __restrict__ w, const int* __restrict__ src,
    const int* __restrict__ dst,
    const ushort_t* __restrict__ W1p, const float* __restrict__ bm1,
    const ushort_t* __restrict__ W2p, const float* __restrict__ bm2,
    float* msum, int E)
{
    __shared__ __align__(16) ushort_t msg_c[NCH1 * EB * 32];

    const int t    = threadIdx.x;
    const int lane = t & 63;
    const int wv   = t >> 6;
    const int e0   = blockIdx.x * EB;

    {
        const int el = lane >> 2;
        const int q  = lane & 3;
        const int ge = e0 + wv * 16 + el;
        const bool ok = ge < E;
        const int ns = ok ? src[ge] : 0;
        const int nd = ok ? dst[ge] : 0;
        const int mrow = wv * 16 + el;
        #pragma unroll
        for (int i = 0; i < 8; ++i) {
            const int k0 = i * 32 + q * 8;
            union { unsigned short us[8]; short8v v; } pk;
            if (ok) {
                const float* base = (k0 < D) ? (f + (size_t)ns * D + k0)
                                             : (f + (size_t)nd * D + (k0 - D));
                float4 v0 = *(const float4*)base;
                float4 v1 = *(const float4*)(base + 4);
                pk.us[0] = f2bf(v0.x); pk.us[1] = f2bf(v0.y);
                pk.us[2] = f2bf(v0.z); pk.us[3] = f2bf(v0.w);
                pk.us[4] = f2bf(v1.x); pk.us[5] = f2bf(v1.y);
                pk.us[6] = f2bf(v1.z); pk.us[7] = f2bf(v1.w);
            } else {
                #pragma unroll
                for (int j = 0; j < 8; ++j) pk.us[j] = 0;
            }
            *(short8v*)&msg_c[(i * EB + mrow) * 32 + q * 8] = pk.v;
        }
        {
            union { unsigned short us[8]; short8v v; } pk;
            #pragma unroll
            for (int j = 0; j < 8; ++j) pk.us[j] = 0;
            if (ok) {
                if (q < 2) {
                    float4 w0 = *(const float4*)(w + (size_t)ge * DE + q * 8);
                    float4 w1 = *(const float4*)(w + (size_t)ge * DE + q * 8 + 4);
                    pk.us[0] = f2bf(w0.x); pk.us[1] = f2bf(w0.y);
                    pk.us[2] = f2bf(w0.z); pk.us[3] = f2bf(w0.w);
                    pk.us[4] = f2bf(w1.x); pk.us[5] = f2bf(w1.y);
                    pk.us[6] = f2bf(w1.z); pk.us[7] = f2bf(w1.w);
                } else if (q == 2) {
                    float dx = x[ns*3+0] - x[nd*3+0];
                    float dy = x[ns*3+1] - x[nd*3+1];
                    float dz = x[ns*3+2] - x[nd*3+2];
                    pk.us[0] = f2bf(dx*dx + dy*dy + dz*dz);
                }
            }
            *(short8v*)&msg_c[(8 * EB + mrow) * 32 + q * 8] = pk.v;
        }
    }

    const int col  = lane & 15;
    const int g    = lane >> 4;
    const int erow = wv * 16 + col;

    f32x4 acc[8];
    #pragma unroll
    for (int ct = 0; ct < 8; ++ct) {
        float bv = bm1[ct * 16 + col];
        acc[ct] = (f32x4){bv, bv, bv, bv};
    }
    for (int c = 0; c < NCH1; ++c) {
        short8v a = *(const short8v*)&msg_c[(c * EB + erow) * 32 + g * 8];
        #pragma unroll
        for (int ct = 0; ct < 8; ++ct) {
            short8v b = *(const short8v*)&W1p[(size_t)(ct * 16 + col) * KP1 + c * 32 + g * 8];
            acc[ct] = __builtin_amdgcn_mfma_f32_16x16x32_bf16(a, b, acc[ct], 0, 0, 0);
        }
    }
    #pragma unroll
    for (int ct = 0; ct < 8; ++ct) {
        const int h  = ct * 16 + col;
        const int hc = h >> 5, hi = h & 31;
        #pragma unroll
        for (int r = 0; r < 4; ++r) {
            const int e = wv * 16 + g * 4 + r;
            msg_c[(hc * EB + e) * 32 + hi] = f2bf(fmaxf(acc[ct][r], 0.f));
        }
    }

    f32x4 acc2[8];
    #pragma unroll
    for (int ct = 0; ct < 8; ++ct) {
        float bv = bm2[ct * 16 + col];
        acc2[ct] = (f32x4){bv, bv, bv, bv};
    }
    for (int c = 0; c < NCH2; ++c) {
        short8v a = *(const short8v*)&msg_c[(c * EB + erow) * 32 + g * 8];
        #pragma unroll
        for (int ct = 0; ct < 8; ++ct) {
            short8v b = *(const short8v*)&W2p[(size_t)(ct * 16 + col) * HD + c * 32 + g * 8];
            acc2[ct] = __builtin_amdgcn_mfma_f32_16x16x32_bf16(a, b, acc2[ct], 0, 0, 0);
        }
    }

    #pragma unroll
    for (int r = 0; r < 4; ++r) {
        const int el = wv * 16 + g * 4 + r;
        const int ge = e0 + el;
        if (ge < E) {
            const int dg = dst[ge];
            float* p = msum + (size_t)dg * D + col;
            #pragma unroll
            for (int ct = 0; ct < 8; ++ct)
                atomicAdd(p + ct * 16, acc2[ct][r]);
        }
    }
}

extern "C" void kernel_launch(void* const* d_in, const int* in_sizes, int n_in,
                              void* d_out, int out_size, void* d_ws, size_t ws_size,
                              hipStream_t stream) {
    const float* f   = (const float*)d_in[0];
    const float* x   = (const float*)d_in[1];
    const float* w   = (const float*)d_in[2];
    const int*   src = (const int*)d_in[3];
    const int*   dst = (const int*)d_in[4];
    const float* Wm1 = (const float*)d_in[5];
    const float* bm1 = (const float*)d_in[6];
    const float* Wm2 = (const float*)d_in[7];
    const float* bm2 = (const float*)d_in[8];
    const float* Wu1 = (const float*)d_in[9];
    const float* bu1 = (const float*)d_in[10];
    const float* Wu2 = (const float*)d_in[11];
    const float* bu2 = (const float*)d_in[12];

    const int Nn = in_sizes[0] / D;
    const int E  = in_sizes[3];

    const size_t wbytes = (size_t)(128 * KP1 + HD * D) * sizeof(ushort_t);
    auto align512 = [](size_t v) { return (v + 511) & ~(size_t)511; };

    const size_t fb_bytes = (size_t)Nn * D * 2;
    char* wsb = (char*)d_ws;
    const int rp_elems = 128 * KP1 + HD * D;

    // ---------------- two-phase CSR layout ----------------
    size_t off = 0;
    const size_t o_w    = off; off = align512(off + wbytes);
    const size_t o_fb   = off; off = align512(off + fb_bytes);
    const size_t o_cnt  = off; off = align512(off + (size_t)Nn * 4);
    const size_t o_roff = off; off = align512(off + (size_t)Nn * 4);
    const size_t o_cur  = off; off = align512(off + (size_t)Nn * 4);
    const size_t o_perm = off; off = align512(off + (size_t)E * 4);
    const size_t o_sdst = off; off = align512(off + (size_t)E * 4);
    const size_t o_m    = off; off = align512(off + (size_t)E * D * 2);
    const size_t two_phase_total = off;

    if (ws_size >= two_phase_total) {
        ushort_t* W1p   = (ushort_t*)(wsb + o_w);
        ushort_t* W2p   = W1p + 128 * KP1;
        ushort_t* fbf   = (ushort_t*)(wsb + o_fb);
        int* cnt        = (int*)(wsb + o_cnt);
        int* roff       = (int*)(wsb + o_roff);
        int* cursor     = (int*)(wsb + o_cur);
        int* perm       = (int*)(wsb + o_perm);
        int* sdst       = (int*)(wsb + o_sdst);
        ushort_t* m_srt = (ushort_t*)(wsb + o_m);

        hipMemsetAsync(cnt, 0, (size_t)Nn * 4, stream);
        repack_kernel<<<dim3((rp_elems + 255) / 256), dim3(256), 0, stream>>>(Wm1, Wm2, W1p, W2p);
        const int n8 = Nn * D / 8;
        fconv_kernel<<<dim3((n8 + 255) / 256), dim3(256), 0, stream>>>(f, fbf, n8);
        hist_kernel<<<dim3((E + 255) / 256), dim3(256), 0, stream>>>(dst, cnt, E);
        scan_kernel<<<dim3(1), dim3(1024), 0, stream>>>(cnt, roff, cursor, Nn);
        scatter_kernel<<<dim3((E + 255) / 256), dim3(256), 0, stream>>>(dst, cursor, perm, sdst, E);
        edge_mfma_sorted_kernel<<<dim3((E + EB - 1) / EB), dim3(NT), 0, stream>>>(
            fbf, x, w, src, perm, sdst, W1p, bm1, W2p, bm2, m_srt, E);
        node_csr_kernel<<<dim3((Nn + NB - 1) / NB), dim3(NT), 0, stream>>>(
            f, m_srt, roff, cnt, Wu1, bu1, Wu2, bu2, (float*)d_out, Nn);
        return;
    }

    // ---------------- fallback: pk-atomic path ----------------
    size_t off2 = 0;
    const size_t p_w  = off2; off2 = align512(off2 + wbytes);
    const size_t p_fb = off2; off2 = align512(off2 + fb_bytes);
    const size_t p_ms = off2; off2 = align512(off2 + (size_t)Nn * D * 2);
    if (ws_size >= off2) {
        ushort_t* W1p  = (ushort_t*)(wsb + p_w);
        ushort_t* W2p  = W1p + 128 * KP1;
        ushort_t* fbf  = (ushort_t*)(wsb + p_fb);
        ushort_t* msum = (ushort_t*)(wsb + p_ms);
        hipMemsetAsync(msum, 0, (size_t)Nn * D * 2, stream);
        repack_kernel<<<dim3((rp_elems + 255) / 256), dim3(256), 0, stream>>>(Wm1, Wm2, W1p, W2p);
        const int n8 = Nn * D / 8;
        fconv_kernel<<<dim3((n8 + 255) / 256), dim3(256), 0, stream>>>(f, fbf, n8);
        edge_mfma_kernel<<<dim3((E + EB - 1) / EB), dim3(NT), 0, stream>>>(
            fbf, x, w, src, dst, W1p, bm1, W2p, bm2, msum, E);
        node_kernel<true><<<dim3((Nn + NB - 1) / NB), dim3(NT), 0, stream>>>(
            f, msum, Wu1, bu1, Wu2, bu2, (float*)d_out, Nn);
        return;
    }

    // ---------------- last resort: fp32 atomics, msum in d_out ----------------
    {
        ushort_t* W1p  = (ushort_t*)wsb;
        ushort_t* W2p  = W1p + 128 * KP1;
        float* msum    = (float*)d_out;
        hipMemsetAsync(msum, 0, (size_t)Nn * D * 4, stream);
        repack_kernel<<<dim3((rp_elems + 255) / 256), dim3(256), 0, stream>>>(Wm1, Wm2, W1p, W2p);
        edge_mfma_kernel_fa<<<dim3((E + EB - 1) / EB), dim3(NT), 0, stream>>>(
            f, x, w, src, dst, W1p, bm1, W2p, bm2, msum, E);
        node_kernel<false><<<dim3((Nn + NB - 1) / NB), dim3(NT), 0, stream>>>(
            f, msum, Wu1, bu1, Wu2, bu2, (float*)d_out, Nn);
    }
}

// Round 10
// 470.312 us; speedup vs baseline: 1.2212x; 1.0730x over previous
//
#include <hip/hip_runtime.h>

#define D 128
#define HD 128
#define DE 16
#define MSG_IN 273
#define EB 64        // edges per block (mfma path)
#define NT 256
#define KP1 288      // padded msg K = 9 chunks of 32
#define NCH1 9
#define NCH2 4
#define NB 32
#define HID_PAD 132
#define CH8 (4 * EB * 64)   // ushort offset of chunk-8 region in lds[]

typedef __attribute__((ext_vector_type(8))) short short8v;
typedef __attribute__((ext_vector_type(4))) float f32x4;
typedef unsigned short ushort_t;

#define GLOAD_LDS16(gp, lp) \
    __builtin_amdgcn_global_load_lds((const __attribute__((address_space(1))) unsigned int*)(gp), \
                                     (__attribute__((address_space(3))) unsigned int*)(lp), 16, 0, 0)

__device__ __forceinline__ unsigned short f2bf(float v) {
    unsigned int u = __builtin_bit_cast(unsigned int, v);
    u += 0x7fffu + ((u >> 16) & 1u);
    return (unsigned short)(u >> 16);
}
__device__ __forceinline__ float bf2f(ushort_t u) {
    return __builtin_bit_cast(float, (unsigned int)u << 16);
}

// ---------------- fused prepass: weight repack + f->bf16 + dst hist + msum zero ----------------
__global__ void fused_pre_kernel(const float* __restrict__ Wm1, const float* __restrict__ Wm2,
                                 ushort_t* __restrict__ W1p, ushort_t* __restrict__ W2p,
                                 const float* __restrict__ f, ushort_t* __restrict__ fb,
                                 const int* __restrict__ dst, int* __restrict__ cnt,
                                 float* __restrict__ msum,
                                 int n8, int E, int nq) {
    const int gid    = blockIdx.x * 256 + threadIdx.x;
    const int stride = gridDim.x * 256;
    const int rp1 = 128 * KP1;
    const int rp_elems = rp1 + HD * D;
    for (int i = gid; i < rp_elems; i += stride) {
        if (i < rp1) {
            int n = i / KP1, k = i % KP1;
            W1p[i] = f2bf((k < MSG_IN) ? Wm1[(size_t)k * HD + n] : 0.f);
        } else {
            int i2 = i - rp1;
            int n = i2 / HD, k = i2 % HD;
            W2p[i2] = f2bf(Wm2[(size_t)k * D + n]);
        }
    }
    for (int i = gid; i < n8; i += stride) {
        float4 v0 = *(const float4*)(f + (size_t)i * 8);
        float4 v1 = *(const float4*)(f + (size_t)i * 8 + 4);
        union { ushort_t us[8]; short8v v; } pk;
        pk.us[0] = f2bf(v0.x); pk.us[1] = f2bf(v0.y);
        pk.us[2] = f2bf(v0.z); pk.us[3] = f2bf(v0.w);
        pk.us[4] = f2bf(v1.x); pk.us[5] = f2bf(v1.y);
        pk.us[6] = f2bf(v1.z); pk.us[7] = f2bf(v1.w);
        *(short8v*)(fb + (size_t)i * 8) = pk.v;
    }
    for (int i = gid; i < E; i += stride) atomicAdd(&cnt[dst[i]], 1);
    float4 z = {0.f, 0.f, 0.f, 0.f};
    for (int i = gid; i < nq; i += stride) *(float4*)(msum + (size_t)i * 4) = z;
}

// ---------------- CSR build: parallel scan -> scatter ----------------
__global__ __launch_bounds__(1024) void scan_kernel(const int* __restrict__ cnt,
                                                    int* __restrict__ roff,
                                                    int* __restrict__ cursor, int Nn) {
    __shared__ int wsum[16];
    const int t = threadIdx.x, l = t & 63, wid = t >> 6;
    int running = 0;
    for (int base = 0; base < Nn; base += 1024) {
        const int i = base + t;
        const int v = (i < Nn) ? cnt[i] : 0;
        int s = v;
        #pragma unroll
        for (int off = 1; off < 64; off <<= 1) {
            int u = __shfl_up(s, off, 64);
            if (l >= off) s += u;
        }
        if (l == 63) wsum[wid] = s;
        __syncthreads();
        if (wid == 0 && l < 16) {
            int xv = wsum[l];
            #pragma unroll
            for (int off = 1; off < 16; off <<= 1) {
                int u = __shfl_up(xv, off, 64);
                if (l >= off) xv += u;
            }
            wsum[l] = xv;
        }
        __syncthreads();
        const int prev  = (wid > 0) ? wsum[wid - 1] : 0;
        const int total = wsum[15];
        if (i < Nn) {
            int ex = running + prev + s - v;
            roff[i] = ex; cursor[i] = ex;
        }
        running += total;
        __syncthreads();
    }
}

__global__ void scatter_kernel(const int* __restrict__ dst, int* cursor,
                               int* __restrict__ perm, int* __restrict__ sdst, int E) {
    int i = blockIdx.x * 256 + threadIdx.x;
    if (i < E) {
        int d = dst[i];
        int s = atomicAdd(&cursor[d], 1);
        perm[s] = i;
        sdst[s] = d;
    }
}

// ---------------- edge kernel v10: fused in-register segment reduce -> msum (f32) ----------------
// Wave-local reduce: every wave holds ALL 64 (sorted) edges for its 32 output cols,
// so dst-runs reduce in registers; plain stores for interior nodes, atomics at block
// boundaries only.
__global__ __launch_bounds__(NT, 4) void edge_mfma_fused_kernel(
    const ushort_t* __restrict__ fbf, const float* __restrict__ x,
    const float* __restrict__ w, const int* __restrict__ src,
    const int* __restrict__ perm, const int* __restrict__ sdst,
    const ushort_t* __restrict__ W1p, const float* __restrict__ bm1,
    const ushort_t* __restrict__ W2p, const float* __restrict__ bm2,
    float* __restrict__ msum, int E)
{
    __shared__ __align__(16) ushort_t lds[4 * EB * 64 + EB * 32];  // 36,864 B
    __shared__ int s_sd[EB];

    const int t    = threadIdx.x;
    const int lane = t & 63;
    const int wv   = t >> 6;
    const int e0   = blockIdx.x * EB;

    if (t < EB) s_sd[t] = (e0 + t < E) ? sdst[e0 + t] : -1;
    const int prevd = (e0 > 0) ? sdst[e0 - 1] : -2;
    const int nextd = (e0 + EB < E) ? sdst[e0 + EB] : -2;

    // ---- f staging: 8 x global_load_lds_dwordx4, pre-swizzled global source ----
    {
        const int el8 = lane >> 3;
        const int s   = lane & 7;
        const int sl  = s ^ el8;            // involution swizzle
        const int slA = min(e0 + wv * 16 + el8,     E - 1);
        const int slB = min(e0 + wv * 16 + 8 + el8, E - 1);
        const int geA = perm[slA], geB = perm[slB];
        const int nsA = src[geA], ndA = sdst[slA];
        const int nsB = src[geB], ndB = sdst[slB];
        #pragma unroll
        for (int p = 0; p < 4; ++p) {
            const int n0 = (p < 2) ? nsA : ndA;
            const int n1 = (p < 2) ? nsB : ndB;
            const ushort_t* g0 = fbf + (size_t)n0 * D + (p & 1) * 64 + sl * 8;
            const ushort_t* g1 = fbf + (size_t)n1 * D + (p & 1) * 64 + sl * 8;
            GLOAD_LDS16(g0, &lds[(p * EB + wv * 16    ) * 64]);
            GLOAD_LDS16(g1, &lds[(p * EB + wv * 16 + 8) * 64]);
        }
    }
    // ---- chunk 8: w feats (k0..15), sqd (k16), zeros; 2-bit swizzle ----
    {
        const int el = lane >> 2, q = lane & 3;
        const int qp = q ^ (el & 3);
        const int slot = e0 + wv * 16 + el;
        const bool ok = slot < E;
        const int sc = min(slot, E - 1);
        const int ge = perm[sc];
        union { ushort_t us[8]; short8v v; } pk;
        #pragma unroll
        for (int j = 0; j < 8; ++j) pk.us[j] = 0;
        if (ok) {
            if (q < 2) {
                float4 w0 = *(const float4*)(w + (size_t)ge * DE + q * 8);
                float4 w1 = *(const float4*)(w + (size_t)ge * DE + q * 8 + 4);
                pk.us[0] = f2bf(w0.x); pk.us[1] = f2bf(w0.y);
                pk.us[2] = f2bf(w0.z); pk.us[3] = f2bf(w0.w);
                pk.us[4] = f2bf(w1.x); pk.us[5] = f2bf(w1.y);
                pk.us[6] = f2bf(w1.z); pk.us[7] = f2bf(w1.w);
            } else if (q == 2) {
                const int ns = src[ge], nd = sdst[sc];
                float dx = x[ns*3+0] - x[nd*3+0];
                float dy = x[ns*3+1] - x[nd*3+1];
                float dz = x[ns*3+2] - x[nd*3+2];
                pk.us[0] = f2bf(dx*dx + dy*dy + dz*dz);
            }
        }
        *(short8v*)&lds[CH8 + (wv * 16 + el) * 32 + qp * 8] = pk.v;
    }

    const int col = lane & 15;
    const int g   = lane >> 4;

    const size_t wrow0 = (size_t)(wv * 32 + col) * KP1;
    const size_t wrow1 = (size_t)(wv * 32 + 16 + col) * KP1;
    short8v nb0 = *(const short8v*)&W1p[wrow0 + g * 8];
    short8v nb1 = *(const short8v*)&W1p[wrow1 + g * 8];

    __syncthreads();   // B0: staging complete

    // ---- layer 1: [64,288] x [288,32] per wave ----
    f32x4 acc[4][2];
    {
        float bv0 = bm1[wv * 32 + col];
        float bv1 = bm1[wv * 32 + 16 + col];
        #pragma unroll
        for (int rt = 0; rt < 4; ++rt) {
            acc[rt][0] = (f32x4){bv0, bv0, bv0, bv0};
            acc[rt][1] = (f32x4){bv1, bv1, bv1, bv1};
        }
    }
    #pragma unroll
    for (int c = 0; c < NCH1; ++c) {
        short8v b0 = nb0, b1 = nb1;
        if (c + 1 < NCH1) {
            nb0 = *(const short8v*)&W1p[wrow0 + (c + 1) * 32 + g * 8];
            nb1 = *(const short8v*)&W1p[wrow1 + (c + 1) * 32 + g * 8];
        }
        short8v a[4];
        #pragma unroll
        for (int rt = 0; rt < 4; ++rt) {
            const int row = rt * 16 + col;
            if (c < 8) {
                const int sP = (((c & 1) << 2) + g) ^ (row & 7);
                a[rt] = *(const short8v*)&lds[((c >> 1) * EB + row) * 64 + sP * 8];
            } else {
                const int sP = g ^ (row & 3);
                a[rt] = *(const short8v*)&lds[CH8 + row * 32 + sP * 8];
            }
        }
        #pragma unroll
        for (int rt = 0; rt < 4; ++rt) {
            acc[rt][0] = __builtin_amdgcn_mfma_f32_16x16x32_bf16(a[rt], b0, acc[rt][0], 0, 0, 0);
            acc[rt][1] = __builtin_amdgcn_mfma_f32_16x16x32_bf16(a[rt], b1, acc[rt][1], 0, 0, 0);
        }
    }
    __syncthreads();   // B1

    // hid (relu, bf16, pair-packed b32) -> pairs 0-1 region, same swizzle
    const bool even = (col & 1) == 0;
    const int ph = wv >> 1;
    #pragma unroll
    for (int rt = 0; rt < 4; ++rt)
        #pragma unroll
        for (int j = 0; j < 2; ++j)
            #pragma unroll
            for (int r = 0; r < 4; ++r) {
                const int row = rt * 16 + g * 4 + r;
                float v  = fmaxf(acc[rt][j][r], 0.f);
                float vn = __shfl_xor(v, 1, 64);
                if (even) {
                    unsigned int pk2 = (unsigned)f2bf(v) | ((unsigned)f2bf(vn) << 16);
                    const int sH = (((wv & 1) << 2) + j * 2 + (col >> 3)) ^ (row & 7);
                    *(unsigned int*)&lds[(ph * EB + row) * 64 + sH * 8 + (col & 7)] = pk2;
                }
            }
    __syncthreads();   // B2

    // ---- layer 2: [64,128] x [128,32] per wave ----
    const size_t w2r0 = (size_t)(wv * 32 + col) * HD;
    const size_t w2r1 = (size_t)(wv * 32 + 16 + col) * HD;
    short8v m0 = *(const short8v*)&W2p[w2r0 + g * 8];
    short8v m1 = *(const short8v*)&W2p[w2r1 + g * 8];
    f32x4 acc2[4][2];
    {
        float bv0 = bm2[wv * 32 + col];
        float bv1 = bm2[wv * 32 + 16 + col];
        #pragma unroll
        for (int rt = 0; rt < 4; ++rt) {
            acc2[rt][0] = (f32x4){bv0, bv0, bv0, bv0};
            acc2[rt][1] = (f32x4){bv1, bv1, bv1, bv1};
        }
    }
    #pragma unroll
    for (int c = 0; c < NCH2; ++c) {
        short8v b0 = m0, b1 = m1;
        if (c + 1 < NCH2) {
            m0 = *(const short8v*)&W2p[w2r0 + (c + 1) * 32 + g * 8];
            m1 = *(const short8v*)&W2p[w2r1 + (c + 1) * 32 + g * 8];
        }
        short8v a[4];
        #pragma unroll
        for (int rt = 0; rt < 4; ++rt) {
            const int row = rt * 16 + col;
            const int sP = (((c & 1) << 2) + g) ^ (row & 7);
            a[rt] = *(const short8v*)&lds[((c >> 1) * EB + row) * 64 + sP * 8];
        }
        #pragma unroll
        for (int rt = 0; rt < 4; ++rt) {
            acc2[rt][0] = __builtin_amdgcn_mfma_f32_16x16x32_bf16(a[rt], b0, acc2[rt][0], 0, 0, 0);
            acc2[rt][1] = __builtin_amdgcn_mfma_f32_16x16x32_bf16(a[rt], b1, acc2[rt][1], 0, 0, 0);
        }
    }

    // ---- wave-local segment reduce -> msum (f32) ----
    // quad pre-sums: sum over r of each rt-quad (slots rt*16 + g*4 + 0..3)
    float qs[4][2];
    #pragma unroll
    for (int rt = 0; rt < 4; ++rt) {
        qs[rt][0] = (acc2[rt][0][0] + acc2[rt][0][1]) + (acc2[rt][0][2] + acc2[rt][0][3]);
        qs[rt][1] = (acc2[rt][1][0] + acc2[rt][1][1]) + (acc2[rt][1][2] + acc2[rt][1][3]);
    }
    const int nvalid = min(EB, E - e0);
    int run_beg = 0;
    while (run_beg < nvalid) {
        const int dg = s_sd[run_beg];
        int run_end = run_beg + 1;
        while (run_end < nvalid && s_sd[run_end] == dg) ++run_end;

        float s0 = 0.f, s1 = 0.f;
        #pragma unroll
        for (int rt = 0; rt < 4; ++rt) {
            const int qb = rt * 16 + g * 4;
            if (qb >= run_beg && qb + 4 <= run_end) {
                s0 += qs[rt][0]; s1 += qs[rt][1];
            } else if (qb + 4 > run_beg && qb < run_end) {
                #pragma unroll
                for (int r = 0; r < 4; ++r) {
                    const int sl = qb + r;
                    if (sl >= run_beg && sl < run_end) {
                        s0 += acc2[rt][0][r]; s1 += acc2[rt][1][r];
                    }
                }
            }
        }
        // combine the 4 k-groups (g)
        s0 += __shfl_xor(s0, 16, 64); s0 += __shfl_xor(s0, 32, 64);
        s1 += __shfl_xor(s1, 16, 64); s1 += __shfl_xor(s1, 32, 64);
        if (g == 0) {
            const bool bnd = (run_beg == 0 && dg == prevd) ||
                             (run_end == nvalid && dg == nextd);
            float* p = msum + (size_t)dg * D + wv * 32 + col;
            if (bnd) { atomicAdd(p, s0); atomicAdd(p + 16, s1); }
            else     { p[0] = s0; p[16] = s1; }
        }
        run_beg = run_end;
    }
}

// ---------------- node kernel: update MLP (fp32 compute, templated msum dtype) ----------------
template<bool MB16>
__global__ __launch_bounds__(NT, 2) void node_kernel(
    const float* __restrict__ f, const void* __restrict__ msum_v,
    const float* __restrict__ Wu1, const float* __restrict__ bu1,
    const float* __restrict__ Wu2, const float* __restrict__ bu2,
    float* out, int Nn)
{
    __shared__ __align__(16) float hin[NB][HID_PAD];
    __shared__ __align__(16) float hid[NB][HID_PAD];
    const int t  = threadIdx.x;
    const int n0 = blockIdx.x * NB;
    const int nn = min(NB, Nn - n0);

    {
        const int half = t >> 7, tt = t & 127;
        for (int e = half; e < nn; e += 2) {
            size_t off = (size_t)(n0 + e) * D + tt;
            float mv = MB16 ? bf2f(((const ushort_t*)msum_v)[off])
                            : ((const float*)msum_v)[off];
            hin[e][tt] = mv + f[off];
        }
    }
    __syncthreads();

    const int tc = t & 15, te2 = (t >> 4) * 2, c0 = tc * 8;
    float a1[2][8];
    #pragma unroll
    for (int c = 0; c < 8; ++c) { float bv = bu1[c0 + c]; a1[0][c] = bv; a1[1][c] = bv; }
    for (int i = 0; i < D; i += 4) {
        float m0[4], m1[4];
        *(float4*)m0 = *(const float4*)&hin[te2][i];
        *(float4*)m1 = *(const float4*)&hin[te2 + 1][i];
        #pragma unroll
        for (int r = 0; r < 4; ++r) {
            float wr[8];
            *(float4*)&wr[0] = *(const float4*)(Wu1 + (size_t)(i + r) * HD + c0);
            *(float4*)&wr[4] = *(const float4*)(Wu1 + (size_t)(i + r) * HD + c0 + 4);
            #pragma unroll
            for (int c = 0; c < 8; ++c) { a1[0][c] += m0[r]*wr[c]; a1[1][c] += m1[r]*wr[c]; }
        }
    }
    #pragma unroll
    for (int j = 0; j < 2; ++j) {
        float v[8];
        #pragma unroll
        for (int c = 0; c < 8; ++c) v[c] = fmaxf(a1[j][c], 0.f);
        *(float4*)&hid[te2 + j][c0] = *(float4*)&v[0];
        *(float4*)&hid[te2 + j][c0 + 4] = *(float4*)&v[4];
    }
    __syncthreads();
    float a2[2][8];
    #pragma unroll
    for (int c = 0; c < 8; ++c) { float bv = bu2[c0 + c]; a2[0][c] = bv; a2[1][c] = bv; }
    for (int h = 0; h < HD; h += 4) {
        float m0[4], m1[4];
        *(float4*)m0 = *(const float4*)&hid[te2][h];
        *(float4*)m1 = *(const float4*)&hid[te2 + 1][h];
        #pragma unroll
        for (int r = 0; r < 4; ++r) {
            float wr[8];
            *(float4*)&wr[0] = *(const float4*)(Wu2 + (size_t)(h + r) * D + c0);
            *(float4*)&wr[4] = *(const float4*)(Wu2 + (size_t)(h + r) * D + c0 + 4);
            #pragma unroll
            for (int c = 0; c < 8; ++c) { a2[0][c] += m0[r]*wr[c]; a2[1][c] += m1[r]*wr[c]; }
        }
    }
    #pragma unroll
    for (int j = 0; j < 2; ++j) {
        int e = te2 + j, gn = n0 + e;
        if (e < nn) {
            *(float4*)(out + (size_t)gn * D + c0) = *(float4*)&a2[j][0];
            *(float4*)(out + (size_t)gn * D + c0 + 4) = *(float4*)&a2[j][4];
        }
    }
}

// ================= fallback kernels (pk-atomic path; no CSR) =================

__global__ void repack_kernel(const float* __restrict__ Wm1, const float* __restrict__ Wm2,
                              ushort_t* __restrict__ W1p, ushort_t* __restrict__ W2p) {
    int idx = blockIdx.x * 256 + threadIdx.x;
    const int n1 = 128 * KP1;
    if (idx < n1) {
        int n = idx / KP1, k = idx % KP1;
        W1p[idx] = f2bf((k < MSG_IN) ? Wm1[(size_t)k * HD + n] : 0.f);
    } else {
        int i2 = idx - n1;
        if (i2 < HD * D) {
            int n = i2 / HD, k = i2 % HD;
            W2p[i2] = f2bf(Wm2[(size_t)k * D + n]);
        }
    }
}

__global__ void fconv_kernel(const float* __restrict__ f, ushort_t* __restrict__ fb, int n8) {
    int i = blockIdx.x * 256 + threadIdx.x;
    if (i < n8) {
        float4 v0 = *(const float4*)(f + (size_t)i * 8);
        float4 v1 = *(const float4*)(f + (size_t)i * 8 + 4);
        union { ushort_t us[8]; short8v v; } pk;
        pk.us[0] = f2bf(v0.x); pk.us[1] = f2bf(v0.y);
        pk.us[2] = f2bf(v0.z); pk.us[3] = f2bf(v0.w);
        pk.us[4] = f2bf(v1.x); pk.us[5] = f2bf(v1.y);
        pk.us[6] = f2bf(v1.z); pk.us[7] = f2bf(v1.w);
        *(short8v*)(fb + (size_t)i * 8) = pk.v;
    }
}

__global__ __launch_bounds__(NT, 4) void edge_mfma_kernel(
    const ushort_t* __restrict__ fbf, const float* __restrict__ x,
    const float* __restrict__ w, const int* __restrict__ src,
    const int* __restrict__ dst,
    const ushort_t* __restrict__ W1p, const float* __restrict__ bm1,
    const ushort_t* __restrict__ W2p, const float* __restrict__ bm2,
    ushort_t* msum, int E)
{
    __shared__ __align__(16) ushort_t lds[4 * EB * 64 + EB * 32];
    __shared__ int s_dst[EB];

    const int t    = threadIdx.x;
    const int lane = t & 63;
    const int wv   = t >> 6;
    const int e0   = blockIdx.x * EB;

    if (t < EB) s_dst[t] = (e0 + t < E) ? dst[e0 + t] : 0;
    {
        const int el8 = lane >> 3;
        const int s   = lane & 7;
        const int sl  = s ^ el8;
        const int geA = min(e0 + wv * 16 + el8,     E - 1);
        const int geB = min(e0 + wv * 16 + 8 + el8, E - 1);
        const int nsA = src[geA], ndA = dst[geA];
        const int nsB = src[geB], ndB = dst[geB];
        #pragma unroll
        for (int p = 0; p < 4; ++p) {
            const int n0 = (p < 2) ? nsA : ndA;
            const int n1 = (p < 2) ? nsB : ndB;
            const ushort_t* g0 = fbf + (size_t)n0 * D + (p & 1) * 64 + sl * 8;
            const ushort_t* g1 = fbf + (size_t)n1 * D + (p & 1) * 64 + sl * 8;
            GLOAD_LDS16(g0, &lds[(p * EB + wv * 16    ) * 64]);
            GLOAD_LDS16(g1, &lds[(p * EB + wv * 16 + 8) * 64]);
        }
    }
    {
        const int el = lane >> 2, q = lane & 3;
        const int qp = q ^ (el & 3);
        const int ge = e0 + wv * 16 + el;
        const bool ok = ge < E;
        const int gc = min(ge, E - 1);
        union { ushort_t us[8]; short8v v; } pk;
        #pragma unroll
        for (int j = 0; j < 8; ++j) pk.us[j] = 0;
        if (ok) {
            if (q < 2) {
                float4 w0 = *(const float4*)(w + (size_t)gc * DE + q * 8);
                float4 w1 = *(const float4*)(w + (size_t)gc * DE + q * 8 + 4);
                pk.us[0] = f2bf(w0.x); pk.us[1] = f2bf(w0.y);
                pk.us[2] = f2bf(w0.z); pk.us[3] = f2bf(w0.w);
                pk.us[4] = f2bf(w1.x); pk.us[5] = f2bf(w1.y);
                pk.us[6] = f2bf(w1.z); pk.us[7] = f2bf(w1.w);
            } else if (q == 2) {
                const int ns = src[gc], nd = dst[gc];
                float dx = x[ns*3+0] - x[nd*3+0];
                float dy = x[ns*3+1] - x[nd*3+1];
                float dz = x[ns*3+2] - x[nd*3+2];
                pk.us[0] = f2bf(dx*dx + dy*dy + dz*dz);
            }
        }
        *(short8v*)&lds[CH8 + (wv * 16 + el) * 32 + qp * 8] = pk.v;
    }

    const int col = lane & 15;
    const int g   = lane >> 4;
    const size_t wrow0 = (size_t)(wv * 32 + col) * KP1;
    const size_t wrow1 = (size_t)(wv * 32 + 16 + col) * KP1;
    short8v nb0 = *(const short8v*)&W1p[wrow0 + g * 8];
    short8v nb1 = *(const short8v*)&W1p[wrow1 + g * 8];
    __syncthreads();

    f32x4 acc[4][2];
    {
        float bv0 = bm1[wv * 32 + col];
        float bv1 = bm1[wv * 32 + 16 + col];
        #pragma unroll
        for (int rt = 0; rt < 4; ++rt) {
            acc[rt][0] = (f32x4){bv0, bv0, bv0, bv0};
            acc[rt][1] = (f32x4){bv1, bv1, bv1, bv1};
        }
    }
    #pragma unroll
    for (int c = 0; c < NCH1; ++c) {
        short8v b0 = nb0, b1 = nb1;
        if (c + 1 < NCH1) {
            nb0 = *(const short8v*)&W1p[wrow0 + (c + 1) * 32 + g * 8];
            nb1 = *(const short8v*)&W1p[wrow1 + (c + 1) * 32 + g * 8];
        }
        short8v a[4];
        #pragma unroll
        for (int rt = 0; rt < 4; ++rt) {
            const int row = rt * 16 + col;
            if (c < 8) {
                const int sP = (((c & 1) << 2) + g) ^ (row & 7);
                a[rt] = *(const short8v*)&lds[((c >> 1) * EB + row) * 64 + sP * 8];
            } else {
                const int sP = g ^ (row & 3);
                a[rt] = *(const short8v*)&lds[CH8 + row * 32 + sP * 8];
            }
        }
        #pragma unroll
        for (int rt = 0; rt < 4; ++rt) {
            acc[rt][0] = __builtin_amdgcn_mfma_f32_16x16x32_bf16(a[rt], b0, acc[rt][0], 0, 0, 0);
            acc[rt][1] = __builtin_amdgcn_mfma_f32_16x16x32_bf16(a[rt], b1, acc[rt][1], 0, 0, 0);
        }
    }
    __syncthreads();

    const bool even = (col & 1) == 0;
    const int ph = wv >> 1;
    #pragma unroll
    for (int rt = 0; rt < 4; ++rt)
        #pragma unroll
        for (int j = 0; j < 2; ++j)
            #pragma unroll
            for (int r = 0; r < 4; ++r) {
                const int row = rt * 16 + g * 4 + r;
                float v  = fmaxf(acc[rt][j][r], 0.f);
                float vn = __shfl_xor(v, 1, 64);
                if (even) {
                    unsigned int pk2 = (unsigned)f2bf(v) | ((unsigned)f2bf(vn) << 16);
                    const int sH = (((wv & 1) << 2) + j * 2 + (col >> 3)) ^ (row & 7);
                    *(unsigned int*)&lds[(ph * EB + row) * 64 + sH * 8 + (col & 7)] = pk2;
                }
            }
    __syncthreads();

    const size_t w2r0 = (size_t)(wv * 32 + col) * HD;
    const size_t w2r1 = (size_t)(wv * 32 + 16 + col) * HD;
    short8v m0 = *(const short8v*)&W2p[w2r0 + g * 8];
    short8v m1 = *(const short8v*)&W2p[w2r1 + g * 8];
    f32x4 acc2[4][2];
    {
        float bv0 = bm2[wv * 32 + col];
        float bv1 = bm2[wv * 32 + 16 + col];
        #pragma unroll
        for (int rt = 0; rt < 4; ++rt) {
            acc2[rt][0] = (f32x4){bv0, bv0, bv0, bv0};
            acc2[rt][1] = (f32x4){bv1, bv1, bv1, bv1};
        }
    }
    #pragma unroll
    for (int c = 0; c < NCH2; ++c) {
        short8v b0 = m0, b1 = m1;
        if (c + 1 < NCH2) {
            m0 = *(const short8v*)&W2p[w2r0 + (c + 1) * 32 + g * 8];
            m1 = *(const short8v*)&W2p[w2r1 + (c + 1) * 32 + g * 8];
        }
        short8v a[4];
        #pragma unroll
        for (int rt = 0; rt < 4; ++rt) {
            const int row = rt * 16 + col;
            const int sP = (((c & 1) << 2) + g) ^ (row & 7);
            a[rt] = *(const short8v*)&lds[((c >> 1) * EB + row) * 64 + sP * 8];
        }
        #pragma unroll
        for (int rt = 0; rt < 4; ++rt) {
            acc2[rt][0] = __builtin_amdgcn_mfma_f32_16x16x32_bf16(a[rt], b0, acc2[rt][0], 0, 0, 0);
            acc2[rt][1] = __builtin_amdgcn_mfma_f32_16x16x32_bf16(a[rt], b1, acc2[rt][1], 0, 0, 0);
        }
    }

    #pragma unroll
    for (int rt = 0; rt < 4; ++rt)
        #pragma unroll
        for (int r = 0; r < 4; ++r) {
            const int e  = rt * 16 + g * 4 + r;
            const int ge = e0 + e;
            const int dg = s_dst[e];
            #pragma unroll
            for (int j = 0; j < 2; ++j) {
                float v  = acc2[rt][j][r];
                float vn = __shfl_xor(v, 1, 64);
                if (even && ge < E) {
                    unsigned int pk2 = (unsigned)f2bf(v) | ((unsigned)f2bf(vn) << 16);
                    ushort_t* p = msum + (size_t)dg * D + wv * 32 + j * 16 + col;
                    asm volatile("global_atomic_pk_add_bf16 %0, %1, off"
                                 :: "v"(p), "v"(pk2) : "memory");
                }
            }
        }
}

extern "C" void kernel_launch(void* const* d_in, const int* in_sizes, int n_in,
                              void* d_out, int out_size, void* d_ws, size_t ws_size,
                              hipStream_t stream) {
    const float* f   = (const float*)d_in[0];
    const float* x   = (const float*)d_in[1];
    const float* w   = (const float*)d_in[2];
    const int*   src = (const int*)d_in[3];
    const int*   dst = (const int*)d_in[4];
    const float* Wm1 = (const float*)d_in[5];
    const float* bm1 = (const float*)d_in[6];
    const float* Wm2 = (const float*)d_in[7];
    const float* bm2 = (const float*)d_in[8];
    const float* Wu1 = (const float*)d_in[9];
    const float* bu1 = (const float*)d_in[10];
    const float* Wu2 = (const float*)d_in[11];
    const float* bu2 = (const float*)d_in[12];

    const int Nn = in_sizes[0] / D;
    const int E  = in_sizes[3];

    const size_t wbytes = (size_t)(128 * KP1 + HD * D) * sizeof(ushort_t);
    auto align512 = [](size_t v) { return (v + 511) & ~(size_t)511; };

    const size_t fb_bytes = (size_t)Nn * D * 2;
    char* wsb = (char*)d_ws;

    // ---------------- primary: fused-reduce CSR layout ----------------
    size_t off = 0;
    const size_t o_w    = off; off = align512(off + wbytes);
    const size_t o_fb   = off; off = align512(off + fb_bytes);
    const size_t o_cnt  = off; off = align512(off + (size_t)Nn * 4);
    const size_t o_roff = off; off = align512(off + (size_t)Nn * 4);
    const size_t o_cur  = off; off = align512(off + (size_t)Nn * 4);
    const size_t o_perm = off; off = align512(off + (size_t)E * 4);
    const size_t o_sdst = off; off = align512(off + (size_t)E * 4);
    const size_t o_ms   = off; off = align512(off + (size_t)Nn * D * 4);
    const size_t primary_total = off;

    if (ws_size >= primary_total) {
        ushort_t* W1p = (ushort_t*)(wsb + o_w);
        ushort_t* W2p = W1p + 128 * KP1;
        ushort_t* fbf = (ushort_t*)(wsb + o_fb);
        int* cnt      = (int*)(wsb + o_cnt);
        int* roff     = (int*)(wsb + o_roff);
        int* cursor   = (int*)(wsb + o_cur);
        int* perm     = (int*)(wsb + o_perm);
        int* sdst     = (int*)(wsb + o_sdst);
        float* msum   = (float*)(wsb + o_ms);

        const int n8 = Nn * D / 8;
        const int nq = Nn * D / 4;
        hipMemsetAsync(cnt, 0, (size_t)Nn * 4, stream);
        fused_pre_kernel<<<dim3(1024), dim3(256), 0, stream>>>(
            Wm1, Wm2, W1p, W2p, f, fbf, dst, cnt, msum, n8, E, nq);
        scan_kernel<<<dim3(1), dim3(1024), 0, stream>>>(cnt, roff, cursor, Nn);
        scatter_kernel<<<dim3((E + 255) / 256), dim3(256), 0, stream>>>(dst, cursor, perm, sdst, E);
        edge_mfma_fused_kernel<<<dim3((E + EB - 1) / EB), dim3(NT), 0, stream>>>(
            fbf, x, w, src, perm, sdst, W1p, bm1, W2p, bm2, msum, E);
        node_kernel<false><<<dim3((Nn + NB - 1) / NB), dim3(NT), 0, stream>>>(
            f, msum, Wu1, bu1, Wu2, bu2, (float*)d_out, Nn);
        return;
    }

    // ---------------- fallback: pk-atomic path ----------------
    size_t off2 = 0;
    const size_t p_w  = off2; off2 = align512(off2 + wbytes);
    const size_t p_fb = off2; off2 = align512(off2 + fb_bytes);
    const size_t p_ms = off2; off2 = align512(off2 + (size_t)Nn * D * 2);
    if (ws_size >= off2) {
        ushort_t* W1p  = (ushort_t*)(wsb + p_w);
        ushort_t* W2p  = W1p + 128 * KP1;
        ushort_t* fbf  = (ushort_t*)(wsb + p_fb);
        ushort_t* msum = (ushort_t*)(wsb + p_ms);
        const int rp_elems = 128 * KP1 + HD * D;
        hipMemsetAsync(msum, 0, (size_t)Nn * D * 2, stream);
        repack_kernel<<<dim3((rp_elems + 255) / 256), dim3(256), 0, stream>>>(Wm1, Wm2, W1p, W2p);
        const int n8 = Nn * D / 8;
        fconv_kernel<<<dim3((n8 + 255) / 256), dim3(256), 0, stream>>>(f, fbf, n8);
        edge_mfma_kernel<<<dim3((E + EB - 1) / EB), dim3(NT), 0, stream>>>(
            fbf, x, w, src, dst, W1p, bm1, W2p, bm2, msum, E);
        node_kernel<true><<<dim3((Nn + NB - 1) / NB), dim3(NT), 0, stream>>>(
            f, msum, Wu1, bu1, Wu2, bu2, (float*)d_out, Nn);
        return;
    }
}

// Round 11
// 409.951 us; speedup vs baseline: 1.4010x; 1.1472x over previous
//
#include <hip/hip_runtime.h>

#define D 128
#define HD 128
#define DE 16
#define MSG_IN 273
#define EB 64        // edges per block (mfma path)
#define NT 256
#define KP1 288      // padded msg K = 9 chunks of 32
#define NCH1 9
#define NCH2 4
#define NB 32
#define HID_PAD 132
#define CH8 (4 * EB * 64)   // ushort offset of chunk-8 region in lds[]

typedef __attribute__((ext_vector_type(8))) short short8v;
typedef __attribute__((ext_vector_type(4))) float f32x4;
typedef unsigned short ushort_t;

#define GLOAD_LDS16(gp, lp) \
    __builtin_amdgcn_global_load_lds((const __attribute__((address_space(1))) unsigned int*)(gp), \
                                     (__attribute__((address_space(3))) unsigned int*)(lp), 16, 0, 0)

__device__ __forceinline__ unsigned short f2bf(float v) {
    unsigned int u = __builtin_bit_cast(unsigned int, v);
    u += 0x7fffu + ((u >> 16) & 1u);
    return (unsigned short)(u >> 16);
}
__device__ __forceinline__ float bf2f(ushort_t u) {
    return __builtin_bit_cast(float, (unsigned int)u << 16);
}
__device__ __forceinline__ unsigned int cvt_pk_bf16(float lo, float hi) {
    unsigned int r;
    asm("v_cvt_pk_bf16_f32 %0, %1, %2" : "=v"(r) : "v"(lo), "v"(hi));
    return r;
}

// ---------------- fused prepass: weight repack + f->bf16 + dst hist + msum zero ----------------
__global__ void fused_pre_kernel(const float* __restrict__ Wm1, const float* __restrict__ Wm2,
                                 ushort_t* __restrict__ W1p, ushort_t* __restrict__ W2p,
                                 const float* __restrict__ f, ushort_t* __restrict__ fb,
                                 const int* __restrict__ dst, int* __restrict__ cnt,
                                 float* __restrict__ msum,
                                 int n8, int E, int nq) {
    const int gid    = blockIdx.x * 256 + threadIdx.x;
    const int stride = gridDim.x * 256;
    const int rp1 = 128 * KP1;
    const int rp_elems = rp1 + HD * D;
    for (int i = gid; i < rp_elems; i += stride) {
        if (i < rp1) {
            int n = i / KP1, k = i % KP1;
            W1p[i] = f2bf((k < MSG_IN) ? Wm1[(size_t)k * HD + n] : 0.f);
        } else {
            int i2 = i - rp1;
            int n = i2 / HD, k = i2 % HD;
            W2p[i2] = f2bf(Wm2[(size_t)k * D + n]);
        }
    }
    for (int i = gid; i < n8; i += stride) {
        float4 v0 = *(const float4*)(f + (size_t)i * 8);
        float4 v1 = *(const float4*)(f + (size_t)i * 8 + 4);
        union { ushort_t us[8]; short8v v; } pk;
        pk.us[0] = f2bf(v0.x); pk.us[1] = f2bf(v0.y);
        pk.us[2] = f2bf(v0.z); pk.us[3] = f2bf(v0.w);
        pk.us[4] = f2bf(v1.x); pk.us[5] = f2bf(v1.y);
        pk.us[6] = f2bf(v1.z); pk.us[7] = f2bf(v1.w);
        *(short8v*)(fb + (size_t)i * 8) = pk.v;
    }
    for (int i = gid; i < E; i += stride) atomicAdd(&cnt[dst[i]], 1);
    float4 z = {0.f, 0.f, 0.f, 0.f};
    for (int i = gid; i < nq; i += stride) *(float4*)(msum + (size_t)i * 4) = z;
}

// ---------------- CSR build: parallel scan (4 elems/thread) -> scatter ----------------
__global__ __launch_bounds__(1024) void scan_kernel(const int* __restrict__ cnt,
                                                    int* __restrict__ roff,
                                                    int* __restrict__ cursor, int Nn) {
    __shared__ int wsum[16];
    const int t = threadIdx.x, l = t & 63, wid = t >> 6;
    int running = 0;
    for (int base = 0; base < Nn; base += 4096) {
        const int i0 = base + t * 4;
        int v0 = 0, v1 = 0, v2 = 0, v3 = 0;
        if (i0 + 3 < Nn) {
            int4 v = *(const int4*)(cnt + i0);
            v0 = v.x; v1 = v.y; v2 = v.z; v3 = v.w;
        } else {
            if (i0 + 0 < Nn) v0 = cnt[i0 + 0];
            if (i0 + 1 < Nn) v1 = cnt[i0 + 1];
            if (i0 + 2 < Nn) v2 = cnt[i0 + 2];
        }
        const int vsum = v0 + v1 + v2 + v3;
        int s = vsum;
        #pragma unroll
        for (int off = 1; off < 64; off <<= 1) {
            int u = __shfl_up(s, off, 64);
            if (l >= off) s += u;
        }
        if (l == 63) wsum[wid] = s;
        __syncthreads();
        if (wid == 0 && l < 16) {
            int xv = wsum[l];
            #pragma unroll
            for (int off = 1; off < 16; off <<= 1) {
                int u = __shfl_up(xv, off, 64);
                if (l >= off) xv += u;
            }
            wsum[l] = xv;
        }
        __syncthreads();
        const int prev  = (wid > 0) ? wsum[wid - 1] : 0;
        const int total = wsum[15];
        int ex = running + prev + (s - vsum);
        if (i0 + 0 < Nn) { roff[i0 + 0] = ex; cursor[i0 + 0] = ex; } ex += v0;
        if (i0 + 1 < Nn) { roff[i0 + 1] = ex; cursor[i0 + 1] = ex; } ex += v1;
        if (i0 + 2 < Nn) { roff[i0 + 2] = ex; cursor[i0 + 2] = ex; } ex += v2;
        if (i0 + 3 < Nn) { roff[i0 + 3] = ex; cursor[i0 + 3] = ex; }
        running += total;
        __syncthreads();
    }
}

__global__ void scatter_kernel(const int* __restrict__ dst, int* cursor,
                               int* __restrict__ perm, int* __restrict__ sdst, int E) {
    int i = blockIdx.x * 256 + threadIdx.x;
    if (i < E) {
        int d = dst[i];
        int s = atomicAdd(&cursor[d], 1);
        perm[s] = i;
        sdst[s] = d;
    }
}

// ---------------- edge kernel v11: fused in-register segment reduce, ballot run-meta ----------------
__global__ __launch_bounds__(NT, 4) void edge_mfma_fused_kernel(
    const ushort_t* __restrict__ fbf, const float* __restrict__ x,
    const float* __restrict__ w, const int* __restrict__ src,
    const int* __restrict__ perm, const int* __restrict__ sdst,
    const ushort_t* __restrict__ W1p, const float* __restrict__ bm1,
    const ushort_t* __restrict__ W2p, const float* __restrict__ bm2,
    float* __restrict__ msum, int E)
{
    __shared__ __align__(16) ushort_t lds[4 * EB * 64 + EB * 32];  // 36,864 B

    const int t    = threadIdx.x;
    const int lane = t & 63;
    const int wv   = t >> 6;
    const int e0   = blockIdx.x * EB;

    // per-lane sorted-dst (issued early; used by the register reduce at the end)
    const int myd  = (e0 + lane < E) ? sdst[e0 + lane] : -1;
    const int prevd = (e0 > 0) ? sdst[e0 - 1] : -2;
    const int nextd = (e0 + EB < E) ? sdst[e0 + EB] : -2;

    // ---- f staging: 8 x global_load_lds_dwordx4, pre-swizzled global source ----
    {
        const int el8 = lane >> 3;
        const int s   = lane & 7;
        const int sl  = s ^ el8;            // involution swizzle
        const int slA = min(e0 + wv * 16 + el8,     E - 1);
        const int slB = min(e0 + wv * 16 + 8 + el8, E - 1);
        const int geA = perm[slA], geB = perm[slB];
        const int nsA = src[geA], ndA = sdst[slA];
        const int nsB = src[geB], ndB = sdst[slB];
        #pragma unroll
        for (int p = 0; p < 4; ++p) {
            const int n0 = (p < 2) ? nsA : ndA;
            const int n1 = (p < 2) ? nsB : ndB;
            const ushort_t* g0 = fbf + (size_t)n0 * D + (p & 1) * 64 + sl * 8;
            const ushort_t* g1 = fbf + (size_t)n1 * D + (p & 1) * 64 + sl * 8;
            GLOAD_LDS16(g0, &lds[(p * EB + wv * 16    ) * 64]);
            GLOAD_LDS16(g1, &lds[(p * EB + wv * 16 + 8) * 64]);
        }
    }
    // ---- chunk 8: w feats (k0..15), sqd (k16), zeros; 2-bit swizzle ----
    {
        const int el = lane >> 2, q = lane & 3;
        const int qp = q ^ (el & 3);
        const int slot = e0 + wv * 16 + el;
        const bool ok = slot < E;
        const int sc = min(slot, E - 1);
        const int ge = perm[sc];
        union { ushort_t us[8]; short8v v; } pk;
        #pragma unroll
        for (int j = 0; j < 8; ++j) pk.us[j] = 0;
        if (ok) {
            if (q < 2) {
                float4 w0 = *(const float4*)(w + (size_t)ge * DE + q * 8);
                float4 w1 = *(const float4*)(w + (size_t)ge * DE + q * 8 + 4);
                pk.us[0] = f2bf(w0.x); pk.us[1] = f2bf(w0.y);
                pk.us[2] = f2bf(w0.z); pk.us[3] = f2bf(w0.w);
                pk.us[4] = f2bf(w1.x); pk.us[5] = f2bf(w1.y);
                pk.us[6] = f2bf(w1.z); pk.us[7] = f2bf(w1.w);
            } else if (q == 2) {
                const int ns = src[ge], nd = sdst[sc];
                float dx = x[ns*3+0] - x[nd*3+0];
                float dy = x[ns*3+1] - x[nd*3+1];
                float dz = x[ns*3+2] - x[nd*3+2];
                pk.us[0] = f2bf(dx*dx + dy*dy + dz*dz);
            }
        }
        *(short8v*)&lds[CH8 + (wv * 16 + el) * 32 + qp * 8] = pk.v;
    }

    const int col = lane & 15;
    const int g   = lane >> 4;

    const size_t wrow0 = (size_t)(wv * 32 + col) * KP1;
    const size_t wrow1 = (size_t)(wv * 32 + 16 + col) * KP1;
    short8v nb0 = *(const short8v*)&W1p[wrow0 + g * 8];
    short8v nb1 = *(const short8v*)&W1p[wrow1 + g * 8];

    __syncthreads();   // B0: staging complete

    // ---- layer 1: [64,288] x [288,32] per wave ----
    f32x4 acc[4][2];
    {
        float bv0 = bm1[wv * 32 + col];
        float bv1 = bm1[wv * 32 + 16 + col];
        #pragma unroll
        for (int rt = 0; rt < 4; ++rt) {
            acc[rt][0] = (f32x4){bv0, bv0, bv0, bv0};
            acc[rt][1] = (f32x4){bv1, bv1, bv1, bv1};
        }
    }
    #pragma unroll
    for (int c = 0; c < NCH1; ++c) {
        short8v b0 = nb0, b1 = nb1;
        if (c + 1 < NCH1) {
            nb0 = *(const short8v*)&W1p[wrow0 + (c + 1) * 32 + g * 8];
            nb1 = *(const short8v*)&W1p[wrow1 + (c + 1) * 32 + g * 8];
        }
        short8v a[4];
        #pragma unroll
        for (int rt = 0; rt < 4; ++rt) {
            const int row = rt * 16 + col;
            if (c < 8) {
                const int sP = (((c & 1) << 2) + g) ^ (row & 7);
                a[rt] = *(const short8v*)&lds[((c >> 1) * EB + row) * 64 + sP * 8];
            } else {
                const int sP = g ^ (row & 3);
                a[rt] = *(const short8v*)&lds[CH8 + row * 32 + sP * 8];
            }
        }
        #pragma unroll
        for (int rt = 0; rt < 4; ++rt) {
            acc[rt][0] = __builtin_amdgcn_mfma_f32_16x16x32_bf16(a[rt], b0, acc[rt][0], 0, 0, 0);
            acc[rt][1] = __builtin_amdgcn_mfma_f32_16x16x32_bf16(a[rt], b1, acc[rt][1], 0, 0, 0);
        }
    }
    __syncthreads();   // B1

    // hid (relu, bf16, cvt_pk pair-packed b32) -> pairs 0-1 region, same swizzle
    const bool even = (col & 1) == 0;
    const int ph = wv >> 1;
    #pragma unroll
    for (int rt = 0; rt < 4; ++rt)
        #pragma unroll
        for (int j = 0; j < 2; ++j)
            #pragma unroll
            for (int r = 0; r < 4; ++r) {
                const int row = rt * 16 + g * 4 + r;
                float v  = fmaxf(acc[rt][j][r], 0.f);
                float vn = __shfl_xor(v, 1, 64);
                if (even) {
                    unsigned int pk2 = cvt_pk_bf16(v, vn);
                    const int sH = (((wv & 1) << 2) + j * 2 + (col >> 3)) ^ (row & 7);
                    *(unsigned int*)&lds[(ph * EB + row) * 64 + sH * 8 + (col & 7)] = pk2;
                }
            }
    __syncthreads();   // B2

    // ---- layer 2: [64,128] x [128,32] per wave ----
    const size_t w2r0 = (size_t)(wv * 32 + col) * HD;
    const size_t w2r1 = (size_t)(wv * 32 + 16 + col) * HD;
    short8v m0 = *(const short8v*)&W2p[w2r0 + g * 8];
    short8v m1 = *(const short8v*)&W2p[w2r1 + g * 8];
    f32x4 acc2[4][2];
    {
        float bv0 = bm2[wv * 32 + col];
        float bv1 = bm2[wv * 32 + 16 + col];
        #pragma unroll
        for (int rt = 0; rt < 4; ++rt) {
            acc2[rt][0] = (f32x4){bv0, bv0, bv0, bv0};
            acc2[rt][1] = (f32x4){bv1, bv1, bv1, bv1};
        }
    }
    #pragma unroll
    for (int c = 0; c < NCH2; ++c) {
        short8v b0 = m0, b1 = m1;
        if (c + 1 < NCH2) {
            m0 = *(const short8v*)&W2p[w2r0 + (c + 1) * 32 + g * 8];
            m1 = *(const short8v*)&W2p[w2r1 + (c + 1) * 32 + g * 8];
        }
        short8v a[4];
        #pragma unroll
        for (int rt = 0; rt < 4; ++rt) {
            const int row = rt * 16 + col;
            const int sP = (((c & 1) << 2) + g) ^ (row & 7);
            a[rt] = *(const short8v*)&lds[((c >> 1) * EB + row) * 64 + sP * 8];
        }
        #pragma unroll
        for (int rt = 0; rt < 4; ++rt) {
            acc2[rt][0] = __builtin_amdgcn_mfma_f32_16x16x32_bf16(a[rt], b0, acc2[rt][0], 0, 0, 0);
            acc2[rt][1] = __builtin_amdgcn_mfma_f32_16x16x32_bf16(a[rt], b1, acc2[rt][1], 0, 0, 0);
        }
    }

    // ---- wave-local segment reduce -> msum (f32); ballot-derived run metadata ----
    float qs[4][2];
    #pragma unroll
    for (int rt = 0; rt < 4; ++rt) {
        qs[rt][0] = (acc2[rt][0][0] + acc2[rt][0][1]) + (acc2[rt][0][2] + acc2[rt][0][3]);
        qs[rt][1] = (acc2[rt][1][0] + acc2[rt][1][1]) + (acc2[rt][1][2] + acc2[rt][1][3]);
    }
    const int nvalid = min(EB, E - e0);
    const int dprev_l = __shfl_up(myd, 1, 64);
    const bool head = (lane == 0) || (myd != dprev_l);
    unsigned long long rem = __ballot(head && (lane < nvalid));
    while (rem) {
        const int beg = (int)__builtin_ctzll(rem);
        rem &= rem - 1;
        const int end = rem ? (int)__builtin_ctzll(rem) : nvalid;
        const int dg  = __shfl(myd, beg, 64);

        float s0 = 0.f, s1 = 0.f;
        #pragma unroll
        for (int rt = 0; rt < 4; ++rt) {
            const int qb = rt * 16 + g * 4;
            const int lo = max(qb, beg);
            const int hi = min(qb + 4, end);
            if (lo < hi) {
                if (lo == qb && hi == qb + 4) {
                    s0 += qs[rt][0]; s1 += qs[rt][1];
                } else {
                    #pragma unroll
                    for (int r = 0; r < 4; ++r) {
                        const int sl = qb + r;
                        if (sl >= beg && sl < end) {
                            s0 += acc2[rt][0][r]; s1 += acc2[rt][1][r];
                        }
                    }
                }
            }
        }
        s0 += __shfl_xor(s0, 16, 64); s0 += __shfl_xor(s0, 32, 64);
        s1 += __shfl_xor(s1, 16, 64); s1 += __shfl_xor(s1, 32, 64);
        if (g == 0) {
            const bool bnd = (beg == 0 && dg == prevd) || (end == nvalid && dg == nextd);
            float* p = msum + (size_t)dg * D + wv * 32 + col;
            if (bnd) { atomicAdd(p, s0); atomicAdd(p + 16, s1); }
            else     { p[0] = s0; p[16] = s1; }
        }
    }
}

// ---------------- node kernel: update MLP (fp32 compute, templated msum dtype) ----------------
template<bool MB16>
__global__ __launch_bounds__(NT, 4) void node_kernel(
    const float* __restrict__ f, const void* __restrict__ msum_v,
    const float* __restrict__ Wu1, const float* __restrict__ bu1,
    const float* __restrict__ Wu2, const float* __restrict__ bu2,
    float* out, int Nn)
{
    __shared__ __align__(16) float hin[NB][HID_PAD];
    __shared__ __align__(16) float hid[NB][HID_PAD];
    const int t  = threadIdx.x;
    const int n0 = blockIdx.x * NB;
    const int nn = min(NB, Nn - n0);

    {
        const int half = t >> 7, tt = t & 127;
        for (int e = half; e < nn; e += 2) {
            size_t off = (size_t)(n0 + e) * D + tt;
            float mv = MB16 ? bf2f(((const ushort_t*)msum_v)[off])
                            : ((const float*)msum_v)[off];
            hin[e][tt] = mv + f[off];
        }
    }
    __syncthreads();

    const int tc = t & 15, te2 = (t >> 4) * 2, c0 = tc * 8;
    float a1[2][8];
    #pragma unroll
    for (int c = 0; c < 8; ++c) { float bv = bu1[c0 + c]; a1[0][c] = bv; a1[1][c] = bv; }
    for (int i = 0; i < D; i += 4) {
        float m0[4], m1[4];
        *(float4*)m0 = *(const float4*)&hin[te2][i];
        *(float4*)m1 = *(const float4*)&hin[te2 + 1][i];
        #pragma unroll
        for (int r = 0; r < 4; ++r) {
            float wr[8];
            *(float4*)&wr[0] = *(const float4*)(Wu1 + (size_t)(i + r) * HD + c0);
            *(float4*)&wr[4] = *(const float4*)(Wu1 + (size_t)(i + r) * HD + c0 + 4);
            #pragma unroll
            for (int c = 0; c < 8; ++c) { a1[0][c] += m0[r]*wr[c]; a1[1][c] += m1[r]*wr[c]; }
        }
    }
    #pragma unroll
    for (int j = 0; j < 2; ++j) {
        float v[8];
        #pragma unroll
        for (int c = 0; c < 8; ++c) v[c] = fmaxf(a1[j][c], 0.f);
        *(float4*)&hid[te2 + j][c0] = *(float4*)&v[0];
        *(float4*)&hid[te2 + j][c0 + 4] = *(float4*)&v[4];
    }
    __syncthreads();
    float a2[2][8];
    #pragma unroll
    for (int c = 0; c < 8; ++c) { float bv = bu2[c0 + c]; a2[0][c] = bv; a2[1][c] = bv; }
    for (int h = 0; h < HD; h += 4) {
        float m0[4], m1[4];
        *(float4*)m0 = *(const float4*)&hid[te2][h];
        *(float4*)m1 = *(const float4*)&hid[te2 + 1][h];
        #pragma unroll
        for (int r = 0; r < 4; ++r) {
            float wr[8];
            *(float4*)&wr[0] = *(const float4*)(Wu2 + (size_t)(h + r) * D + c0);
            *(float4*)&wr[4] = *(const float4*)(Wu2 + (size_t)(h + r) * D + c0 + 4);
            #pragma unroll
            for (int c = 0; c < 8; ++c) { a2[0][c] += m0[r]*wr[c]; a2[1][c] += m1[r]*wr[c]; }
        }
    }
    #pragma unroll
    for (int j = 0; j < 2; ++j) {
        int e = te2 + j, gn = n0 + e;
        if (e < nn) {
            *(float4*)(out + (size_t)gn * D + c0) = *(float4*)&a2[j][0];
            *(float4*)(out + (size_t)gn * D + c0 + 4) = *(float4*)&a2[j][4];
        }
    }
}

// ================= fallback kernels (pk-atomic path; no CSR) =================

__global__ void repack_kernel(const float* __restrict__ Wm1, const float* __restrict__ Wm2,
                              ushort_t* __restrict__ W1p, ushort_t* __restrict__ W2p) {
    int idx = blockIdx.x * 256 + threadIdx.x;
    const int n1 = 128 * KP1;
    if (idx < n1) {
        int n = idx / KP1, k = idx % KP1;
        W1p[idx] = f2bf((k < MSG_IN) ? Wm1[(size_t)k * HD + n] : 0.f);
    } else {
        int i2 = idx - n1;
        if (i2 < HD * D) {
            int n = i2 / HD, k = i2 % HD;
            W2p[i2] = f2bf(Wm2[(size_t)k * D + n]);
        }
    }
}

__global__ void fconv_kernel(const float* __restrict__ f, ushort_t* __restrict__ fb, int n8) {
    int i = blockIdx.x * 256 + threadIdx.x;
    if (i < n8) {
        float4 v0 = *(const float4*)(f + (size_t)i * 8);
        float4 v1 = *(const float4*)(f + (size_t)i * 8 + 4);
        union { ushort_t us[8]; short8v v; } pk;
        pk.us[0] = f2bf(v0.x); pk.us[1] = f2bf(v0.y);
        pk.us[2] = f2bf(v0.z); pk.us[3] = f2bf(v0.w);
        pk.us[4] = f2bf(v1.x); pk.us[5] = f2bf(v1.y);
        pk.us[6] = f2bf(v1.z); pk.us[7] = f2bf(v1.w);
        *(short8v*)(fb + (size_t)i * 8) = pk.v;
    }
}

__global__ __launch_bounds__(NT, 4) void edge_mfma_kernel(
    const ushort_t* __restrict__ fbf, const float* __restrict__ x,
    const float* __restrict__ w, const int* __restrict__ src,
    const int* __restrict__ dst,
    const ushort_t* __restrict__ W1p, const float* __restrict__ bm1,
    const ushort_t* __restrict__ W2p, const float* __restrict__ bm2,
    ushort_t* msum, int E)
{
    __shared__ __align__(16) ushort_t lds[4 * EB * 64 + EB * 32];
    __shared__ int s_dst[EB];

    const int t    = threadIdx.x;
    const int lane = t & 63;
    const int wv   = t >> 6;
    const int e0   = blockIdx.x * EB;

    if (t < EB) s_dst[t] = (e0 + t < E) ? dst[e0 + t] : 0;
    {
        const int el8 = lane >> 3;
        const int s   = lane & 7;
        const int sl  = s ^ el8;
        const int geA = min(e0 + wv * 16 + el8,     E - 1);
        const int geB = min(e0 + wv * 16 + 8 + el8, E - 1);
        const int nsA = src[geA], ndA = dst[geA];
        const int nsB = src[geB], ndB = dst[geB];
        #pragma unroll
        for (int p = 0; p < 4; ++p) {
            const int n0 = (p < 2) ? nsA : ndA;
            const int n1 = (p < 2) ? nsB : ndB;
            const ushort_t* g0 = fbf + (size_t)n0 * D + (p & 1) * 64 + sl * 8;
            const ushort_t* g1 = fbf + (size_t)n1 * D + (p & 1) * 64 + sl * 8;
            GLOAD_LDS16(g0, &lds[(p * EB + wv * 16    ) * 64]);
            GLOAD_LDS16(g1, &lds[(p * EB + wv * 16 + 8) * 64]);
        }
    }
    {
        const int el = lane >> 2, q = lane & 3;
        const int qp = q ^ (el & 3);
        const int ge = e0 + wv * 16 + el;
        const bool ok = ge < E;
        const int gc = min(ge, E - 1);
        union { ushort_t us[8]; short8v v; } pk;
        #pragma unroll
        for (int j = 0; j < 8; ++j) pk.us[j] = 0;
        if (ok) {
            if (q < 2) {
                float4 w0 = *(const float4*)(w + (size_t)gc * DE + q * 8);
                float4 w1 = *(const float4*)(w + (size_t)gc * DE + q * 8 + 4);
                pk.us[0] = f2bf(w0.x); pk.us[1] = f2bf(w0.y);
                pk.us[2] = f2bf(w0.z); pk.us[3] = f2bf(w0.w);
                pk.us[4] = f2bf(w1.x); pk.us[5] = f2bf(w1.y);
                pk.us[6] = f2bf(w1.z); pk.us[7] = f2bf(w1.w);
            } else if (q == 2) {
                const int ns = src[gc], nd = dst[gc];
                float dx = x[ns*3+0] - x[nd*3+0];
                float dy = x[ns*3+1] - x[nd*3+1];
                float dz = x[ns*3+2] - x[nd*3+2];
                pk.us[0] = f2bf(dx*dx + dy*dy + dz*dz);
            }
        }
        *(short8v*)&lds[CH8 + (wv * 16 + el) * 32 + qp * 8] = pk.v;
    }

    const int col = lane & 15;
    const int g   = lane >> 4;
    const size_t wrow0 = (size_t)(wv * 32 + col) * KP1;
    const size_t wrow1 = (size_t)(wv * 32 + 16 + col) * KP1;
    short8v nb0 = *(const short8v*)&W1p[wrow0 + g * 8];
    short8v nb1 = *(const short8v*)&W1p[wrow1 + g * 8];
    __syncthreads();

    f32x4 acc[4][2];
    {
        float bv0 = bm1[wv * 32 + col];
        float bv1 = bm1[wv * 32 + 16 + col];
        #pragma unroll
        for (int rt = 0; rt < 4; ++rt) {
            acc[rt][0] = (f32x4){bv0, bv0, bv0, bv0};
            acc[rt][1] = (f32x4){bv1, bv1, bv1, bv1};
        }
    }
    #pragma unroll
    for (int c = 0; c < NCH1; ++c) {
        short8v b0 = nb0, b1 = nb1;
        if (c + 1 < NCH1) {
            nb0 = *(const short8v*)&W1p[wrow0 + (c + 1) * 32 + g * 8];
            nb1 = *(const short8v*)&W1p[wrow1 + (c + 1) * 32 + g * 8];
        }
        short8v a[4];
        #pragma unroll
        for (int rt = 0; rt < 4; ++rt) {
            const int row = rt * 16 + col;
            if (c < 8) {
                const int sP = (((c & 1) << 2) + g) ^ (row & 7);
                a[rt] = *(const short8v*)&lds[((c >> 1) * EB + row) * 64 + sP * 8];
            } else {
                const int sP = g ^ (row & 3);
                a[rt] = *(const short8v*)&lds[CH8 + row * 32 + sP * 8];
            }
        }
        #pragma unroll
        for (int rt = 0; rt < 4; ++rt) {
            acc[rt][0] = __builtin_amdgcn_mfma_f32_16x16x32_bf16(a[rt], b0, acc[rt][0], 0, 0, 0);
            acc[rt][1] = __builtin_amdgcn_mfma_f32_16x16x32_bf16(a[rt], b1, acc[rt][1], 0, 0, 0);
        }
    }
    __syncthreads();

    const bool even = (col & 1) == 0;
    const int ph = wv >> 1;
    #pragma unroll
    for (int rt = 0; rt < 4; ++rt)
        #pragma unroll
        for (int j = 0; j < 2; ++j)
            #pragma unroll
            for (int r = 0; r < 4; ++r) {
                const int row = rt * 16 + g * 4 + r;
                float v  = fmaxf(acc[rt][j][r], 0.f);
                float vn = __shfl_xor(v, 1, 64);
                if (even) {
                    unsigned int pk2 = cvt_pk_bf16(v, vn);
                    const int sH = (((wv & 1) << 2) + j * 2 + (col >> 3)) ^ (row & 7);
                    *(unsigned int*)&lds[(ph * EB + row) * 64 + sH * 8 + (col & 7)] = pk2;
                }
            }
    __syncthreads();

    const size_t w2r0 = (size_t)(wv * 32 + col) * HD;
    const size_t w2r1 = (size_t)(wv * 32 + 16 + col) * HD;
    short8v m0 = *(const short8v*)&W2p[w2r0 + g * 8];
    short8v m1 = *(const short8v*)&W2p[w2r1 + g * 8];
    f32x4 acc2[4][2];
    {
        float bv0 = bm2[wv * 32 + col];
        float bv1 = bm2[wv * 32 + 16 + col];
        #pragma unroll
        for (int rt = 0; rt < 4; ++rt) {
            acc2[rt][0] = (f32x4){bv0, bv0, bv0, bv0};
            acc2[rt][1] = (f32x4){bv1, bv1, bv1, bv1};
        }
    }
    #pragma unroll
    for (int c = 0; c < NCH2; ++c) {
        short8v b0 = m0, b1 = m1;
        if (c + 1 < NCH2) {
            m0 = *(const short8v*)&W2p[w2r0 + (c + 1) * 32 + g * 8];
            m1 = *(const short8v*)&W2p[w2r1 + (c + 1) * 32 + g * 8];
        }
        short8v a[4];
        #pragma unroll
        for (int rt = 0; rt < 4; ++rt) {
            const int row = rt * 16 + col;
            const int sP = (((c & 1) << 2) + g) ^ (row & 7);
            a[rt] = *(const short8v*)&lds[((c >> 1) * EB + row) * 64 + sP * 8];
        }
        #pragma unroll
        for (int rt = 0; rt < 4; ++rt) {
            acc2[rt][0] = __builtin_amdgcn_mfma_f32_16x16x32_bf16(a[rt], b0, acc2[rt][0], 0, 0, 0);
            acc2[rt][1] = __builtin_amdgcn_mfma_f32_16x16x32_bf16(a[rt], b1, acc2[rt][1], 0, 0, 0);
        }
    }

    #pragma unroll
    for (int rt = 0; rt < 4; ++rt)
        #pragma unroll
        for (int r = 0; r < 4; ++r) {
            const int e  = rt * 16 + g * 4 + r;
            const int ge = e0 + e;
            const int dg = s_dst[e];
            #pragma unroll
            for (int j = 0; j < 2; ++j) {
                float v  = acc2[rt][j][r];
                float vn = __shfl_xor(v, 1, 64);
                if (even && ge < E) {
                    unsigned int pk2 = cvt_pk_bf16(v, vn);
                    ushort_t* p = msum + (size_t)dg * D + wv * 32 + j * 16 + col;
                    asm volatile("global_atomic_pk_add_bf16 %0, %1, off"
                                 :: "v"(p), "v"(pk2) : "memory");
                }
            }
        }
}

extern "C" void kernel_launch(void* const* d_in, const int* in_sizes, int n_in,
                              void* d_out, int out_size, void* d_ws, size_t ws_size,
                              hipStream_t stream) {
    const float* f   = (const float*)d_in[0];
    const float* x   = (const float*)d_in[1];
    const float* w   = (const float*)d_in[2];
    const int*   src = (const int*)d_in[3];
    const int*   dst = (const int*)d_in[4];
    const float* Wm1 = (const float*)d_in[5];
    const float* bm1 = (const float*)d_in[6];
    const float* Wm2 = (const float*)d_in[7];
    const float* bm2 = (const float*)d_in[8];
    const float* Wu1 = (const float*)d_in[9];
    const float* bu1 = (const float*)d_in[10];
    const float* Wu2 = (const float*)d_in[11];
    const float* bu2 = (const float*)d_in[12];

    const int Nn = in_sizes[0] / D;
    const int E  = in_sizes[3];

    const size_t wbytes = (size_t)(128 * KP1 + HD * D) * sizeof(ushort_t);
    auto align512 = [](size_t v) { return (v + 511) & ~(size_t)511; };

    const size_t fb_bytes = (size_t)Nn * D * 2;
    char* wsb = (char*)d_ws;

    // ---------------- primary: fused-reduce CSR layout ----------------
    size_t off = 0;
    const size_t o_w    = off; off = align512(off + wbytes);
    const size_t o_fb   = off; off = align512(off + fb_bytes);
    const size_t o_cnt  = off; off = align512(off + (size_t)Nn * 4);
    const size_t o_roff = off; off = align512(off + (size_t)Nn * 4);
    const size_t o_cur  = off; off = align512(off + (size_t)Nn * 4);
    const size_t o_perm = off; off = align512(off + (size_t)E * 4);
    const size_t o_sdst = off; off = align512(off + (size_t)E * 4);
    const size_t o_ms   = off; off = align512(off + (size_t)Nn * D * 4);
    const size_t primary_total = off;

    if (ws_size >= primary_total) {
        ushort_t* W1p = (ushort_t*)(wsb + o_w);
        ushort_t* W2p = W1p + 128 * KP1;
        ushort_t* fbf = (ushort_t*)(wsb + o_fb);
        int* cnt      = (int*)(wsb + o_cnt);
        int* roff     = (int*)(wsb + o_roff);
        int* cursor   = (int*)(wsb + o_cur);
        int* perm     = (int*)(wsb + o_perm);
        int* sdst     = (int*)(wsb + o_sdst);
        float* msum   = (float*)(wsb + o_ms);

        const int n8 = Nn * D / 8;
        const int nq = Nn * D / 4;
        hipMemsetAsync(cnt, 0, (size_t)Nn * 4, stream);
        fused_pre_kernel<<<dim3(1024), dim3(256), 0, stream>>>(
            Wm1, Wm2, W1p, W2p, f, fbf, dst, cnt, msum, n8, E, nq);
        scan_kernel<<<dim3(1), dim3(1024), 0, stream>>>(cnt, roff, cursor, Nn);
        scatter_kernel<<<dim3((E + 255) / 256), dim3(256), 0, stream>>>(dst, cursor, perm, sdst, E);
        edge_mfma_fused_kernel<<<dim3((E + EB - 1) / EB), dim3(NT), 0, stream>>>(
            fbf, x, w, src, perm, sdst, W1p, bm1, W2p, bm2, msum, E);
        node_kernel<false><<<dim3((Nn + NB - 1) / NB), dim3(NT), 0, stream>>>(
            f, msum, Wu1, bu1, Wu2, bu2, (float*)d_out, Nn);
        return;
    }

    // ---------------- fallback: pk-atomic path ----------------
    size_t off2 = 0;
    const size_t p_w  = off2; off2 = align512(off2 + wbytes);
    const size_t p_fb = off2; off2 = align512(off2 + fb_bytes);
    const size_t p_ms = off2; off2 = align512(off2 + (size_t)Nn * D * 2);
    if (ws_size >= off2) {
        ushort_t* W1p  = (ushort_t*)(wsb + p_w);
        ushort_t* W2p  = W1p + 128 * KP1;
        ushort_t* fbf  = (ushort_t*)(wsb + p_fb);
        ushort_t* msum = (ushort_t*)(wsb + p_ms);
        const int rp_elems = 128 * KP1 + HD * D;
        hipMemsetAsync(msum, 0, (size_t)Nn * D * 2, stream);
        repack_kernel<<<dim3((rp_elems + 255) / 256), dim3(256), 0, stream>>>(Wm1, Wm2, W1p, W2p);
        const int n8 = Nn * D / 8;
        fconv_kernel<<<dim3((n8 + 255) / 256), dim3(256), 0, stream>>>(f, fbf, n8);
        edge_mfma_kernel<<<dim3((E + EB - 1) / EB), dim3(NT), 0, stream>>>(
            fbf, x, w, src, dst, W1p, bm1, W2p, bm2, msum, E);
        node_kernel<true><<<dim3((Nn + NB - 1) / NB), dim3(NT), 0, stream>>>(
            f, msum, Wu1, bu1, Wu2, bu2, (float*)d_out, Nn);
        return;
    }
}

// Round 12
// 404.840 us; speedup vs baseline: 1.4187x; 1.0126x over previous
//
#include <hip/hip_runtime.h>

#define D 128
#define HD 128
#define DE 16
#define MSG_IN 273
#define EB 64        // edges per block (mfma path)
#define NT 256
#define KP1 288      // padded msg K = 9 chunks of 32
#define NCH1 9
#define NCH2 4
#define NB 32
#define HID_PAD 132
#define CH8 (4 * EB * 64)   // ushort offset of chunk-8 region in lds[]

typedef __attribute__((ext_vector_type(8))) short short8v;
typedef __attribute__((ext_vector_type(4))) float f32x4;
typedef unsigned short ushort_t;

#define GLOAD_LDS16(gp, lp) \
    __builtin_amdgcn_global_load_lds((const __attribute__((address_space(1))) unsigned int*)(gp), \
                                     (__attribute__((address_space(3))) unsigned int*)(lp), 16, 0, 0)

__device__ __forceinline__ unsigned short f2bf(float v) {
    unsigned int u = __builtin_bit_cast(unsigned int, v);
    u += 0x7fffu + ((u >> 16) & 1u);
    return (unsigned short)(u >> 16);
}
__device__ __forceinline__ float bf2f(ushort_t u) {
    return __builtin_bit_cast(float, (unsigned int)u << 16);
}
__device__ __forceinline__ unsigned int cvt_pk_bf16(float lo, float hi) {
    unsigned int r;
    asm("v_cvt_pk_bf16_f32 %0, %1, %2" : "=v"(r) : "v"(lo), "v"(hi));
    return r;
}

// ---------------- fused prepass: weight repack + f->bf16 + dst hist + msum zero ----------------
__global__ void fused_pre_kernel(const float* __restrict__ Wm1, const float* __restrict__ Wm2,
                                 ushort_t* __restrict__ W1p, ushort_t* __restrict__ W2p,
                                 const float* __restrict__ f, ushort_t* __restrict__ fb,
                                 const int* __restrict__ dst, int* __restrict__ cnt,
                                 float* __restrict__ msum,
                                 int n8, int E, int nq) {
    const int gid    = blockIdx.x * 256 + threadIdx.x;
    const int stride = gridDim.x * 256;
    const int rp1 = 128 * KP1;
    const int rp_elems = rp1 + HD * D;
    for (int i = gid; i < rp_elems; i += stride) {
        if (i < rp1) {
            int n = i / KP1, k = i % KP1;
            W1p[i] = f2bf((k < MSG_IN) ? Wm1[(size_t)k * HD + n] : 0.f);
        } else {
            int i2 = i - rp1;
            int n = i2 / HD, k = i2 % HD;
            W2p[i2] = f2bf(Wm2[(size_t)k * D + n]);
        }
    }
    for (int i = gid; i < n8; i += stride) {
        float4 v0 = *(const float4*)(f + (size_t)i * 8);
        float4 v1 = *(const float4*)(f + (size_t)i * 8 + 4);
        union { ushort_t us[8]; short8v v; } pk;
        pk.us[0] = f2bf(v0.x); pk.us[1] = f2bf(v0.y);
        pk.us[2] = f2bf(v0.z); pk.us[3] = f2bf(v0.w);
        pk.us[4] = f2bf(v1.x); pk.us[5] = f2bf(v1.y);
        pk.us[6] = f2bf(v1.z); pk.us[7] = f2bf(v1.w);
        *(short8v*)(fb + (size_t)i * 8) = pk.v;
    }
    for (int i = gid; i < E; i += stride) atomicAdd(&cnt[dst[i]], 1);
    float4 z = {0.f, 0.f, 0.f, 0.f};
    for (int i = gid; i < nq; i += stride) *(float4*)(msum + (size_t)i * 4) = z;
}

// ---------------- CSR build: parallel scan (4 elems/thread) -> scatter ----------------
__global__ __launch_bounds__(1024) void scan_kernel(const int* __restrict__ cnt,
                                                    int* __restrict__ roff,
                                                    int* __restrict__ cursor, int Nn) {
    __shared__ int wsum[16];
    const int t = threadIdx.x, l = t & 63, wid = t >> 6;
    int running = 0;
    for (int base = 0; base < Nn; base += 4096) {
        const int i0 = base + t * 4;
        int v0 = 0, v1 = 0, v2 = 0, v3 = 0;
        if (i0 + 3 < Nn) {
            int4 v = *(const int4*)(cnt + i0);
            v0 = v.x; v1 = v.y; v2 = v.z; v3 = v.w;
        } else {
            if (i0 + 0 < Nn) v0 = cnt[i0 + 0];
            if (i0 + 1 < Nn) v1 = cnt[i0 + 1];
            if (i0 + 2 < Nn) v2 = cnt[i0 + 2];
        }
        const int vsum = v0 + v1 + v2 + v3;
        int s = vsum;
        #pragma unroll
        for (int off = 1; off < 64; off <<= 1) {
            int u = __shfl_up(s, off, 64);
            if (l >= off) s += u;
        }
        if (l == 63) wsum[wid] = s;
        __syncthreads();
        if (wid == 0 && l < 16) {
            int xv = wsum[l];
            #pragma unroll
            for (int off = 1; off < 16; off <<= 1) {
                int u = __shfl_up(xv, off, 64);
                if (l >= off) xv += u;
            }
            wsum[l] = xv;
        }
        __syncthreads();
        const int prev  = (wid > 0) ? wsum[wid - 1] : 0;
        const int total = wsum[15];
        int ex = running + prev + (s - vsum);
        if (i0 + 0 < Nn) { roff[i0 + 0] = ex; cursor[i0 + 0] = ex; } ex += v0;
        if (i0 + 1 < Nn) { roff[i0 + 1] = ex; cursor[i0 + 1] = ex; } ex += v1;
        if (i0 + 2 < Nn) { roff[i0 + 2] = ex; cursor[i0 + 2] = ex; } ex += v2;
        if (i0 + 3 < Nn) { roff[i0 + 3] = ex; cursor[i0 + 3] = ex; }
        running += total;
        __syncthreads();
    }
}

__global__ void scatter_kernel(const int* __restrict__ dst, int* cursor,
                               int* __restrict__ perm, int* __restrict__ sdst, int E) {
    int i = blockIdx.x * 256 + threadIdx.x;
    if (i < E) {
        int d = dst[i];
        int s = atomicAdd(&cursor[d], 1);
        perm[s] = i;
        sdst[s] = d;
    }
}

// ---------------- edge kernel v12: fused in-register segment reduce, b16 hid writes ----------------
__global__ __launch_bounds__(NT, 4) void edge_mfma_fused_kernel(
    const ushort_t* __restrict__ fbf, const float* __restrict__ x,
    const float* __restrict__ w, const int* __restrict__ src,
    const int* __restrict__ perm, const int* __restrict__ sdst,
    const ushort_t* __restrict__ W1p, const float* __restrict__ bm1,
    const ushort_t* __restrict__ W2p, const float* __restrict__ bm2,
    float* __restrict__ msum, int E)
{
    __shared__ __align__(16) ushort_t lds[4 * EB * 64 + EB * 32];  // 36,864 B

    const int t    = threadIdx.x;
    const int lane = t & 63;
    const int wv   = t >> 6;
    const int e0   = blockIdx.x * EB;

    // per-lane sorted-dst (issued early; used by the register reduce at the end)
    const int myd  = (e0 + lane < E) ? sdst[e0 + lane] : -1;
    const int prevd = (e0 > 0) ? sdst[e0 - 1] : -2;
    const int nextd = (e0 + EB < E) ? sdst[e0 + EB] : -2;

    // ---- f staging: 8 x global_load_lds_dwordx4, pre-swizzled global source ----
    {
        const int el8 = lane >> 3;
        const int s   = lane & 7;
        const int sl  = s ^ el8;            // involution swizzle
        const int slA = min(e0 + wv * 16 + el8,     E - 1);
        const int slB = min(e0 + wv * 16 + 8 + el8, E - 1);
        const int geA = perm[slA], geB = perm[slB];
        const int nsA = src[geA], ndA = sdst[slA];
        const int nsB = src[geB], ndB = sdst[slB];
        #pragma unroll
        for (int p = 0; p < 4; ++p) {
            const int n0 = (p < 2) ? nsA : ndA;
            const int n1 = (p < 2) ? nsB : ndB;
            const ushort_t* g0 = fbf + (size_t)n0 * D + (p & 1) * 64 + sl * 8;
            const ushort_t* g1 = fbf + (size_t)n1 * D + (p & 1) * 64 + sl * 8;
            GLOAD_LDS16(g0, &lds[(p * EB + wv * 16    ) * 64]);
            GLOAD_LDS16(g1, &lds[(p * EB + wv * 16 + 8) * 64]);
        }
    }
    // ---- chunk 8: w feats (k0..15), sqd (k16), zeros; 2-bit swizzle ----
    {
        const int el = lane >> 2, q = lane & 3;
        const int qp = q ^ (el & 3);
        const int slot = e0 + wv * 16 + el;
        const bool ok = slot < E;
        const int sc = min(slot, E - 1);
        const int ge = perm[sc];
        union { ushort_t us[8]; short8v v; } pk;
        #pragma unroll
        for (int j = 0; j < 8; ++j) pk.us[j] = 0;
        if (ok) {
            if (q < 2) {
                float4 w0 = *(const float4*)(w + (size_t)ge * DE + q * 8);
                float4 w1 = *(const float4*)(w + (size_t)ge * DE + q * 8 + 4);
                pk.us[0] = f2bf(w0.x); pk.us[1] = f2bf(w0.y);
                pk.us[2] = f2bf(w0.z); pk.us[3] = f2bf(w0.w);
                pk.us[4] = f2bf(w1.x); pk.us[5] = f2bf(w1.y);
                pk.us[6] = f2bf(w1.z); pk.us[7] = f2bf(w1.w);
            } else if (q == 2) {
                const int ns = src[ge], nd = sdst[sc];
                float dx = x[ns*3+0] - x[nd*3+0];
                float dy = x[ns*3+1] - x[nd*3+1];
                float dz = x[ns*3+2] - x[nd*3+2];
                pk.us[0] = f2bf(dx*dx + dy*dy + dz*dz);
            }
        }
        *(short8v*)&lds[CH8 + (wv * 16 + el) * 32 + qp * 8] = pk.v;
    }

    const int col = lane & 15;
    const int g   = lane >> 4;

    const size_t wrow0 = (size_t)(wv * 32 + col) * KP1;
    const size_t wrow1 = (size_t)(wv * 32 + 16 + col) * KP1;
    short8v nb0 = *(const short8v*)&W1p[wrow0 + g * 8];
    short8v nb1 = *(const short8v*)&W1p[wrow1 + g * 8];

    __syncthreads();   // B0: staging complete

    // ---- layer 1: [64,288] x [288,32] per wave ----
    f32x4 acc[4][2];
    {
        float bv0 = bm1[wv * 32 + col];
        float bv1 = bm1[wv * 32 + 16 + col];
        #pragma unroll
        for (int rt = 0; rt < 4; ++rt) {
            acc[rt][0] = (f32x4){bv0, bv0, bv0, bv0};
            acc[rt][1] = (f32x4){bv1, bv1, bv1, bv1};
        }
    }
    #pragma unroll
    for (int c = 0; c < NCH1; ++c) {
        short8v b0 = nb0, b1 = nb1;
        if (c + 1 < NCH1) {
            nb0 = *(const short8v*)&W1p[wrow0 + (c + 1) * 32 + g * 8];
            nb1 = *(const short8v*)&W1p[wrow1 + (c + 1) * 32 + g * 8];
        }
        short8v a[4];
        #pragma unroll
        for (int rt = 0; rt < 4; ++rt) {
            const int row = rt * 16 + col;
            if (c < 8) {
                const int sP = (((c & 1) << 2) + g) ^ (row & 7);
                a[rt] = *(const short8v*)&lds[((c >> 1) * EB + row) * 64 + sP * 8];
            } else {
                const int sP = g ^ (row & 3);
                a[rt] = *(const short8v*)&lds[CH8 + row * 32 + sP * 8];
            }
        }
        #pragma unroll
        for (int rt = 0; rt < 4; ++rt) {
            acc[rt][0] = __builtin_amdgcn_mfma_f32_16x16x32_bf16(a[rt], b0, acc[rt][0], 0, 0, 0);
            acc[rt][1] = __builtin_amdgcn_mfma_f32_16x16x32_bf16(a[rt], b1, acc[rt][1], 0, 0, 0);
        }
    }
    __syncthreads();   // B1

    // hid (relu, bf16) -> pairs 0-1 region, same swizzle; all-lane b16 stores (no shfl)
    const int ph = wv >> 1;
    #pragma unroll
    for (int rt = 0; rt < 4; ++rt)
        #pragma unroll
        for (int j = 0; j < 2; ++j)
            #pragma unroll
            for (int r = 0; r < 4; ++r) {
                const int row = rt * 16 + g * 4 + r;
                float v = fmaxf(acc[rt][j][r], 0.f);
                unsigned int pk2 = cvt_pk_bf16(v, v);
                const int sH = (((wv & 1) << 2) + j * 2 + (col >> 3)) ^ (row & 7);
                lds[(ph * EB + row) * 64 + sH * 8 + (col & 7)] = (ushort_t)pk2;
            }
    __syncthreads();   // B2

    // ---- layer 2: [64,128] x [128,32] per wave ----
    const size_t w2r0 = (size_t)(wv * 32 + col) * HD;
    const size_t w2r1 = (size_t)(wv * 32 + 16 + col) * HD;
    short8v m0 = *(const short8v*)&W2p[w2r0 + g * 8];
    short8v m1 = *(const short8v*)&W2p[w2r1 + g * 8];
    f32x4 acc2[4][2];
    {
        float bv0 = bm2[wv * 32 + col];
        float bv1 = bm2[wv * 32 + 16 + col];
        #pragma unroll
        for (int rt = 0; rt < 4; ++rt) {
            acc2[rt][0] = (f32x4){bv0, bv0, bv0, bv0};
            acc2[rt][1] = (f32x4){bv1, bv1, bv1, bv1};
        }
    }
    #pragma unroll
    for (int c = 0; c < NCH2; ++c) {
        short8v b0 = m0, b1 = m1;
        if (c + 1 < NCH2) {
            m0 = *(const short8v*)&W2p[w2r0 + (c + 1) * 32 + g * 8];
            m1 = *(const short8v*)&W2p[w2r1 + (c + 1) * 32 + g * 8];
        }
        short8v a[4];
        #pragma unroll
        for (int rt = 0; rt < 4; ++rt) {
            const int row = rt * 16 + col;
            const int sP = (((c & 1) << 2) + g) ^ (row & 7);
            a[rt] = *(const short8v*)&lds[((c >> 1) * EB + row) * 64 + sP * 8];
        }
        #pragma unroll
        for (int rt = 0; rt < 4; ++rt) {
            acc2[rt][0] = __builtin_amdgcn_mfma_f32_16x16x32_bf16(a[rt], b0, acc2[rt][0], 0, 0, 0);
            acc2[rt][1] = __builtin_amdgcn_mfma_f32_16x16x32_bf16(a[rt], b1, acc2[rt][1], 0, 0, 0);
        }
    }

    // ---- wave-local segment reduce -> msum (f32); ballot-derived run metadata ----
    float qs[4][2];
    #pragma unroll
    for (int rt = 0; rt < 4; ++rt) {
        qs[rt][0] = (acc2[rt][0][0] + acc2[rt][0][1]) + (acc2[rt][0][2] + acc2[rt][0][3]);
        qs[rt][1] = (acc2[rt][1][0] + acc2[rt][1][1]) + (acc2[rt][1][2] + acc2[rt][1][3]);
    }
    const int nvalid = min(EB, E - e0);
    const int dprev_l = __shfl_up(myd, 1, 64);
    const bool head = (lane == 0) || (myd != dprev_l);
    unsigned long long rem = __ballot(head && (lane < nvalid));
    while (rem) {
        const int beg = (int)__builtin_ctzll(rem);
        rem &= rem - 1;
        const int end = rem ? (int)__builtin_ctzll(rem) : nvalid;
        const int dg  = __shfl(myd, beg, 64);

        float s0 = 0.f, s1 = 0.f;
        #pragma unroll
        for (int rt = 0; rt < 4; ++rt) {
            const int qb = rt * 16 + g * 4;
            const int lo = max(qb, beg);
            const int hi = min(qb + 4, end);
            if (lo < hi) {
                if (lo == qb && hi == qb + 4) {
                    s0 += qs[rt][0]; s1 += qs[rt][1];
                } else {
                    #pragma unroll
                    for (int r = 0; r < 4; ++r) {
                        const int sl = qb + r;
                        if (sl >= beg && sl < end) {
                            s0 += acc2[rt][0][r]; s1 += acc2[rt][1][r];
                        }
                    }
                }
            }
        }
        s0 += __shfl_xor(s0, 16, 64); s0 += __shfl_xor(s0, 32, 64);
        s1 += __shfl_xor(s1, 16, 64); s1 += __shfl_xor(s1, 32, 64);
        if (g == 0) {
            const bool bnd = (beg == 0 && dg == prevd) || (end == nvalid && dg == nextd);
            float* p = msum + (size_t)dg * D + wv * 32 + col;
            if (bnd) { atomicAdd(p, s0); atomicAdd(p + 16, s1); }
            else     { p[0] = s0; p[16] = s1; }
        }
    }
}

// ---------------- node kernel v12: float4-vectorized staging + update MLP ----------------
template<bool MB16>
__global__ __launch_bounds__(NT, 4) void node_kernel(
    const float* __restrict__ f, const void* __restrict__ msum_v,
    const float* __restrict__ Wu1, const float* __restrict__ bu1,
    const float* __restrict__ Wu2, const float* __restrict__ bu2,
    float* out, int Nn)
{
    __shared__ __align__(16) float hin[NB][HID_PAD];
    __shared__ __align__(16) float hid[NB][HID_PAD];
    const int t  = threadIdx.x;
    const int n0 = blockIdx.x * NB;
    const int nn = min(NB, Nn - n0);

    {
        // 32 rows x 128 cols = 4096 floats; 256 threads x 4 floats x 4 iters, all float4
        #pragma unroll
        for (int it = 0; it < 4; ++it) {
            const int idx = it * 1024 + t * 4;
            const int e   = idx >> 7;
            const int cb  = idx & 127;
            if (e < nn) {
                const size_t off = (size_t)(n0 + e) * D + cb;
                float4 mv;
                if (MB16) {
                    uint2 pk = *(const uint2*)((const ushort_t*)msum_v + off);
                    mv.x = bf2f((ushort_t)(pk.x & 0xffffu));
                    mv.y = bf2f((ushort_t)(pk.x >> 16));
                    mv.z = bf2f((ushort_t)(pk.y & 0xffffu));
                    mv.w = bf2f((ushort_t)(pk.y >> 16));
                } else {
                    mv = *(const float4*)((const float*)msum_v + off);
                }
                float4 fv = *(const float4*)&f[off];
                float4 o = {mv.x + fv.x, mv.y + fv.y, mv.z + fv.z, mv.w + fv.w};
                *(float4*)&hin[e][cb] = o;
            }
        }
    }
    __syncthreads();

    const int tc = t & 15, te2 = (t >> 4) * 2, c0 = tc * 8;
    float a1[2][8];
    #pragma unroll
    for (int c = 0; c < 8; ++c) { float bv = bu1[c0 + c]; a1[0][c] = bv; a1[1][c] = bv; }
    for (int i = 0; i < D; i += 4) {
        float m0[4], m1[4];
        *(float4*)m0 = *(const float4*)&hin[te2][i];
        *(float4*)m1 = *(const float4*)&hin[te2 + 1][i];
        #pragma unroll
        for (int r = 0; r < 4; ++r) {
            float wr[8];
            *(float4*)&wr[0] = *(const float4*)(Wu1 + (size_t)(i + r) * HD + c0);
            *(float4*)&wr[4] = *(const float4*)(Wu1 + (size_t)(i + r) * HD + c0 + 4);
            #pragma unroll
            for (int c = 0; c < 8; ++c) { a1[0][c] += m0[r]*wr[c]; a1[1][c] += m1[r]*wr[c]; }
        }
    }
    #pragma unroll
    for (int j = 0; j < 2; ++j) {
        float v[8];
        #pragma unroll
        for (int c = 0; c < 8; ++c) v[c] = fmaxf(a1[j][c], 0.f);
        *(float4*)&hid[te2 + j][c0] = *(float4*)&v[0];
        *(float4*)&hid[te2 + j][c0 + 4] = *(float4*)&v[4];
    }
    __syncthreads();
    float a2[2][8];
    #pragma unroll
    for (int c = 0; c < 8; ++c) { float bv = bu2[c0 + c]; a2[0][c] = bv; a2[1][c] = bv; }
    for (int h = 0; h < HD; h += 4) {
        float m0[4], m1[4];
        *(float4*)m0 = *(const float4*)&hid[te2][h];
        *(float4*)m1 = *(const float4*)&hid[te2 + 1][h];
        #pragma unroll
        for (int r = 0; r < 4; ++r) {
            float wr[8];
            *(float4*)&wr[0] = *(const float4*)(Wu2 + (size_t)(h + r) * D + c0);
            *(float4*)&wr[4] = *(const float4*)(Wu2 + (size_t)(h + r) * D + c0 + 4);
            #pragma unroll
            for (int c = 0; c < 8; ++c) { a2[0][c] += m0[r]*wr[c]; a2[1][c] += m1[r]*wr[c]; }
        }
    }
    #pragma unroll
    for (int j = 0; j < 2; ++j) {
        int e = te2 + j, gn = n0 + e;
        if (e < nn) {
            *(float4*)(out + (size_t)gn * D + c0) = *(float4*)&a2[j][0];
            *(float4*)(out + (size_t)gn * D + c0 + 4) = *(float4*)&a2[j][4];
        }
    }
}

// ================= fallback kernels (pk-atomic path; no CSR) =================

__global__ void repack_kernel(const float* __restrict__ Wm1, const float* __restrict__ Wm2,
                              ushort_t* __restrict__ W1p, ushort_t* __restrict__ W2p) {
    int idx = blockIdx.x * 256 + threadIdx.x;
    const int n1 = 128 * KP1;
    if (idx < n1) {
        int n = idx / KP1, k = idx % KP1;
        W1p[idx] = f2bf((k < MSG_IN) ? Wm1[(size_t)k * HD + n] : 0.f);
    } else {
        int i2 = idx - n1;
        if (i2 < HD * D) {
            int n = i2 / HD, k = i2 % HD;
            W2p[i2] = f2bf(Wm2[(size_t)k * D + n]);
        }
    }
}

__global__ void fconv_kernel(const float* __restrict__ f, ushort_t* __restrict__ fb, int n8) {
    int i = blockIdx.x * 256 + threadIdx.x;
    if (i < n8) {
        float4 v0 = *(const float4*)(f + (size_t)i * 8);
        float4 v1 = *(const float4*)(f + (size_t)i * 8 + 4);
        union { ushort_t us[8]; short8v v; } pk;
        pk.us[0] = f2bf(v0.x); pk.us[1] = f2bf(v0.y);
        pk.us[2] = f2bf(v0.z); pk.us[3] = f2bf(v0.w);
        pk.us[4] = f2bf(v1.x); pk.us[5] = f2bf(v1.y);
        pk.us[6] = f2bf(v1.z); pk.us[7] = f2bf(v1.w);
        *(short8v*)(fb + (size_t)i * 8) = pk.v;
    }
}

__global__ __launch_bounds__(NT, 4) void edge_mfma_kernel(
    const ushort_t* __restrict__ fbf, const float* __restrict__ x,
    const float* __restrict__ w, const int* __restrict__ src,
    const int* __restrict__ dst,
    const ushort_t* __restrict__ W1p, const float* __restrict__ bm1,
    const ushort_t* __restrict__ W2p, const float* __restrict__ bm2,
    ushort_t* msum, int E)
{
    __shared__ __align__(16) ushort_t lds[4 * EB * 64 + EB * 32];
    __shared__ int s_dst[EB];

    const int t    = threadIdx.x;
    const int lane = t & 63;
    const int wv   = t >> 6;
    const int e0   = blockIdx.x * EB;

    if (t < EB) s_dst[t] = (e0 + t < E) ? dst[e0 + t] : 0;
    {
        const int el8 = lane >> 3;
        const int s   = lane & 7;
        const int sl  = s ^ el8;
        const int geA = min(e0 + wv * 16 + el8,     E - 1);
        const int geB = min(e0 + wv * 16 + 8 + el8, E - 1);
        const int nsA = src[geA], ndA = dst[geA];
        const int nsB = src[geB], ndB = dst[geB];
        #pragma unroll
        for (int p = 0; p < 4; ++p) {
            const int n0 = (p < 2) ? nsA : ndA;
            const int n1 = (p < 2) ? nsB : ndB;
            const ushort_t* g0 = fbf + (size_t)n0 * D + (p & 1) * 64 + sl * 8;
            const ushort_t* g1 = fbf + (size_t)n1 * D + (p & 1) * 64 + sl * 8;
            GLOAD_LDS16(g0, &lds[(p * EB + wv * 16    ) * 64]);
            GLOAD_LDS16(g1, &lds[(p * EB + wv * 16 + 8) * 64]);
        }
    }
    {
        const int el = lane >> 2, q = lane & 3;
        const int qp = q ^ (el & 3);
        const int ge = e0 + wv * 16 + el;
        const bool ok = ge < E;
        const int gc = min(ge, E - 1);
        union { ushort_t us[8]; short8v v; } pk;
        #pragma unroll
        for (int j = 0; j < 8; ++j) pk.us[j] = 0;
        if (ok) {
            if (q < 2) {
                float4 w0 = *(const float4*)(w + (size_t)gc * DE + q * 8);
                float4 w1 = *(const float4*)(w + (size_t)gc * DE + q * 8 + 4);
                pk.us[0] = f2bf(w0.x); pk.us[1] = f2bf(w0.y);
                pk.us[2] = f2bf(w0.z); pk.us[3] = f2bf(w0.w);
                pk.us[4] = f2bf(w1.x); pk.us[5] = f2bf(w1.y);
                pk.us[6] = f2bf(w1.z); pk.us[7] = f2bf(w1.w);
            } else if (q == 2) {
                const int ns = src[gc], nd = dst[gc];
                float dx = x[ns*3+0] - x[nd*3+0];
                float dy = x[ns*3+1] - x[nd*3+1];
                float dz = x[ns*3+2] - x[nd*3+2];
                pk.us[0] = f2bf(dx*dx + dy*dy + dz*dz);
            }
        }
        *(short8v*)&lds[CH8 + (wv * 16 + el) * 32 + qp * 8] = pk.v;
    }

    const int col = lane & 15;
    const int g   = lane >> 4;
    const size_t wrow0 = (size_t)(wv * 32 + col) * KP1;
    const size_t wrow1 = (size_t)(wv * 32 + 16 + col) * KP1;
    short8v nb0 = *(const short8v*)&W1p[wrow0 + g * 8];
    short8v nb1 = *(const short8v*)&W1p[wrow1 + g * 8];
    __syncthreads();

    f32x4 acc[4][2];
    {
        float bv0 = bm1[wv * 32 + col];
        float bv1 = bm1[wv * 32 + 16 + col];
        #pragma unroll
        for (int rt = 0; rt < 4; ++rt) {
            acc[rt][0] = (f32x4){bv0, bv0, bv0, bv0};
            acc[rt][1] = (f32x4){bv1, bv1, bv1, bv1};
        }
    }
    #pragma unroll
    for (int c = 0; c < NCH1; ++c) {
        short8v b0 = nb0, b1 = nb1;
        if (c + 1 < NCH1) {
            nb0 = *(const short8v*)&W1p[wrow0 + (c + 1) * 32 + g * 8];
            nb1 = *(const short8v*)&W1p[wrow1 + (c + 1) * 32 + g * 8];
        }
        short8v a[4];
        #pragma unroll
        for (int rt = 0; rt < 4; ++rt) {
            const int row = rt * 16 + col;
            if (c < 8) {
                const int sP = (((c & 1) << 2) + g) ^ (row & 7);
                a[rt] = *(const short8v*)&lds[((c >> 1) * EB + row) * 64 + sP * 8];
            } else {
                const int sP = g ^ (row & 3);
                a[rt] = *(const short8v*)&lds[CH8 + row * 32 + sP * 8];
            }
        }
        #pragma unroll
        for (int rt = 0; rt < 4; ++rt) {
            acc[rt][0] = __builtin_amdgcn_mfma_f32_16x16x32_bf16(a[rt], b0, acc[rt][0], 0, 0, 0);
            acc[rt][1] = __builtin_amdgcn_mfma_f32_16x16x32_bf16(a[rt], b1, acc[rt][1], 0, 0, 0);
        }
    }
    __syncthreads();

    const int ph = wv >> 1;
    #pragma unroll
    for (int rt = 0; rt < 4; ++rt)
        #pragma unroll
        for (int j = 0; j < 2; ++j)
            #pragma unroll
            for (int r = 0; r < 4; ++r) {
                const int row = rt * 16 + g * 4 + r;
                float v = fmaxf(acc[rt][j][r], 0.f);
                unsigned int pk2 = cvt_pk_bf16(v, v);
                const int sH = (((wv & 1) << 2) + j * 2 + (col >> 3)) ^ (row & 7);
                lds[(ph * EB + row) * 64 + sH * 8 + (col & 7)] = (ushort_t)pk2;
            }
    __syncthreads();

    const size_t w2r0 = (size_t)(wv * 32 + col) * HD;
    const size_t w2r1 = (size_t)(wv * 32 + 16 + col) * HD;
    short8v m0 = *(const short8v*)&W2p[w2r0 + g * 8];
    short8v m1 = *(const short8v*)&W2p[w2r1 + g * 8];
    f32x4 acc2[4][2];
    {
        float bv0 = bm2[wv * 32 + col];
        float bv1 = bm2[wv * 32 + 16 + col];
        #pragma unroll
        for (int rt = 0; rt < 4; ++rt) {
            acc2[rt][0] = (f32x4){bv0, bv0, bv0, bv0};
            acc2[rt][1] = (f32x4){bv1, bv1, bv1, bv1};
        }
    }
    #pragma unroll
    for (int c = 0; c < NCH2; ++c) {
        short8v b0 = m0, b1 = m1;
        if (c + 1 < NCH2) {
            m0 = *(const short8v*)&W2p[w2r0 + (c + 1) * 32 + g * 8];
            m1 = *(const short8v*)&W2p[w2r1 + (c + 1) * 32 + g * 8];
        }
        short8v a[4];
        #pragma unroll
        for (int rt = 0; rt < 4; ++rt) {
            const int row = rt * 16 + col;
            const int sP = (((c & 1) << 2) + g) ^ (row & 7);
            a[rt] = *(const short8v*)&lds[((c >> 1) * EB + row) * 64 + sP * 8];
        }
        #pragma unroll
        for (int rt = 0; rt < 4; ++rt) {
            acc2[rt][0] = __builtin_amdgcn_mfma_f32_16x16x32_bf16(a[rt], b0, acc2[rt][0], 0, 0, 0);
            acc2[rt][1] = __builtin_amdgcn_mfma_f32_16x16x32_bf16(a[rt], b1, acc2[rt][1], 0, 0, 0);
        }
    }

    const bool even = (col & 1) == 0;
    #pragma unroll
    for (int rt = 0; rt < 4; ++rt)
        #pragma unroll
        for (int r = 0; r < 4; ++r) {
            const int e  = rt * 16 + g * 4 + r;
            const int ge = e0 + e;
            const int dg = s_dst[e];
            #pragma unroll
            for (int j = 0; j < 2; ++j) {
                float v  = acc2[rt][j][r];
                float vn = __shfl_xor(v, 1, 64);
                if (even && ge < E) {
                    unsigned int pk2 = cvt_pk_bf16(v, vn);
                    ushort_t* p = msum + (size_t)dg * D + wv * 32 + j * 16 + col;
                    asm volatile("global_atomic_pk_add_bf16 %0, %1, off"
                                 :: "v"(p), "v"(pk2) : "memory");
                }
            }
        }
}

extern "C" void kernel_launch(void* const* d_in, const int* in_sizes, int n_in,
                              void* d_out, int out_size, void* d_ws, size_t ws_size,
                              hipStream_t stream) {
    const float* f   = (const float*)d_in[0];
    const float* x   = (const float*)d_in[1];
    const float* w   = (const float*)d_in[2];
    const int*   src = (const int*)d_in[3];
    const int*   dst = (const int*)d_in[4];
    const float* Wm1 = (const float*)d_in[5];
    const float* bm1 = (const float*)d_in[6];
    const float* Wm2 = (const float*)d_in[7];
    const float* bm2 = (const float*)d_in[8];
    const float* Wu1 = (const float*)d_in[9];
    const float* bu1 = (const float*)d_in[10];
    const float* Wu2 = (const float*)d_in[11];
    const float* bu2 = (const float*)d_in[12];

    const int Nn = in_sizes[0] / D;
    const int E  = in_sizes[3];

    const size_t wbytes = (size_t)(128 * KP1 + HD * D) * sizeof(ushort_t);
    auto align512 = [](size_t v) { return (v + 511) & ~(size_t)511; };

    const size_t fb_bytes = (size_t)Nn * D * 2;
    char* wsb = (char*)d_ws;

    // ---------------- primary: fused-reduce CSR layout ----------------
    size_t off = 0;
    const size_t o_w    = off; off = align512(off + wbytes);
    const size_t o_fb   = off; off = align512(off + fb_bytes);
    const size_t o_cnt  = off; off = align512(off + (size_t)Nn * 4);
    const size_t o_roff = off; off = align512(off + (size_t)Nn * 4);
    const size_t o_cur  = off; off = align512(off + (size_t)Nn * 4);
    const size_t o_perm = off; off = align512(off + (size_t)E * 4);
    const size_t o_sdst = off; off = align512(off + (size_t)E * 4);
    const size_t o_ms   = off; off = align512(off + (size_t)Nn * D * 4);
    const size_t primary_total = off;

    if (ws_size >= primary_total) {
        ushort_t* W1p = (ushort_t*)(wsb + o_w);
        ushort_t* W2p = W1p + 128 * KP1;
        ushort_t* fbf = (ushort_t*)(wsb + o_fb);
        int* cnt      = (int*)(wsb + o_cnt);
        int* roff     = (int*)(wsb + o_roff);
        int* cursor   = (int*)(wsb + o_cur);
        int* perm     = (int*)(wsb + o_perm);
        int* sdst     = (int*)(wsb + o_sdst);
        float* msum   = (float*)(wsb + o_ms);

        const int n8 = Nn * D / 8;
        const int nq = Nn * D / 4;
        hipMemsetAsync(cnt, 0, (size_t)Nn * 4, stream);
        fused_pre_kernel<<<dim3(1024), dim3(256), 0, stream>>>(
            Wm1, Wm2, W1p, W2p, f, fbf, dst, cnt, msum, n8, E, nq);
        scan_kernel<<<dim3(1), dim3(1024), 0, stream>>>(cnt, roff, cursor, Nn);
        scatter_kernel<<<dim3((E + 255) / 256), dim3(256), 0, stream>>>(dst, cursor, perm, sdst, E);
        edge_mfma_fused_kernel<<<dim3((E + EB - 1) / EB), dim3(NT), 0, stream>>>(
            fbf, x, w, src, perm, sdst, W1p, bm1, W2p, bm2, msum, E);
        node_kernel<false><<<dim3((Nn + NB - 1) / NB), dim3(NT), 0, stream>>>(
            f, msum, Wu1, bu1, Wu2, bu2, (float*)d_out, Nn);
        return;
    }

    // ---------------- fallback: pk-atomic path ----------------
    size_t off2 = 0;
    const size_t p_w  = off2; off2 = align512(off2 + wbytes);
    const size_t p_fb = off2; off2 = align512(off2 + fb_bytes);
    const size_t p_ms = off2; off2 = align512(off2 + (size_t)Nn * D * 2);
    if (ws_size >= off2) {
        ushort_t* W1p  = (ushort_t*)(wsb + p_w);
        ushort_t* W2p  = W1p + 128 * KP1;
        ushort_t* fbf  = (ushort_t*)(wsb + p_fb);
        ushort_t* msum = (ushort_t*)(wsb + p_ms);
        const int rp_elems = 128 * KP1 + HD * D;
        hipMemsetAsync(msum, 0, (size_t)Nn * D * 2, stream);
        repack_kernel<<<dim3((rp_elems + 255) / 256), dim3(256), 0, stream>>>(Wm1, Wm2, W1p, W2p);
        const int n8 = Nn * D / 8;
        fconv_kernel<<<dim3((n8 + 255) / 256), dim3(256), 0, stream>>>(f, fbf, n8);
        edge_mfma_kernel<<<dim3((E + EB - 1) / EB), dim3(NT), 0, stream>>>(
            fbf, x, w, src, dst, W1p, bm1, W2p, bm2, msum, E);
        node_kernel<true><<<dim3((Nn + NB - 1) / NB), dim3(NT), 0, stream>>>(
            f, msum, Wu1, bu1, Wu2, bu2, (float*)d_out, Nn);
        return;
    }
}